// Round 9
// baseline (1238.060 us; speedup 1.0000x reference)
//
#include <hip/hip_runtime.h>
#include <cstdint>
#include <cstdio>

#define DIMF 128
#define BKT_SHIFT 9        // 512 dsts per bucket
#define BKT_MAX 1024       // supports n3 <= 524288
#define P1_CHUNK 8192      // edges per p1/bcount block
#define P2_CAP 12288       // LDS image capacity (mean bucket ~8192, sigma ~90)

typedef __attribute__((ext_vector_type(8))) short short8v;
typedef __attribute__((ext_vector_type(4))) float f32x4;
typedef __attribute__((ext_vector_type(4))) unsigned int u32x4;

// Feature format: each row = 128 u32 words; word j = hi_bf16(x_j) | lo_bf16 << 16.
// srcl stores WORD offsets (src * 128), not raw indices.

// ---------------- JAX threefry2x32 (exact) ----------------
__host__ __device__ __forceinline__ void tf2x32(uint32_t k0, uint32_t k1,
                                                uint32_t x0, uint32_t x1,
                                                uint32_t& o0, uint32_t& o1) {
  uint32_t ks2 = k0 ^ k1 ^ 0x1BD11BDAu;
  x0 += k0; x1 += k1;
#define TFR(r) { x0 += x1; x1 = (x1 << (r)) | (x1 >> (32 - (r))); x1 ^= x0; }
  TFR(13) TFR(15) TFR(26) TFR(6)
  x0 += k1;  x1 += ks2 + 1u;
  TFR(17) TFR(29) TFR(16) TFR(24)
  x0 += ks2; x1 += k0 + 2u;
  TFR(13) TFR(15) TFR(26) TFR(6)
  x0 += k0;  x1 += k1 + 3u;
  TFR(17) TFR(29) TFR(16) TFR(24)
  x0 += k1;  x1 += ks2 + 4u;
  TFR(13) TFR(15) TFR(26) TFR(6)
  x0 += ks2; x1 += k0 + 5u;
#undef TFR
  o0 = x0; o1 = x1;
}

__device__ __forceinline__ short f2bf_rne(float x) {
  uint32_t u = __float_as_uint(x);
  uint32_t r = (u + 0x7FFFu + ((u >> 16) & 1u)) >> 16;
  return (short)r;
}
__device__ __forceinline__ float bfhi_f(short h) {
  return __uint_as_float(((uint32_t)(uint16_t)h) << 16);
}
__device__ __forceinline__ uint32_t pack_hl(float v) {
  short hi = f2bf_rne(v);
  short lo = f2bf_rne(v - bfhi_f(hi));
  return (uint32_t)(uint16_t)hi | ((uint32_t)(uint16_t)lo << 16);
}
__device__ __forceinline__ float unpk_sum(uint32_t w) {
  return __uint_as_float(w << 16) + __uint_as_float(w & 0xFFFF0000u);
}
__device__ __forceinline__ void pack2(uint32_t we, uint32_t wo, uint32_t& h, uint32_t& l) {
  h = (we & 0xFFFFu) | (wo << 16);
  l = (we >> 16) | (wo & 0xFFFF0000u);
}

// ---------------- input dropout(0.2)+relu -> interleaved rows ----------------
__global__ __launch_bounds__(256) void k_drop_in(const float* __restrict__ in,
                                                 uint32_t* __restrict__ out,
                                                 int npair, uint32_t k0, uint32_t k1) {
  int p = blockIdx.x * 256 + threadIdx.x;
  if (p >= npair) return;
  int row = p >> 6, c2 = (p & 63) * 2;
  float2 x = *(const float2*)(in + (size_t)row * 128 + c2);
  uint32_t idx = (uint32_t)(row * 128 + c2);
  float v[2] = {x.x, x.y};
  uint32_t wv[2];
#pragma unroll
  for (int q = 0; q < 2; ++q) {
    uint32_t o0, o1;
    tf2x32(k0, k1, 0u, idx + q, o0, o1);
    uint32_t bits = o0 ^ o1;
    float u = __uint_as_float((bits >> 9) | 0x3f800000u) - 1.0f;
    float y = (u < 0.8f) ? (v[q] / 0.8f) : 0.0f;
    y = fmaxf(y, 0.0f);
    wv[q] = pack_hl(y);
  }
  *(uint2*)(out + (size_t)row * 128 + c2) = make_uint2(wv[0], wv[1]);
}

// ---------------- CSR build: 2-level bucket sort ----------------
__global__ __launch_bounds__(256) void k_bcount(const int* __restrict__ ei0,
                                                const int* __restrict__ ei1,
                                                const int* __restrict__ ei2,
                                                int* __restrict__ bcnt,
                                                int E, int n, int gE8, int nbk) {
  __shared__ int hist[BKT_MAX];
  int t = threadIdx.x;
  int type = blockIdx.x / gE8;
  int chunk = blockIdx.x - type * gE8;
  const int* ei = type == 0 ? ei0 : (type == 1 ? ei1 : ei2);
  int base = chunk * P1_CHUNK;
  int dof = type * n;
  for (int i = t; i < nbk; i += 256) hist[i] = 0;
  __syncthreads();
  for (int j = 0; j < P1_CHUNK / 256; ++j) {
    int e = base + j * 256 + t;
    if (e < E) atomicAdd(&hist[(ei[E + e] + dof) >> BKT_SHIFT], 1);
  }
  __syncthreads();
  for (int i = t; i < nbk; i += 256)
    if (hist[i]) atomicAdd(&bcnt[i], hist[i]);
}

__global__ __launch_bounds__(256) void k_bscan(const int* __restrict__ bcnt,
                                               int* __restrict__ boff,
                                               int* __restrict__ gcur,
                                               int* __restrict__ off,
                                               int nbk, int n3) {
  __shared__ int ts[256];
  int t = threadIdx.x;
  int base = t * 4;
  int v[4];
#pragma unroll
  for (int i = 0; i < 4; ++i) v[i] = (base + i < nbk) ? bcnt[base + i] : 0;
  ts[t] = v[0] + v[1] + v[2] + v[3];
  __syncthreads();
  for (int ofs = 1; ofs < 256; ofs <<= 1) {
    int x = ts[t];
    int y = (t >= ofs) ? ts[t - ofs] : 0;
    __syncthreads();
    ts[t] = x + y;
    __syncthreads();
  }
  int run = (t == 0) ? 0 : ts[t - 1];
#pragma unroll
  for (int i = 0; i < 4; ++i) {
    if (base + i < nbk) { boff[base + i] = run; gcur[base + i] = run; }
    run += v[i];
  }
  if (t == 255) { boff[nbk] = ts[255]; off[n3] = ts[255]; }
}

// phase 1: scatter packed (src | localdst<<20) into per-block private runs
__global__ __launch_bounds__(256) void k_p1(const int* __restrict__ ei0,
                                            const int* __restrict__ ei1,
                                            const int* __restrict__ ei2,
                                            int* __restrict__ gcur,
                                            uint32_t* __restrict__ p1o,
                                            int E, int n, int gE8, int nbk) {
  __shared__ int hist[BKT_MAX];
  __shared__ int cur[BKT_MAX];
  int t = threadIdx.x;
  int type = blockIdx.x / gE8;
  int chunk = blockIdx.x - type * gE8;
  const int* ei = type == 0 ? ei0 : (type == 1 ? ei1 : ei2);
  int base = chunk * P1_CHUNK;
  int dof = type * n;
  for (int i = t; i < nbk; i += 256) hist[i] = 0;
  __syncthreads();
  int sv[P1_CHUNK / 256];
  int dv[P1_CHUNK / 256];
#pragma unroll
  for (int j = 0; j < P1_CHUNK / 256; ++j) {
    int e = base + j * 256 + t;
    if (e < E) { sv[j] = ei[e]; dv[j] = ei[E + e] + dof; }
    else dv[j] = -1;
  }
#pragma unroll
  for (int j = 0; j < P1_CHUNK / 256; ++j)
    if (dv[j] >= 0) atomicAdd(&hist[dv[j] >> BKT_SHIFT], 1);
  __syncthreads();
  for (int i = t; i < nbk; i += 256) {
    int h = hist[i];
    if (h > 0) cur[i] = atomicAdd(&gcur[i], h);
  }
  __syncthreads();
#pragma unroll
  for (int j = 0; j < P1_CHUNK / 256; ++j) {
    if (dv[j] >= 0) {
      int bkt = dv[j] >> BKT_SHIFT;
      int pos = atomicAdd(&cur[bkt], 1);
      p1o[pos] = (uint32_t)sv[j] | ((uint32_t)(dv[j] & 511) << 20);
    }
  }
}

// phase 2: counting sort within bucket (LDS), write off[] + coalesced srcl
// srcl gets WORD offsets (src*128) to shave gather address math.
__global__ __launch_bounds__(256) void k_p2(const uint32_t* __restrict__ p1o,
                                            const int* __restrict__ boff,
                                            int* __restrict__ off,
                                            int* __restrict__ srcl, int n3) {
  __shared__ int cnt_l[512];
  __shared__ int off_l[512];
  __shared__ int cur_l[512];
  __shared__ int ts[256];
  __shared__ int img[P2_CAP];
  int b = blockIdx.x;
  int t = threadIdx.x;
  int rb = boff[b], re = boff[b + 1];
  int sz = re - rb;
  int d0 = b << BKT_SHIFT;
  cnt_l[t] = 0; cnt_l[t + 256] = 0;
  __syncthreads();
  for (int i = rb + t; i < re; i += 256)
    atomicAdd(&cnt_l[p1o[i] >> 20], 1);
  __syncthreads();
  int c0 = cnt_l[2 * t], c1 = cnt_l[2 * t + 1];
  ts[t] = c0 + c1;
  __syncthreads();
  for (int ofs = 1; ofs < 256; ofs <<= 1) {
    int x = ts[t];
    int y = (t >= ofs) ? ts[t - ofs] : 0;
    __syncthreads();
    ts[t] = x + y;
    __syncthreads();
  }
  int ebase = (t == 0) ? 0 : ts[t - 1];
  off_l[2 * t] = ebase; off_l[2 * t + 1] = ebase + c0;
  cur_l[2 * t] = ebase; cur_l[2 * t + 1] = ebase + c0;
  __syncthreads();
  for (int j = t; j < 512; j += 256) {
    int d = d0 + j;
    if (d < n3) off[d] = rb + off_l[j];
  }
  if (sz <= P2_CAP) {
    for (int i = rb + t; i < re; i += 256) {
      uint32_t w = p1o[i];
      int pos = atomicAdd(&cur_l[w >> 20], 1);
      img[pos] = (int)(w & 0xFFFFFu) << 7;   // word offset
    }
    __syncthreads();
    for (int i = t; i < sz; i += 256) srcl[rb + i] = img[i];
  } else {
    for (int i = rb + t; i < re; i += 256) {
      uint32_t w = p1o[i];
      int pos = atomicAdd(&cur_l[w >> 20], 1);
      srcl[rb + pos] = (int)(w & 0xFFFFFu) << 7;
    }
  }
}

// ---------------- CSR gather-mean: 32 lanes/dst, 2 dsts/wave, unroll 4 ----------------
__device__ __forceinline__ void gather_one32(const uint32_t* __restrict__ feat,
                                             const int* __restrict__ off,
                                             const int* __restrict__ srcl,
                                             uint32_t* __restrict__ out,
                                             int d, int lane) {
  int b = off[d], e = off[d + 1];
  const int c4 = lane * 4;
  float a0 = 0.f, a1 = 0.f, a2 = 0.f, a3 = 0.f;
  float b0 = 0.f, b1 = 0.f, b2 = 0.f, b3 = 0.f;
  float c0 = 0.f, c1 = 0.f, c2 = 0.f, c3 = 0.f;
  float e0 = 0.f, e1 = 0.f, e2 = 0.f, e3 = 0.f;
  int j = b;
  for (; j + 3 < e; j += 4) {
    int o0 = __builtin_nontemporal_load(srcl + j);
    int o1 = __builtin_nontemporal_load(srcl + j + 1);
    int o2 = __builtin_nontemporal_load(srcl + j + 2);
    int o3 = __builtin_nontemporal_load(srcl + j + 3);
    uint4 w0 = *(const uint4*)(feat + (size_t)(o0 + c4));
    uint4 w1 = *(const uint4*)(feat + (size_t)(o1 + c4));
    uint4 w2 = *(const uint4*)(feat + (size_t)(o2 + c4));
    uint4 w3 = *(const uint4*)(feat + (size_t)(o3 + c4));
    a0 += unpk_sum(w0.x); a1 += unpk_sum(w0.y); a2 += unpk_sum(w0.z); a3 += unpk_sum(w0.w);
    b0 += unpk_sum(w1.x); b1 += unpk_sum(w1.y); b2 += unpk_sum(w1.z); b3 += unpk_sum(w1.w);
    c0 += unpk_sum(w2.x); c1 += unpk_sum(w2.y); c2 += unpk_sum(w2.z); c3 += unpk_sum(w2.w);
    e0 += unpk_sum(w3.x); e1 += unpk_sum(w3.y); e2 += unpk_sum(w3.z); e3 += unpk_sum(w3.w);
  }
  for (; j < e; ++j) {
    int o = __builtin_nontemporal_load(srcl + j);
    uint4 w = *(const uint4*)(feat + (size_t)(o + c4));
    a0 += unpk_sum(w.x); a1 += unpk_sum(w.y); a2 += unpk_sum(w.z); a3 += unpk_sum(w.w);
  }
  float sc = 1.0f / (float)max(e - b, 1);
  float v0 = ((a0 + b0) + (c0 + e0)) * sc;
  float v1 = ((a1 + b1) + (c1 + e1)) * sc;
  float v2 = ((a2 + b2) + (c2 + e2)) * sc;
  float v3 = ((a3 + b3) + (c3 + e3)) * sc;
  u32x4 r = {pack_hl(v0), pack_hl(v1), pack_hl(v2), pack_hl(v3)};
  __builtin_nontemporal_store(r, (u32x4*)(out + (size_t)d * 128 + c4));
}

// all 3 message types of one layer in a single dispatch; 2 dsts per wave
__global__ __launch_bounds__(256) void k_gather3(
    const uint32_t* __restrict__ fA, const uint32_t* __restrict__ fB,
    uint32_t* __restrict__ g1, uint32_t* __restrict__ g2, uint32_t* __restrict__ g3,
    const int* __restrict__ off, const int* __restrict__ srcl, int n) {
  int wv = (blockIdx.x * 256 + threadIdx.x) >> 6;
  int half = (threadIdx.x >> 5) & 1;
  int lane = threadIdx.x & 31;
  int d = wv * 2 + half;
  if (d >= 3 * n) return;
  if (d < n)          gather_one32(fA, off + n,     srcl, g1, d,         lane);  // ei1: A->B
  else if (d < 2 * n) gather_one32(fB, off + 2 * n, srcl, g2, d - n,     lane);  // ei2: B->A
  else                gather_one32(fA, off,         srcl, g3, d - 2 * n, lane);  // ei0: A->A
}

// ---------------- combined-weight precompute: C=A0@B0(+A1@B1) -> transposed hi/lo planar ----------------
struct WDesc { const float* A0; const float* B0; const float* A1; const float* B1; short* Ch; short* Cl; };
struct WPack { WDesc d[10]; };

__global__ __launch_bounds__(256) void k_wprec(WPack p) {
  const WDesc d = p.d[blockIdx.x >> 2];
  const int rt = blockIdx.x & 3;
  __shared__ float A_s[32 * 128];
  const int t = threadIdx.x;
  const int c = t & 127, rh = t >> 7;
  float acc[16];
#pragma unroll
  for (int i = 0; i < 16; ++i) acc[i] = 0.f;
  for (int pass = 0; pass < 2; ++pass) {
    const float* A = pass ? d.A1 : d.A0;
    const float* B = pass ? d.B1 : d.B0;
    if (!A) break;
    __syncthreads();
#pragma unroll
    for (int j = 0; j < 4; ++j) {
      int f = t + 256 * j;
      *(float4*)(A_s + 4 * f) = *(const float4*)(A + (size_t)rt * 32 * 128 + 4 * f);
    }
    __syncthreads();
    for (int k = 0; k < 128; ++k) {
      float b = B[(size_t)k * 128 + c];
#pragma unroll
      for (int i = 0; i < 16; ++i)
        acc[i] += A_s[(rh + 2 * i) * 128 + k] * b;
    }
  }
#pragma unroll
  for (int i = 0; i < 16; ++i) {
    int k = rt * 32 + rh + 2 * i;
    float v = acc[i];
    short hi = f2bf_rne(v);
    short lo = f2bf_rne(v - bfhi_f(hi));
    d.Ch[(size_t)c * 128 + k] = hi;
    d.Cl[(size_t)c * 128 + k] = lo;
  }
}

// ---------------- combined bias ----------------
__global__ __launch_bounds__(256) void k_bias(const float* __restrict__ bn,
                                              const float* __restrict__ bs,
                                              const float* __restrict__ bu,
                                              const float* __restrict__ Wu,
                                              float* __restrict__ cbA, float* __restrict__ cbB) {
  int t = threadIdx.x;
  int h = t & 127;
  if (t < 128) {
    float acc = bu[0 * 128 + h] + bu[2 * 128 + h];
    for (int j = 0; j < 128; ++j) {
      acc += bn[0 * 128 + j] * Wu[(size_t)0 * 32768 + (size_t)j * 128 + h];
      acc += bs[0 * 128 + j] * Wu[(size_t)0 * 32768 + 16384 + (size_t)j * 128 + h];
      acc += bn[2 * 128 + j] * Wu[(size_t)2 * 32768 + (size_t)j * 128 + h];
      acc += bs[2 * 128 + j] * Wu[(size_t)2 * 32768 + 16384 + (size_t)j * 128 + h];
    }
    cbA[h] = acc;
  } else {
    float acc = bu[128 + h];
    for (int j = 0; j < 128; ++j) {
      acc += bn[128 + j] * Wu[(size_t)1 * 32768 + (size_t)j * 128 + h];
      acc += bs[128 + j] * Wu[(size_t)1 * 32768 + 16384 + (size_t)j * 128 + h];
    }
    cbB[h] = acc;
  }
}

// ---------------- split-bf16 MFMA multi-term matmul (interleaved features) ----------------
template <int NT, int MODE>
__global__ __launch_bounds__(256, 2) void k_mmx(
    const uint32_t* __restrict__ s0, const uint32_t* __restrict__ s1, const uint32_t* __restrict__ s2,
    const short* __restrict__ w0h, const short* __restrict__ w0l,
    const short* __restrict__ w1h, const short* __restrict__ w1l,
    const short* __restrict__ w2h, const short* __restrict__ w2l,
    const float* __restrict__ bias, void* __restrict__ outv, int n,
    uint32_t k0, uint32_t k1) {
  __shared__ short A_s[128 * 72];   // [row][32hi|32lo|8pad] shorts, 144B stride
  __shared__ short W_s[128 * 72];   // [n][32hi|32lo|8pad]
  const int t = threadIdx.x;
  const int r0 = blockIdx.x * 128;
  const int lane = t & 63;
  const int w = t >> 6;
  const int wr = w >> 1, wc = w & 1;
  const int lr = lane & 15, lg = lane >> 4;
  const int sr = t >> 1, sh = t & 1;

  f32x4 acc[4][4];
#pragma unroll
  for (int nf = 0; nf < 4; ++nf) {
    float bv = bias[wc * 64 + nf * 16 + lr];
#pragma unroll
    for (int mf = 0; mf < 4; ++mf) acc[mf][nf] = {bv, bv, bv, bv};
  }

  for (int term = 0; term < NT; ++term) {
    const uint32_t* src = term == 0 ? s0 : (term == 1 ? s1 : s2);
    const short* wh  = term == 0 ? w0h : (term == 1 ? w1h : w2h);
    const short* wl  = term == 0 ? w0l : (term == 1 ? w1l : w2l);
    const short* wsrc = sh ? wl : wh;
    for (int ks = 0; ks < 4; ++ks) {
      __syncthreads();
      { // A tile: 16 interleaved words -> 16 hi + 16 lo shorts (planar)
        const uint4* ga = (const uint4*)(src + (size_t)(r0 + sr) * 128 + ks * 32 + sh * 16);
        uint4 q0 = ga[0], q1 = ga[1], q2 = ga[2], q3 = ga[3];
        uint32_t h[8], l[8];
        pack2(q0.x, q0.y, h[0], l[0]); pack2(q0.z, q0.w, h[1], l[1]);
        pack2(q1.x, q1.y, h[2], l[2]); pack2(q1.z, q1.w, h[3], l[3]);
        pack2(q2.x, q2.y, h[4], l[4]); pack2(q2.z, q2.w, h[5], l[5]);
        pack2(q3.x, q3.y, h[6], l[6]); pack2(q3.z, q3.w, h[7], l[7]);
        uint4* Ah = (uint4*)(A_s + sr * 72 + sh * 16);
        uint4* Al = (uint4*)(A_s + sr * 72 + 32 + sh * 16);
        Ah[0] = make_uint4(h[0], h[1], h[2], h[3]);
        Ah[1] = make_uint4(h[4], h[5], h[6], h[7]);
        Al[0] = make_uint4(l[0], l[1], l[2], l[3]);
        Al[1] = make_uint4(l[4], l[5], l[6], l[7]);
        const uint4* gw = (const uint4*)(wsrc + sr * 128 + ks * 32);
        uint4 b0 = gw[0], b1 = gw[1], b2 = gw[2], b3 = gw[3];
        uint4* lw = (uint4*)(W_s + sr * 72 + sh * 32);
        lw[0] = b0; lw[1] = b1; lw[2] = b2; lw[3] = b3;
      }
      __syncthreads();
      short8v whi[4], wlo[4];
#pragma unroll
      for (int nf = 0; nf < 4; ++nf) {
        int nc = wc * 64 + nf * 16 + lr;
        whi[nf] = *(const short8v*)(W_s + nc * 72 + lg * 8);
        wlo[nf] = *(const short8v*)(W_s + nc * 72 + 32 + lg * 8);
      }
#pragma unroll
      for (int mf = 0; mf < 4; ++mf) {
        int ar = wr * 64 + mf * 16 + lr;
        short8v ah = *(const short8v*)(A_s + ar * 72 + lg * 8);
        short8v al = *(const short8v*)(A_s + ar * 72 + 32 + lg * 8);
#pragma unroll
        for (int nf = 0; nf < 4; ++nf) {
          acc[mf][nf] = __builtin_amdgcn_mfma_f32_16x16x32_bf16(ah, whi[nf], acc[mf][nf], 0, 0, 0);
          acc[mf][nf] = __builtin_amdgcn_mfma_f32_16x16x32_bf16(ah, wlo[nf], acc[mf][nf], 0, 0, 0);
          acc[mf][nf] = __builtin_amdgcn_mfma_f32_16x16x32_bf16(al, whi[nf], acc[mf][nf], 0, 0, 0);
        }
      }
    }
  }

#pragma unroll
  for (int mf = 0; mf < 4; ++mf) {
#pragma unroll
    for (int r = 0; r < 4; ++r) {
      int g = r0 + wr * 64 + mf * 16 + lg * 4 + r;
      if (g >= n) continue;
#pragma unroll
      for (int nf = 0; nf < 4; ++nf) {
        int col = wc * 64 + nf * 16 + lr;
        float v = acc[mf][nf][r];
        if constexpr (MODE == 1) {
          uint32_t o0, o1;
          tf2x32(k0, k1, 0u, (uint32_t)(g * 128 + col), o0, o1);
          uint32_t bits = o0 ^ o1;
          float u = __uint_as_float((bits >> 9) | 0x3f800000u) - 1.0f;
          v = (u < 0.8f) ? (v / 0.8f) : 0.0f;
          v = fmaxf(v, 0.0f);
          ((uint32_t*)outv)[(size_t)g * 128 + col] = pack_hl(v);
        } else {
          __builtin_nontemporal_store(v, (float*)outv + (size_t)g * 128 + col);
        }
      }
    }
  }
}

// ---------------- host driver ----------------
extern "C" void kernel_launch(void* const* d_in, const int* in_sizes, int n_in,
                              void* d_out, int out_size, void* d_ws, size_t ws_size,
                              hipStream_t stream) {
  const float* xA  = (const float*)d_in[0];
  const float* xB  = (const float*)d_in[1];
  const int*   ei0 = (const int*)d_in[2];
  const int*   ei1 = (const int*)d_in[3];
  const int*   ei2 = (const int*)d_in[4];
  const float* Wn1 = (const float*)d_in[5];
  const float* Ws1 = (const float*)d_in[6];
  const float* Wu1 = (const float*)d_in[7];
  const float* Wn2 = (const float*)d_in[8];
  const float* Ws2 = (const float*)d_in[9];
  const float* Wu2 = (const float*)d_in[10];
  const float* bn1 = (const float*)d_in[11];
  const float* bs1 = (const float*)d_in[12];
  const float* bu1 = (const float*)d_in[13];
  const float* bn2 = (const float*)d_in[14];
  const float* bs2 = (const float*)d_in[15];
  const float* bu2 = (const float*)d_in[16];

  const int n  = in_sizes[0] / DIMF;        // 100000
  const int E  = in_sizes[2] / 2;           // 1600000
  const int n3 = 3 * n;
  const int nbk = (n3 + 511) >> BKT_SHIFT;  // 586
  const size_t nh = (size_t)n * DIMF;

  float* ws = (float*)d_ws;
  uint32_t* buf_hA = (uint32_t*)(ws);           // hA -> h2A (in place)
  uint32_t* buf_hB = (uint32_t*)(ws + nh);      // hB -> h2B (in place)
  uint32_t* g1     = (uint32_t*)(ws + 2 * nh);  // ei1 aggr / p1o alias
  uint32_t* g2     = (uint32_t*)(ws + 3 * nh);  // ei2 aggr
  short* wtsS   = (short*)(ws + 4 * nh);        // 10 x (16384 hi + 16384 lo) shorts
  float* biasF  = (float*)(wtsS + 10 * 32768);
  float* cbA1 = biasF, *cbB1 = biasF + 128, *cbA2 = biasF + 256, *cbB2 = biasF + 384;
  int* off  = (int*)(biasF + 512);          // [n3+1]
  int* bcnt = off + n3 + 1;                 // [BKT_MAX]
  int* boff = bcnt + BKT_MAX;               // [BKT_MAX+1]
  int* gcur = boff + BKT_MAX + 1;           // [BKT_MAX]
  int* srcl = gcur + BKT_MAX;               // [3E] word offsets
  uint32_t* p1o = g1;                       // 3E u32, used only before gathers
  uint32_t* g3  = (uint32_t*)d_out;         // ei0 aggr scratch: d_out[0..nh) dead
                                            // until final k_mmx (block-local in-place)

  size_t need_bytes = (4 * nh + 512) * sizeof(float)
                    + (size_t)10 * 32768 * sizeof(short)
                    + ((size_t)n3 + 1 + 3 * BKT_MAX + 1 + (size_t)3 * E) * sizeof(int)
                    + 65536;
  if (ws_size < need_bytes) {
    fprintf(stderr, "kernel_launch: ws too small (%zu < %zu)\n", ws_size, need_bytes);
    return;
  }

  // JAX keys: dk = split(key(42), 4) (partitionable threefry, verified round 2)
  uint32_t dk[4][2];
  for (uint32_t i = 0; i < 4; ++i) tf2x32(0u, 42u, 0u, i, dk[i][0], dk[i][1]);

  WPack pk;
  auto U = [](const float* Wu, int t) { return Wu + (size_t)t * 32768; };
  auto L = [](const float* Wu, int t) { return Wu + (size_t)t * 32768 + 16384; };
  auto WH = [&](int m) { return wtsS + (size_t)m * 32768; };
  auto WL = [&](int m) { return wtsS + (size_t)m * 32768 + 16384; };
  const size_t MS = 128 * 128;
  pk.d[0] = { Wn1 + 0 * MS, U(Wu1, 0), nullptr, nullptr, WH(0), WL(0) };
  pk.d[1] = { Wn1 + 1 * MS, U(Wu1, 1), nullptr, nullptr, WH(1), WL(1) };
  pk.d[2] = { Wn1 + 2 * MS, U(Wu1, 2), nullptr, nullptr, WH(2), WL(2) };
  pk.d[3] = { Ws1 + 0 * MS, L(Wu1, 0), Ws1 + 2 * MS, L(Wu1, 2), WH(3), WL(3) };
  pk.d[4] = { Ws1 + 1 * MS, L(Wu1, 1), nullptr, nullptr, WH(4), WL(4) };
  pk.d[5] = { Wn2 + 0 * MS, U(Wu2, 0), nullptr, nullptr, WH(5), WL(5) };
  pk.d[6] = { Wn2 + 1 * MS, U(Wu2, 1), nullptr, nullptr, WH(6), WL(6) };
  pk.d[7] = { Wn2 + 2 * MS, U(Wu2, 2), nullptr, nullptr, WH(7), WL(7) };
  pk.d[8] = { Ws2 + 0 * MS, L(Wu2, 0), Ws2 + 2 * MS, L(Wu2, 2), WH(8), WL(8) };
  pk.d[9] = { Ws2 + 1 * MS, L(Wu2, 1), nullptr, nullptr, WH(9), WL(9) };

  const int gdrop = (int)((nh / 2 + 255) / 256);
  const int gE8   = (E + P1_CHUNK - 1) / P1_CHUNK;
  const int gmm   = (n + 127) / 128;
  const int nwv   = (n3 + 1) / 2;                   // 2 dsts per wave
  const int gga3  = (nwv * 64 + 255) / 256;

  // ---- CSR build: 2-level bucket sort ----
  hipMemsetAsync(bcnt, 0, (size_t)nbk * sizeof(int), stream);
  k_bcount<<<3 * gE8, 256, 0, stream>>>(ei0, ei1, ei2, bcnt, E, n, gE8, nbk);
  k_bscan<<<1, 256, 0, stream>>>(bcnt, boff, gcur, off, nbk, n3);
  k_p1<<<3 * gE8, 256, 0, stream>>>(ei0, ei1, ei2, gcur, p1o, E, n, gE8, nbk);
  k_p2<<<nbk, 256, 0, stream>>>(p1o, boff, off, srcl, n3);

  // ---- weights / biases ----
  k_wprec<<<40, 256, 0, stream>>>(pk);
  k_bias<<<1, 256, 0, stream>>>(bn1, bs1, bu1, Wu1, cbA1, cbB1);
  k_bias<<<1, 256, 0, stream>>>(bn2, bs2, bu2, Wu2, cbA2, cbB2);

  // ---- input dropout+relu -> interleaved ----
  k_drop_in<<<gdrop, 256, 0, stream>>>(xA, buf_hA, (int)(nh / 2), dk[0][0], dk[0][1]);
  k_drop_in<<<gdrop, 256, 0, stream>>>(xB, buf_hB, (int)(nh / 2), dk[1][0], dk[1][1]);

  // ---- layer 1 ----
  k_gather3<<<gga3, 256, 0, stream>>>(buf_hA, buf_hB, g1, g2, g3, off, srcl, n);
  k_mmx<2, 1><<<gmm, 256, 0, stream>>>(g1, buf_hB, nullptr,
                                       WH(1), WL(1), WH(4), WL(4), nullptr, nullptr,
                                       cbB1, buf_hB, n, dk[3][0], dk[3][1]);  // h2B in place
  k_mmx<3, 1><<<gmm, 256, 0, stream>>>(g3, g2, buf_hA,
                                       WH(0), WL(0), WH(2), WL(2), WH(3), WL(3),
                                       cbA1, buf_hA, n, dk[2][0], dk[2][1]);  // h2A in place

  // ---- layer 2 ----
  float* oA = (float*)d_out;
  float* oB = oA + nh;
  k_gather3<<<gga3, 256, 0, stream>>>(buf_hA, buf_hB, g1, g2, g3, off, srcl, n);
  k_mmx<2, 0><<<gmm, 256, 0, stream>>>(g1, buf_hB, nullptr,
                                       WH(6), WL(6), WH(9), WL(9), nullptr, nullptr,
                                       cbB2, oB, n, 0u, 0u);
  k_mmx<3, 0><<<gmm, 256, 0, stream>>>(g3, g2, buf_hA,
                                       WH(5), WL(5), WH(7), WL(7), WH(8), WL(8),
                                       cbA2, oA, n, 0u, 0u);  // in-place over g3
}

// Round 10
// 949.696 us; speedup vs baseline: 1.3036x; 1.3036x over previous
//
#include <hip/hip_runtime.h>
#include <cstdint>
#include <cstdio>

#define DIMF 128
#define BKT_SHIFT 9        // 512 dsts per bucket
#define BKT_MAX 1024       // supports n3 <= 524288
#define P1_CHUNK 8192      // edges per p1/bcount block
#define P2_CAP 12288       // LDS image capacity (mean bucket ~8192, sigma ~90)

typedef __attribute__((ext_vector_type(8))) short short8v;
typedef __attribute__((ext_vector_type(4))) float f32x4;
typedef __attribute__((ext_vector_type(4))) unsigned int u32x4;

// Feature format: SPLIT PLANES. hiX[n*128] shorts (bf16 hi), loX[n*128] shorts
// (bf16 residual); x ~= hi + lo (~2^-17 rel). Gather reads hi plane ONLY
// (error ~1e-5 at output, vs 6e-4 threshold). Gather outputs g: interleaved
// u32 (hi | lo<<16) per element, full precision of the f32 sum.
// srcl stores u32-plane word offsets (src * 64).

// ---------------- JAX threefry2x32 (exact) ----------------
__host__ __device__ __forceinline__ void tf2x32(uint32_t k0, uint32_t k1,
                                                uint32_t x0, uint32_t x1,
                                                uint32_t& o0, uint32_t& o1) {
  uint32_t ks2 = k0 ^ k1 ^ 0x1BD11BDAu;
  x0 += k0; x1 += k1;
#define TFR(r) { x0 += x1; x1 = (x1 << (r)) | (x1 >> (32 - (r))); x1 ^= x0; }
  TFR(13) TFR(15) TFR(26) TFR(6)
  x0 += k1;  x1 += ks2 + 1u;
  TFR(17) TFR(29) TFR(16) TFR(24)
  x0 += ks2; x1 += k0 + 2u;
  TFR(13) TFR(15) TFR(26) TFR(6)
  x0 += k0;  x1 += k1 + 3u;
  TFR(17) TFR(29) TFR(16) TFR(24)
  x0 += k1;  x1 += ks2 + 4u;
  TFR(13) TFR(15) TFR(26) TFR(6)
  x0 += ks2; x1 += k0 + 5u;
#undef TFR
  o0 = x0; o1 = x1;
}

__device__ __forceinline__ short f2bf_rne(float x) {
  uint32_t u = __float_as_uint(x);
  uint32_t r = (u + 0x7FFFu + ((u >> 16) & 1u)) >> 16;
  return (short)r;
}
__device__ __forceinline__ float bfhi_f(short h) {
  return __uint_as_float(((uint32_t)(uint16_t)h) << 16);
}
__device__ __forceinline__ uint32_t pack_hl(float v) {
  short hi = f2bf_rne(v);
  short lo = f2bf_rne(v - bfhi_f(hi));
  return (uint32_t)(uint16_t)hi | ((uint32_t)(uint16_t)lo << 16);
}
// interleaved word -> hi+lo sum
__device__ __forceinline__ float unpk_sum(uint32_t w) {
  return __uint_as_float(w << 16) + __uint_as_float(w & 0xFFFF0000u);
}
// hi-plane word (2 packed bf16) -> 2 floats
__device__ __forceinline__ void unpk2(uint32_t w, float& f0, float& f1) {
  f0 = __uint_as_float(w << 16);
  f1 = __uint_as_float(w & 0xFFFF0000u);
}
__device__ __forceinline__ void pack2(uint32_t we, uint32_t wo, uint32_t& h, uint32_t& l) {
  h = (we & 0xFFFFu) | (wo << 16);
  l = (we >> 16) | (wo & 0xFFFF0000u);
}

// ---------------- input dropout(0.2)+relu -> hi/lo planes ----------------
__global__ __launch_bounds__(256) void k_drop_in(const float* __restrict__ in,
                                                 uint32_t* __restrict__ hiP,
                                                 uint32_t* __restrict__ loP,
                                                 int npair, uint32_t k0, uint32_t k1) {
  int p = blockIdx.x * 256 + threadIdx.x;
  if (p >= npair) return;
  int row = p >> 6, w = p & 63;
  int c2 = w * 2;
  float2 x = *(const float2*)(in + (size_t)row * 128 + c2);
  uint32_t idx = (uint32_t)(row * 128 + c2);
  float v[2] = {x.x, x.y};
  uint32_t hw = 0, lw = 0;
#pragma unroll
  for (int q = 0; q < 2; ++q) {
    uint32_t o0, o1;
    tf2x32(k0, k1, 0u, idx + q, o0, o1);
    uint32_t bits = o0 ^ o1;
    float u = __uint_as_float((bits >> 9) | 0x3f800000u) - 1.0f;
    float y = (u < 0.8f) ? (v[q] / 0.8f) : 0.0f;
    y = fmaxf(y, 0.0f);
    short hi = f2bf_rne(y);
    short lo = f2bf_rne(y - bfhi_f(hi));
    hw |= (uint32_t)(uint16_t)hi << (16 * q);
    lw |= (uint32_t)(uint16_t)lo << (16 * q);
  }
  hiP[(size_t)row * 64 + w] = hw;
  loP[(size_t)row * 64 + w] = lw;
}

// ---------------- CSR build: 2-level bucket sort ----------------
__global__ __launch_bounds__(256) void k_bcount(const int* __restrict__ ei0,
                                                const int* __restrict__ ei1,
                                                const int* __restrict__ ei2,
                                                int* __restrict__ bcnt,
                                                int E, int n, int gE8, int nbk) {
  __shared__ int hist[BKT_MAX];
  int t = threadIdx.x;
  int type = blockIdx.x / gE8;
  int chunk = blockIdx.x - type * gE8;
  const int* ei = type == 0 ? ei0 : (type == 1 ? ei1 : ei2);
  int base = chunk * P1_CHUNK;
  int dof = type * n;
  for (int i = t; i < nbk; i += 256) hist[i] = 0;
  __syncthreads();
  for (int j = 0; j < P1_CHUNK / 256; ++j) {
    int e = base + j * 256 + t;
    if (e < E) atomicAdd(&hist[(ei[E + e] + dof) >> BKT_SHIFT], 1);
  }
  __syncthreads();
  for (int i = t; i < nbk; i += 256)
    if (hist[i]) atomicAdd(&bcnt[i], hist[i]);
}

__global__ __launch_bounds__(256) void k_bscan(const int* __restrict__ bcnt,
                                               int* __restrict__ boff,
                                               int* __restrict__ gcur,
                                               int* __restrict__ off,
                                               int nbk, int n3) {
  __shared__ int ts[256];
  int t = threadIdx.x;
  int base = t * 4;
  int v[4];
#pragma unroll
  for (int i = 0; i < 4; ++i) v[i] = (base + i < nbk) ? bcnt[base + i] : 0;
  ts[t] = v[0] + v[1] + v[2] + v[3];
  __syncthreads();
  for (int ofs = 1; ofs < 256; ofs <<= 1) {
    int x = ts[t];
    int y = (t >= ofs) ? ts[t - ofs] : 0;
    __syncthreads();
    ts[t] = x + y;
    __syncthreads();
  }
  int run = (t == 0) ? 0 : ts[t - 1];
#pragma unroll
  for (int i = 0; i < 4; ++i) {
    if (base + i < nbk) { boff[base + i] = run; gcur[base + i] = run; }
    run += v[i];
  }
  if (t == 255) { boff[nbk] = ts[255]; off[n3] = ts[255]; }
}

// phase 1: scatter packed (src | localdst<<20) into per-block private runs
__global__ __launch_bounds__(256) void k_p1(const int* __restrict__ ei0,
                                            const int* __restrict__ ei1,
                                            const int* __restrict__ ei2,
                                            int* __restrict__ gcur,
                                            uint32_t* __restrict__ p1o,
                                            int E, int n, int gE8, int nbk) {
  __shared__ int hist[BKT_MAX];
  __shared__ int cur[BKT_MAX];
  int t = threadIdx.x;
  int type = blockIdx.x / gE8;
  int chunk = blockIdx.x - type * gE8;
  const int* ei = type == 0 ? ei0 : (type == 1 ? ei1 : ei2);
  int base = chunk * P1_CHUNK;
  int dof = type * n;
  for (int i = t; i < nbk; i += 256) hist[i] = 0;
  __syncthreads();
  int sv[P1_CHUNK / 256];
  int dv[P1_CHUNK / 256];
#pragma unroll
  for (int j = 0; j < P1_CHUNK / 256; ++j) {
    int e = base + j * 256 + t;
    if (e < E) { sv[j] = ei[e]; dv[j] = ei[E + e] + dof; }
    else dv[j] = -1;
  }
#pragma unroll
  for (int j = 0; j < P1_CHUNK / 256; ++j)
    if (dv[j] >= 0) atomicAdd(&hist[dv[j] >> BKT_SHIFT], 1);
  __syncthreads();
  for (int i = t; i < nbk; i += 256) {
    int h = hist[i];
    if (h > 0) cur[i] = atomicAdd(&gcur[i], h);
  }
  __syncthreads();
#pragma unroll
  for (int j = 0; j < P1_CHUNK / 256; ++j) {
    if (dv[j] >= 0) {
      int bkt = dv[j] >> BKT_SHIFT;
      int pos = atomicAdd(&cur[bkt], 1);
      p1o[pos] = (uint32_t)sv[j] | ((uint32_t)(dv[j] & 511) << 20);
    }
  }
}

// phase 2: counting sort within bucket (LDS), write off[] + coalesced srcl.
// srcl gets u32-plane word offsets (src*64).
__global__ __launch_bounds__(256) void k_p2(const uint32_t* __restrict__ p1o,
                                            const int* __restrict__ boff,
                                            int* __restrict__ off,
                                            int* __restrict__ srcl, int n3) {
  __shared__ int cnt_l[512];
  __shared__ int off_l[512];
  __shared__ int cur_l[512];
  __shared__ int ts[256];
  __shared__ int img[P2_CAP];
  int b = blockIdx.x;
  int t = threadIdx.x;
  int rb = boff[b], re = boff[b + 1];
  int sz = re - rb;
  int d0 = b << BKT_SHIFT;
  cnt_l[t] = 0; cnt_l[t + 256] = 0;
  __syncthreads();
  for (int i = rb + t; i < re; i += 256)
    atomicAdd(&cnt_l[p1o[i] >> 20], 1);
  __syncthreads();
  int c0 = cnt_l[2 * t], c1 = cnt_l[2 * t + 1];
  ts[t] = c0 + c1;
  __syncthreads();
  for (int ofs = 1; ofs < 256; ofs <<= 1) {
    int x = ts[t];
    int y = (t >= ofs) ? ts[t - ofs] : 0;
    __syncthreads();
    ts[t] = x + y;
    __syncthreads();
  }
  int ebase = (t == 0) ? 0 : ts[t - 1];
  off_l[2 * t] = ebase; off_l[2 * t + 1] = ebase + c0;
  cur_l[2 * t] = ebase; cur_l[2 * t + 1] = ebase + c0;
  __syncthreads();
  for (int j = t; j < 512; j += 256) {
    int d = d0 + j;
    if (d < n3) off[d] = rb + off_l[j];
  }
  if (sz <= P2_CAP) {
    for (int i = rb + t; i < re; i += 256) {
      uint32_t w = p1o[i];
      int pos = atomicAdd(&cur_l[w >> 20], 1);
      img[pos] = (int)(w & 0xFFFFFu) << 6;   // u32-plane word offset
    }
    __syncthreads();
    for (int i = t; i < sz; i += 256) srcl[rb + i] = img[i];
  } else {
    for (int i = rb + t; i < re; i += 256) {
      uint32_t w = p1o[i];
      int pos = atomicAdd(&cur_l[w >> 20], 1);
      srcl[rb + pos] = (int)(w & 0xFFFFFu) << 6;
    }
  }
}

// ---------------- CSR gather-mean over HI PLANE: 32 lanes/dst, 2 dsts/wave ----------------
__device__ __forceinline__ void gather_one32(const uint32_t* __restrict__ hiP,
                                             const int* __restrict__ off,
                                             const int* __restrict__ srcl,
                                             uint32_t* __restrict__ out,
                                             int d, int lane) {
  int b = off[d], e = off[d + 1];
  const int c2 = lane * 2;        // u32 word pair within 64-word row
  float a0 = 0.f, a1 = 0.f, a2 = 0.f, a3 = 0.f;
  float b0 = 0.f, b1 = 0.f, b2 = 0.f, b3 = 0.f;
  float c0 = 0.f, c1 = 0.f, c2f = 0.f, c3 = 0.f;
  float e0 = 0.f, e1 = 0.f, e2 = 0.f, e3 = 0.f;
  float t0, t1;
  int j = b;
  for (; j + 3 < e; j += 4) {
    int o0 = __builtin_nontemporal_load(srcl + j);
    int o1 = __builtin_nontemporal_load(srcl + j + 1);
    int o2 = __builtin_nontemporal_load(srcl + j + 2);
    int o3 = __builtin_nontemporal_load(srcl + j + 3);
    uint2 w0 = *(const uint2*)(hiP + (size_t)(o0 + c2));
    uint2 w1 = *(const uint2*)(hiP + (size_t)(o1 + c2));
    uint2 w2 = *(const uint2*)(hiP + (size_t)(o2 + c2));
    uint2 w3 = *(const uint2*)(hiP + (size_t)(o3 + c2));
    unpk2(w0.x, t0, t1); a0 += t0; a1 += t1;
    unpk2(w0.y, t0, t1); a2 += t0; a3 += t1;
    unpk2(w1.x, t0, t1); b0 += t0; b1 += t1;
    unpk2(w1.y, t0, t1); b2 += t0; b3 += t1;
    unpk2(w2.x, t0, t1); c0 += t0; c1 += t1;
    unpk2(w2.y, t0, t1); c2f += t0; c3 += t1;
    unpk2(w3.x, t0, t1); e0 += t0; e1 += t1;
    unpk2(w3.y, t0, t1); e2 += t0; e3 += t1;
  }
  for (; j < e; ++j) {
    int o = __builtin_nontemporal_load(srcl + j);
    uint2 w = *(const uint2*)(hiP + (size_t)(o + c2));
    unpk2(w.x, t0, t1); a0 += t0; a1 += t1;
    unpk2(w.y, t0, t1); a2 += t0; a3 += t1;
  }
  float sc = 1.0f / (float)max(e - b, 1);
  float v0 = ((a0 + b0) + (c0 + e0)) * sc;
  float v1 = ((a1 + b1) + (c1 + e1)) * sc;
  float v2 = ((a2 + b2) + (c2f + e2)) * sc;
  float v3 = ((a3 + b3) + (c3 + e3)) * sc;
  u32x4 r = {pack_hl(v0), pack_hl(v1), pack_hl(v2), pack_hl(v3)};
  __builtin_nontemporal_store(r, (u32x4*)(out + (size_t)d * 128 + lane * 4));
}

// all 3 message types of one layer in a single dispatch; 2 dsts per wave
__global__ __launch_bounds__(256) void k_gather3(
    const uint32_t* __restrict__ hiA, const uint32_t* __restrict__ hiB,
    uint32_t* __restrict__ g1, uint32_t* __restrict__ g2, uint32_t* __restrict__ g3,
    const int* __restrict__ off, const int* __restrict__ srcl, int n) {
  int wv = (blockIdx.x * 256 + threadIdx.x) >> 6;
  int half = (threadIdx.x >> 5) & 1;
  int lane = threadIdx.x & 31;
  int d = wv * 2 + half;
  if (d >= 3 * n) return;
  if (d < n)          gather_one32(hiA, off + n,     srcl, g1, d,         lane);  // ei1: A->B
  else if (d < 2 * n) gather_one32(hiB, off + 2 * n, srcl, g2, d - n,     lane);  // ei2: B->A
  else                gather_one32(hiA, off,         srcl, g3, d - 2 * n, lane);  // ei0: A->A
}

// ---------------- combined-weight precompute: C=A0@B0(+A1@B1) -> transposed hi/lo planar ----------------
struct WDesc { const float* A0; const float* B0; const float* A1; const float* B1; short* Ch; short* Cl; };
struct WPack { WDesc d[10]; };

__global__ __launch_bounds__(256) void k_wprec(WPack p) {
  const WDesc d = p.d[blockIdx.x >> 2];
  const int rt = blockIdx.x & 3;
  __shared__ float A_s[32 * 128];
  const int t = threadIdx.x;
  const int c = t & 127, rh = t >> 7;
  float acc[16];
#pragma unroll
  for (int i = 0; i < 16; ++i) acc[i] = 0.f;
  for (int pass = 0; pass < 2; ++pass) {
    const float* A = pass ? d.A1 : d.A0;
    const float* B = pass ? d.B1 : d.B0;
    if (!A) break;
    __syncthreads();
#pragma unroll
    for (int j = 0; j < 4; ++j) {
      int f = t + 256 * j;
      *(float4*)(A_s + 4 * f) = *(const float4*)(A + (size_t)rt * 32 * 128 + 4 * f);
    }
    __syncthreads();
    for (int k = 0; k < 128; ++k) {
      float b = B[(size_t)k * 128 + c];
#pragma unroll
      for (int i = 0; i < 16; ++i)
        acc[i] += A_s[(rh + 2 * i) * 128 + k] * b;
    }
  }
#pragma unroll
  for (int i = 0; i < 16; ++i) {
    int k = rt * 32 + rh + 2 * i;
    float v = acc[i];
    short hi = f2bf_rne(v);
    short lo = f2bf_rne(v - bfhi_f(hi));
    d.Ch[(size_t)c * 128 + k] = hi;
    d.Cl[(size_t)c * 128 + k] = lo;
  }
}

// ---------------- combined bias ----------------
__global__ __launch_bounds__(256) void k_bias(const float* __restrict__ bn,
                                              const float* __restrict__ bs,
                                              const float* __restrict__ bu,
                                              const float* __restrict__ Wu,
                                              float* __restrict__ cbA, float* __restrict__ cbB) {
  int t = threadIdx.x;
  int h = t & 127;
  if (t < 128) {
    float acc = bu[0 * 128 + h] + bu[2 * 128 + h];
    for (int j = 0; j < 128; ++j) {
      acc += bn[0 * 128 + j] * Wu[(size_t)0 * 32768 + (size_t)j * 128 + h];
      acc += bs[0 * 128 + j] * Wu[(size_t)0 * 32768 + 16384 + (size_t)j * 128 + h];
      acc += bn[2 * 128 + j] * Wu[(size_t)2 * 32768 + (size_t)j * 128 + h];
      acc += bs[2 * 128 + j] * Wu[(size_t)2 * 32768 + 16384 + (size_t)j * 128 + h];
    }
    cbA[h] = acc;
  } else {
    float acc = bu[128 + h];
    for (int j = 0; j < 128; ++j) {
      acc += bn[128 + j] * Wu[(size_t)1 * 32768 + (size_t)j * 128 + h];
      acc += bs[128 + j] * Wu[(size_t)1 * 32768 + 16384 + (size_t)j * 128 + h];
    }
    cbB[h] = acc;
  }
}

// ---------------- split-bf16 MFMA multi-term matmul ----------------
// Terms 0..NT-2: interleaved u32 aggr buffers (s0, s1). Term NT-1: planar
// self term (selfHi/selfLo). MODE 0: f32 out (outv). MODE 1: dropout+relu ->
// hi/lo planes (outv=hi, outv2=lo); in-place safe per 128-row block.
template <int NT, int MODE>
__global__ __launch_bounds__(256, 2) void k_mmx(
    const uint32_t* __restrict__ s0, const uint32_t* __restrict__ s1,
    const short* __restrict__ selfHi, const short* __restrict__ selfLo,
    const short* __restrict__ w0h, const short* __restrict__ w0l,
    const short* __restrict__ w1h, const short* __restrict__ w1l,
    const short* __restrict__ w2h, const short* __restrict__ w2l,
    const float* __restrict__ bias, void* __restrict__ outv, void* __restrict__ outv2,
    int n, uint32_t k0, uint32_t k1) {
  __shared__ short A_s[128 * 72];   // [row][32hi|32lo|8pad] shorts, 144B stride
  __shared__ short W_s[128 * 72];
  const int t = threadIdx.x;
  const int r0 = blockIdx.x * 128;
  const int lane = t & 63;
  const int w = t >> 6;
  const int wr = w >> 1, wc = w & 1;
  const int lr = lane & 15, lg = lane >> 4;
  const int sr = t >> 1, sh = t & 1;
  const int rr = min(r0 + sr, n - 1);   // clamp staging rows

  f32x4 acc[4][4];
#pragma unroll
  for (int nf = 0; nf < 4; ++nf) {
    float bv = bias[wc * 64 + nf * 16 + lr];
#pragma unroll
    for (int mf = 0; mf < 4; ++mf) acc[mf][nf] = {bv, bv, bv, bv};
  }

#pragma unroll
  for (int term = 0; term < NT; ++term) {
    const short* wh = term == 0 ? w0h : (term == 1 ? w1h : w2h);
    const short* wl = term == 0 ? w0l : (term == 1 ? w1l : w2l);
    const short* wsrc = sh ? wl : wh;
    for (int ks = 0; ks < 4; ++ks) {
      __syncthreads();
      if (term == NT - 1) {
        // planar self term: straight copy, no unpack
        const short* pl = sh ? selfLo : selfHi;
        const uint4* gp = (const uint4*)(pl + (size_t)rr * 128 + ks * 32);
        uint4 b0 = gp[0], b1 = gp[1], b2 = gp[2], b3 = gp[3];
        uint4* la = (uint4*)(A_s + sr * 72 + sh * 32);
        la[0] = b0; la[1] = b1; la[2] = b2; la[3] = b3;
      } else {
        const uint32_t* src = term == 0 ? s0 : s1;
        const uint4* ga = (const uint4*)(src + (size_t)rr * 128 + ks * 32 + sh * 16);
        uint4 q0 = ga[0], q1 = ga[1], q2 = ga[2], q3 = ga[3];
        uint32_t h[8], l[8];
        pack2(q0.x, q0.y, h[0], l[0]); pack2(q0.z, q0.w, h[1], l[1]);
        pack2(q1.x, q1.y, h[2], l[2]); pack2(q1.z, q1.w, h[3], l[3]);
        pack2(q2.x, q2.y, h[4], l[4]); pack2(q2.z, q2.w, h[5], l[5]);
        pack2(q3.x, q3.y, h[6], l[6]); pack2(q3.z, q3.w, h[7], l[7]);
        uint4* Ah = (uint4*)(A_s + sr * 72 + sh * 16);
        uint4* Al = (uint4*)(A_s + sr * 72 + 32 + sh * 16);
        Ah[0] = make_uint4(h[0], h[1], h[2], h[3]);
        Ah[1] = make_uint4(h[4], h[5], h[6], h[7]);
        Al[0] = make_uint4(l[0], l[1], l[2], l[3]);
        Al[1] = make_uint4(l[4], l[5], l[6], l[7]);
      }
      { // W tile (planar source)
        const uint4* gw = (const uint4*)(wsrc + sr * 128 + ks * 32);
        uint4 b0 = gw[0], b1 = gw[1], b2 = gw[2], b3 = gw[3];
        uint4* lw = (uint4*)(W_s + sr * 72 + sh * 32);
        lw[0] = b0; lw[1] = b1; lw[2] = b2; lw[3] = b3;
      }
      __syncthreads();
      short8v whi[4], wlo[4];
#pragma unroll
      for (int nf = 0; nf < 4; ++nf) {
        int nc = wc * 64 + nf * 16 + lr;
        whi[nf] = *(const short8v*)(W_s + nc * 72 + lg * 8);
        wlo[nf] = *(const short8v*)(W_s + nc * 72 + 32 + lg * 8);
      }
#pragma unroll
      for (int mf = 0; mf < 4; ++mf) {
        int ar = wr * 64 + mf * 16 + lr;
        short8v ah = *(const short8v*)(A_s + ar * 72 + lg * 8);
        short8v al = *(const short8v*)(A_s + ar * 72 + 32 + lg * 8);
#pragma unroll
        for (int nf = 0; nf < 4; ++nf) {
          acc[mf][nf] = __builtin_amdgcn_mfma_f32_16x16x32_bf16(ah, whi[nf], acc[mf][nf], 0, 0, 0);
          acc[mf][nf] = __builtin_amdgcn_mfma_f32_16x16x32_bf16(ah, wlo[nf], acc[mf][nf], 0, 0, 0);
          acc[mf][nf] = __builtin_amdgcn_mfma_f32_16x16x32_bf16(al, whi[nf], acc[mf][nf], 0, 0, 0);
        }
      }
    }
  }

#pragma unroll
  for (int mf = 0; mf < 4; ++mf) {
#pragma unroll
    for (int r = 0; r < 4; ++r) {
      int g = r0 + wr * 64 + mf * 16 + lg * 4 + r;
      if (g >= n) continue;
#pragma unroll
      for (int nf = 0; nf < 4; ++nf) {
        int col = wc * 64 + nf * 16 + lr;
        float v = acc[mf][nf][r];
        if constexpr (MODE == 1) {
          uint32_t o0, o1;
          tf2x32(k0, k1, 0u, (uint32_t)(g * 128 + col), o0, o1);
          uint32_t bits = o0 ^ o1;
          float u = __uint_as_float((bits >> 9) | 0x3f800000u) - 1.0f;
          v = (u < 0.8f) ? (v / 0.8f) : 0.0f;
          v = fmaxf(v, 0.0f);
          short hi = f2bf_rne(v);
          short lo = f2bf_rne(v - bfhi_f(hi));
          ((short*)outv)[(size_t)g * 128 + col] = hi;
          ((short*)outv2)[(size_t)g * 128 + col] = lo;
        } else {
          __builtin_nontemporal_store(v, (float*)outv + (size_t)g * 128 + col);
        }
      }
    }
  }
}

// ---------------- host driver ----------------
extern "C" void kernel_launch(void* const* d_in, const int* in_sizes, int n_in,
                              void* d_out, int out_size, void* d_ws, size_t ws_size,
                              hipStream_t stream) {
  const float* xA  = (const float*)d_in[0];
  const float* xB  = (const float*)d_in[1];
  const int*   ei0 = (const int*)d_in[2];
  const int*   ei1 = (const int*)d_in[3];
  const int*   ei2 = (const int*)d_in[4];
  const float* Wn1 = (const float*)d_in[5];
  const float* Ws1 = (const float*)d_in[6];
  const float* Wu1 = (const float*)d_in[7];
  const float* Wn2 = (const float*)d_in[8];
  const float* Ws2 = (const float*)d_in[9];
  const float* Wu2 = (const float*)d_in[10];
  const float* bn1 = (const float*)d_in[11];
  const float* bs1 = (const float*)d_in[12];
  const float* bu1 = (const float*)d_in[13];
  const float* bn2 = (const float*)d_in[14];
  const float* bs2 = (const float*)d_in[15];
  const float* bu2 = (const float*)d_in[16];

  const int n  = in_sizes[0] / DIMF;        // 100000
  const int E  = in_sizes[2] / 2;           // 1600000
  const int n3 = 3 * n;
  const int nbk = (n3 + 511) >> BKT_SHIFT;  // 586
  const size_t nh = (size_t)n * DIMF;

  short* S = (short*)d_ws;
  short* hiA = S;                       // [nh] shorts
  short* loA = S + nh;
  short* hiB = S + 2 * nh;
  short* loB = S + 3 * nh;
  uint32_t* g1 = (uint32_t*)(S + 4 * nh);   // [nh] u32, ei1 aggr / p1o alias
  uint32_t* g2 = g1 + nh;                   // [nh] u32, ei2 aggr
  short* wtsS  = (short*)(g2 + nh);         // 10 x (16384 hi + 16384 lo)
  float* biasF = (float*)(wtsS + 10 * 32768);
  float* cbA1 = biasF, *cbB1 = biasF + 128, *cbA2 = biasF + 256, *cbB2 = biasF + 384;
  int* off  = (int*)(biasF + 512);          // [n3+1]
  int* bcnt = off + n3 + 1;                 // [BKT_MAX]
  int* boff = bcnt + BKT_MAX;               // [BKT_MAX+1]
  int* gcur = boff + BKT_MAX + 1;           // [BKT_MAX]
  int* srcl = gcur + BKT_MAX;               // [3E] plane word offsets
  uint32_t* p1o = g1;                       // 3E u32, used only before gathers
  uint32_t* g3  = (uint32_t*)d_out;         // ei0 aggr scratch: d_out[0..nh) dead
                                            // until final k_mmx (block-local in-place)

  size_t need_bytes = (size_t)4 * nh * sizeof(short)      // planes
                    + (size_t)2 * nh * sizeof(uint32_t)   // g1, g2
                    + (size_t)10 * 32768 * sizeof(short)
                    + 512 * sizeof(float)
                    + ((size_t)n3 + 1 + 3 * BKT_MAX + 1 + (size_t)3 * E) * sizeof(int)
                    + 65536;
  if (ws_size < need_bytes) {
    fprintf(stderr, "kernel_launch: ws too small (%zu < %zu)\n", ws_size, need_bytes);
    return;
  }

  // JAX keys: dk = split(key(42), 4) (partitionable threefry, verified round 2)
  uint32_t dk[4][2];
  for (uint32_t i = 0; i < 4; ++i) tf2x32(0u, 42u, 0u, i, dk[i][0], dk[i][1]);

  WPack pk;
  auto U = [](const float* Wu, int t) { return Wu + (size_t)t * 32768; };
  auto L = [](const float* Wu, int t) { return Wu + (size_t)t * 32768 + 16384; };
  auto WH = [&](int m) { return wtsS + (size_t)m * 32768; };
  auto WL = [&](int m) { return wtsS + (size_t)m * 32768 + 16384; };
  const size_t MS = 128 * 128;
  pk.d[0] = { Wn1 + 0 * MS, U(Wu1, 0), nullptr, nullptr, WH(0), WL(0) };
  pk.d[1] = { Wn1 + 1 * MS, U(Wu1, 1), nullptr, nullptr, WH(1), WL(1) };
  pk.d[2] = { Wn1 + 2 * MS, U(Wu1, 2), nullptr, nullptr, WH(2), WL(2) };
  pk.d[3] = { Ws1 + 0 * MS, L(Wu1, 0), Ws1 + 2 * MS, L(Wu1, 2), WH(3), WL(3) };
  pk.d[4] = { Ws1 + 1 * MS, L(Wu1, 1), nullptr, nullptr, WH(4), WL(4) };
  pk.d[5] = { Wn2 + 0 * MS, U(Wu2, 0), nullptr, nullptr, WH(5), WL(5) };
  pk.d[6] = { Wn2 + 1 * MS, U(Wu2, 1), nullptr, nullptr, WH(6), WL(6) };
  pk.d[7] = { Wn2 + 2 * MS, U(Wu2, 2), nullptr, nullptr, WH(7), WL(7) };
  pk.d[8] = { Ws2 + 0 * MS, L(Wu2, 0), Ws2 + 2 * MS, L(Wu2, 2), WH(8), WL(8) };
  pk.d[9] = { Ws2 + 1 * MS, L(Wu2, 1), nullptr, nullptr, WH(9), WL(9) };

  const int gdrop = (int)((nh / 2 + 255) / 256);
  const int gE8   = (E + P1_CHUNK - 1) / P1_CHUNK;
  const int gmm   = (n + 127) / 128;
  const int nwv   = (n3 + 1) / 2;                   // 2 dsts per wave
  const int gga3  = (nwv * 64 + 255) / 256;

  // ---- CSR build: 2-level bucket sort ----
  hipMemsetAsync(bcnt, 0, (size_t)nbk * sizeof(int), stream);
  k_bcount<<<3 * gE8, 256, 0, stream>>>(ei0, ei1, ei2, bcnt, E, n, gE8, nbk);
  k_bscan<<<1, 256, 0, stream>>>(bcnt, boff, gcur, off, nbk, n3);
  k_p1<<<3 * gE8, 256, 0, stream>>>(ei0, ei1, ei2, gcur, p1o, E, n, gE8, nbk);
  k_p2<<<nbk, 256, 0, stream>>>(p1o, boff, off, srcl, n3);

  // ---- weights / biases ----
  k_wprec<<<40, 256, 0, stream>>>(pk);
  k_bias<<<1, 256, 0, stream>>>(bn1, bs1, bu1, Wu1, cbA1, cbB1);
  k_bias<<<1, 256, 0, stream>>>(bn2, bs2, bu2, Wu2, cbA2, cbB2);

  // ---- input dropout+relu -> planes ----
  k_drop_in<<<gdrop, 256, 0, stream>>>(xA, (uint32_t*)hiA, (uint32_t*)loA,
                                       (int)(nh / 2), dk[0][0], dk[0][1]);
  k_drop_in<<<gdrop, 256, 0, stream>>>(xB, (uint32_t*)hiB, (uint32_t*)loB,
                                       (int)(nh / 2), dk[1][0], dk[1][1]);

  // ---- layer 1 ----
  k_gather3<<<gga3, 256, 0, stream>>>((const uint32_t*)hiA, (const uint32_t*)hiB,
                                      g1, g2, g3, off, srcl, n);
  k_mmx<2, 1><<<gmm, 256, 0, stream>>>(g1, nullptr, hiB, loB,
                                       WH(1), WL(1), WH(4), WL(4), nullptr, nullptr,
                                       cbB1, hiB, loB, n, dk[3][0], dk[3][1]);  // h2B in place
  k_mmx<3, 1><<<gmm, 256, 0, stream>>>(g3, g2, hiA, loA,
                                       WH(0), WL(0), WH(2), WL(2), WH(3), WL(3),
                                       cbA1, hiA, loA, n, dk[2][0], dk[2][1]);  // h2A in place

  // ---- layer 2 ----
  float* oA = (float*)d_out;
  float* oB = oA + nh;
  k_gather3<<<gga3, 256, 0, stream>>>((const uint32_t*)hiA, (const uint32_t*)hiB,
                                      g1, g2, g3, off, srcl, n);
  k_mmx<2, 0><<<gmm, 256, 0, stream>>>(g1, nullptr, hiB, loB,
                                       WH(6), WL(6), WH(9), WL(9), nullptr, nullptr,
                                       cbB2, oB, nullptr, n, 0u, 0u);
  k_mmx<3, 0><<<gmm, 256, 0, stream>>>(g3, g2, hiA, loA,
                                       WH(5), WL(5), WH(7), WL(7), WH(8), WL(8),
                                       cbA2, oA, nullptr, n, 0u, 0u);  // in-place over g3
}

// Round 11
// 838.760 us; speedup vs baseline: 1.4761x; 1.1323x over previous
//
#include <hip/hip_runtime.h>
#include <cstdint>
#include <cstdio>

#define DIMF 128
#define BKT_SHIFT 9        // 512 dsts per bucket
#define BKT_MAX 1024       // supports n3 <= 524288
#define P1_CHUNK 8192      // edges per p1 block
#define P1_CAP 16384       // padded slots per bucket (mean 8192, sigma ~90)
#define P2_CAP 12288       // LDS image capacity

typedef __attribute__((ext_vector_type(8))) short short8v;
typedef __attribute__((ext_vector_type(4))) float f32x4;
typedef __attribute__((ext_vector_type(4))) unsigned int u32x4;

// Feature format: SPLIT PLANES. hiX/loX[n*128] shorts; x ~= hi + lo.
// Gather reads hi plane only (output error ~1e-5 vs 6e-4 threshold; verified
// r10: absmax unchanged). Gather outputs g: interleaved u32 (hi | lo<<16).
// srcl stores u32-plane word offsets (src * 64).

// ---------------- JAX threefry2x32 (exact) ----------------
__host__ __device__ __forceinline__ void tf2x32(uint32_t k0, uint32_t k1,
                                                uint32_t x0, uint32_t x1,
                                                uint32_t& o0, uint32_t& o1) {
  uint32_t ks2 = k0 ^ k1 ^ 0x1BD11BDAu;
  x0 += k0; x1 += k1;
#define TFR(r) { x0 += x1; x1 = (x1 << (r)) | (x1 >> (32 - (r))); x1 ^= x0; }
  TFR(13) TFR(15) TFR(26) TFR(6)
  x0 += k1;  x1 += ks2 + 1u;
  TFR(17) TFR(29) TFR(16) TFR(24)
  x0 += ks2; x1 += k0 + 2u;
  TFR(13) TFR(15) TFR(26) TFR(6)
  x0 += k0;  x1 += k1 + 3u;
  TFR(17) TFR(29) TFR(16) TFR(24)
  x0 += k1;  x1 += ks2 + 4u;
  TFR(13) TFR(15) TFR(26) TFR(6)
  x0 += ks2; x1 += k0 + 5u;
#undef TFR
  o0 = x0; o1 = x1;
}

__device__ __forceinline__ short f2bf_rne(float x) {
  uint32_t u = __float_as_uint(x);
  uint32_t r = (u + 0x7FFFu + ((u >> 16) & 1u)) >> 16;
  return (short)r;
}
__device__ __forceinline__ float bfhi_f(short h) {
  return __uint_as_float(((uint32_t)(uint16_t)h) << 16);
}
__device__ __forceinline__ uint32_t pack_hl(float v) {
  short hi = f2bf_rne(v);
  short lo = f2bf_rne(v - bfhi_f(hi));
  return (uint32_t)(uint16_t)hi | ((uint32_t)(uint16_t)lo << 16);
}
__device__ __forceinline__ void unpk2(uint32_t w, float& f0, float& f1) {
  f0 = __uint_as_float(w << 16);
  f1 = __uint_as_float(w & 0xFFFF0000u);
}
__device__ __forceinline__ void pack2(uint32_t we, uint32_t wo, uint32_t& h, uint32_t& l) {
  h = (we & 0xFFFFu) | (wo << 16);
  l = (we >> 16) | (wo & 0xFFFF0000u);
}

// ---------------- input dropout(0.2)+relu -> hi/lo planes, both node types ----------------
__global__ __launch_bounds__(256) void k_drop2(const float* __restrict__ xA,
                                               const float* __restrict__ xB,
                                               uint32_t* __restrict__ hiA, uint32_t* __restrict__ loA,
                                               uint32_t* __restrict__ hiB, uint32_t* __restrict__ loB,
                                               int npair, int gdrop,
                                               uint32_t ka0, uint32_t ka1,
                                               uint32_t kb0, uint32_t kb1) {
  int isB = blockIdx.x >= gdrop;
  int p = (blockIdx.x - (isB ? gdrop : 0)) * 256 + threadIdx.x;
  if (p >= npair) return;
  const float* in = isB ? xB : xA;
  uint32_t* hiP = isB ? hiB : hiA;
  uint32_t* loP = isB ? loB : loA;
  uint32_t k0 = isB ? kb0 : ka0, k1 = isB ? kb1 : ka1;
  int row = p >> 6, w = p & 63;
  int c2 = w * 2;
  float2 x = *(const float2*)(in + (size_t)row * 128 + c2);
  uint32_t idx = (uint32_t)(row * 128 + c2);
  float v[2] = {x.x, x.y};
  uint32_t hw = 0, lw = 0;
#pragma unroll
  for (int q = 0; q < 2; ++q) {
    uint32_t o0, o1;
    tf2x32(k0, k1, 0u, idx + q, o0, o1);
    uint32_t bits = o0 ^ o1;
    float u = __uint_as_float((bits >> 9) | 0x3f800000u) - 1.0f;
    float y = (u < 0.8f) ? (v[q] / 0.8f) : 0.0f;
    y = fmaxf(y, 0.0f);
    short hi = f2bf_rne(y);
    short lo = f2bf_rne(y - bfhi_f(hi));
    hw |= (uint32_t)(uint16_t)hi << (16 * q);
    lw |= (uint32_t)(uint16_t)lo << (16 * q);
  }
  hiP[(size_t)row * 64 + w] = hw;
  loP[(size_t)row * 64 + w] = lw;
}

// ---------------- CSR build: padded-bucket sort (no count pass) ----------------
__global__ __launch_bounds__(256) void k_ginit(int* __restrict__ gcur, int nbk) {
  for (int i = threadIdx.x; i < nbk; i += 256) gcur[i] = i * P1_CAP;
}

// phase 1: scatter packed (src | localdst<<20) into per-block runs inside
// each bucket's padded region.
__global__ __launch_bounds__(256) void k_p1(const int* __restrict__ ei0,
                                            const int* __restrict__ ei1,
                                            const int* __restrict__ ei2,
                                            int* __restrict__ gcur,
                                            uint32_t* __restrict__ p1o,
                                            int E, int n, int gE8, int nbk) {
  __shared__ int hist[BKT_MAX];
  __shared__ int cur[BKT_MAX];
  int t = threadIdx.x;
  int type = blockIdx.x / gE8;
  int chunk = blockIdx.x - type * gE8;
  const int* ei = type == 0 ? ei0 : (type == 1 ? ei1 : ei2);
  int base = chunk * P1_CHUNK;
  int dof = type * n;
  for (int i = t; i < nbk; i += 256) hist[i] = 0;
  __syncthreads();
  int sv[P1_CHUNK / 256];
  int dv[P1_CHUNK / 256];
#pragma unroll
  for (int j = 0; j < P1_CHUNK / 256; ++j) {
    int e = base + j * 256 + t;
    if (e < E) { sv[j] = ei[e]; dv[j] = ei[E + e] + dof; }
    else dv[j] = -1;
  }
#pragma unroll
  for (int j = 0; j < P1_CHUNK / 256; ++j)
    if (dv[j] >= 0) atomicAdd(&hist[dv[j] >> BKT_SHIFT], 1);
  __syncthreads();
  for (int i = t; i < nbk; i += 256) {
    int h = hist[i];
    if (h > 0) cur[i] = atomicAdd(&gcur[i], h);
  }
  __syncthreads();
#pragma unroll
  for (int j = 0; j < P1_CHUNK / 256; ++j) {
    if (dv[j] >= 0) {
      int bkt = dv[j] >> BKT_SHIFT;
      int pos = atomicAdd(&cur[bkt], 1);
      p1o[pos] = (uint32_t)sv[j] | ((uint32_t)(dv[j] & 511) << 20);
    }
  }
}

// scan bucket sizes (gcur[b] - b*CAP) -> boff; grand total -> off[n3]
__global__ __launch_bounds__(256) void k_bscan2(const int* __restrict__ gcur,
                                                int* __restrict__ boff,
                                                int* __restrict__ off,
                                                int nbk, int n3) {
  __shared__ int ts[256];
  int t = threadIdx.x;
  int base = t * 4;
  int v[4];
#pragma unroll
  for (int i = 0; i < 4; ++i)
    v[i] = (base + i < nbk) ? (gcur[base + i] - (base + i) * P1_CAP) : 0;
  ts[t] = v[0] + v[1] + v[2] + v[3];
  __syncthreads();
  for (int ofs = 1; ofs < 256; ofs <<= 1) {
    int x = ts[t];
    int y = (t >= ofs) ? ts[t - ofs] : 0;
    __syncthreads();
    ts[t] = x + y;
    __syncthreads();
  }
  int run = (t == 0) ? 0 : ts[t - 1];
#pragma unroll
  for (int i = 0; i < 4; ++i) {
    if (base + i < nbk) boff[base + i] = run;
    run += v[i];
  }
  if (t == 255) { boff[nbk] = ts[255]; off[n3] = ts[255]; }
}

// phase 2: counting sort within bucket (LDS); read padded region, write off[]
// + compacted coalesced srcl (u32-plane word offsets, src*64).
__global__ __launch_bounds__(256) void k_p2(const uint32_t* __restrict__ p1o,
                                            const int* __restrict__ boff,
                                            int* __restrict__ off,
                                            int* __restrict__ srcl, int n3) {
  __shared__ int cnt_l[512];
  __shared__ int off_l[512];
  __shared__ int cur_l[512];
  __shared__ int ts[256];
  __shared__ int img[P2_CAP];
  int b = blockIdx.x;
  int t = threadIdx.x;
  int fb = boff[b];                  // final srcl base
  int sz = boff[b + 1] - fb;
  size_t pb = (size_t)b * P1_CAP;    // padded region base
  int d0 = b << BKT_SHIFT;
  cnt_l[t] = 0; cnt_l[t + 256] = 0;
  __syncthreads();
  for (int i = t; i < sz; i += 256)
    atomicAdd(&cnt_l[p1o[pb + i] >> 20], 1);
  __syncthreads();
  int c0 = cnt_l[2 * t], c1 = cnt_l[2 * t + 1];
  ts[t] = c0 + c1;
  __syncthreads();
  for (int ofs = 1; ofs < 256; ofs <<= 1) {
    int x = ts[t];
    int y = (t >= ofs) ? ts[t - ofs] : 0;
    __syncthreads();
    ts[t] = x + y;
    __syncthreads();
  }
  int ebase = (t == 0) ? 0 : ts[t - 1];
  off_l[2 * t] = ebase; off_l[2 * t + 1] = ebase + c0;
  cur_l[2 * t] = ebase; cur_l[2 * t + 1] = ebase + c0;
  __syncthreads();
  for (int j = t; j < 512; j += 256) {
    int d = d0 + j;
    if (d < n3) off[d] = fb + off_l[j];
  }
  if (sz <= P2_CAP) {
    for (int i = t; i < sz; i += 256) {
      uint32_t w = p1o[pb + i];
      int pos = atomicAdd(&cur_l[w >> 20], 1);
      img[pos] = (int)(w & 0xFFFFFu) << 6;
    }
    __syncthreads();
    for (int i = t; i < sz; i += 256) srcl[fb + i] = img[i];
  } else {  // statistically unreachable
    for (int i = t; i < sz; i += 256) {
      uint32_t w = p1o[pb + i];
      int pos = atomicAdd(&cur_l[w >> 20], 1);
      srcl[fb + pos] = (int)(w & 0xFFFFFu) << 6;
    }
  }
}

// ---------------- CSR gather-mean over HI PLANE: 32 lanes/dst, 2 dsts/wave ----------------
__device__ __forceinline__ void gather_one32(const uint32_t* __restrict__ hiP,
                                             const int* __restrict__ off,
                                             const int* __restrict__ srcl,
                                             uint32_t* __restrict__ out,
                                             int d, int lane) {
  int b = off[d], e = off[d + 1];
  const int c2 = lane * 2;
  float a0 = 0.f, a1 = 0.f, a2 = 0.f, a3 = 0.f;
  float b0 = 0.f, b1 = 0.f, b2 = 0.f, b3 = 0.f;
  float c0 = 0.f, c1 = 0.f, c2f = 0.f, c3 = 0.f;
  float e0 = 0.f, e1 = 0.f, e2 = 0.f, e3 = 0.f;
  float t0, t1;
  int j = b;
  for (; j + 3 < e; j += 4) {
    int o0 = __builtin_nontemporal_load(srcl + j);
    int o1 = __builtin_nontemporal_load(srcl + j + 1);
    int o2 = __builtin_nontemporal_load(srcl + j + 2);
    int o3 = __builtin_nontemporal_load(srcl + j + 3);
    uint2 w0 = *(const uint2*)(hiP + (size_t)(o0 + c2));
    uint2 w1 = *(const uint2*)(hiP + (size_t)(o1 + c2));
    uint2 w2 = *(const uint2*)(hiP + (size_t)(o2 + c2));
    uint2 w3 = *(const uint2*)(hiP + (size_t)(o3 + c2));
    unpk2(w0.x, t0, t1); a0 += t0; a1 += t1;
    unpk2(w0.y, t0, t1); a2 += t0; a3 += t1;
    unpk2(w1.x, t0, t1); b0 += t0; b1 += t1;
    unpk2(w1.y, t0, t1); b2 += t0; b3 += t1;
    unpk2(w2.x, t0, t1); c0 += t0; c1 += t1;
    unpk2(w2.y, t0, t1); c2f += t0; c3 += t1;
    unpk2(w3.x, t0, t1); e0 += t0; e1 += t1;
    unpk2(w3.y, t0, t1); e2 += t0; e3 += t1;
  }
  for (; j < e; ++j) {
    int o = __builtin_nontemporal_load(srcl + j);
    uint2 w = *(const uint2*)(hiP + (size_t)(o + c2));
    unpk2(w.x, t0, t1); a0 += t0; a1 += t1;
    unpk2(w.y, t0, t1); a2 += t0; a3 += t1;
  }
  float sc = 1.0f / (float)max(e - b, 1);
  float v0 = ((a0 + b0) + (c0 + e0)) * sc;
  float v1 = ((a1 + b1) + (c1 + e1)) * sc;
  float v2 = ((a2 + b2) + (c2f + e2)) * sc;
  float v3 = ((a3 + b3) + (c3 + e3)) * sc;
  u32x4 r = {pack_hl(v0), pack_hl(v1), pack_hl(v2), pack_hl(v3)};
  __builtin_nontemporal_store(r, (u32x4*)(out + (size_t)d * 128 + lane * 4));
}

__global__ __launch_bounds__(256) void k_gather3(
    const uint32_t* __restrict__ hiA, const uint32_t* __restrict__ hiB,
    uint32_t* __restrict__ g1, uint32_t* __restrict__ g2, uint32_t* __restrict__ g3,
    const int* __restrict__ off, const int* __restrict__ srcl, int n) {
  int wv = (blockIdx.x * 256 + threadIdx.x) >> 6;
  int half = (threadIdx.x >> 5) & 1;
  int lane = threadIdx.x & 31;
  int d = wv * 2 + half;
  if (d >= 3 * n) return;
  if (d < n)          gather_one32(hiA, off + n,     srcl, g1, d,         lane);  // ei1: A->B
  else if (d < 2 * n) gather_one32(hiB, off + 2 * n, srcl, g2, d - n,     lane);  // ei2: B->A
  else                gather_one32(hiA, off,         srcl, g3, d - 2 * n, lane);  // ei0: A->A
}

// ---------------- combined-weight precompute ----------------
struct WDesc { const float* A0; const float* B0; const float* A1; const float* B1; short* Ch; short* Cl; };
struct WPack { WDesc d[10]; };

__global__ __launch_bounds__(256) void k_wprec(WPack p) {
  const WDesc d = p.d[blockIdx.x >> 2];
  const int rt = blockIdx.x & 3;
  __shared__ float A_s[32 * 128];
  const int t = threadIdx.x;
  const int c = t & 127, rh = t >> 7;
  float acc[16];
#pragma unroll
  for (int i = 0; i < 16; ++i) acc[i] = 0.f;
  for (int pass = 0; pass < 2; ++pass) {
    const float* A = pass ? d.A1 : d.A0;
    const float* B = pass ? d.B1 : d.B0;
    if (!A) break;
    __syncthreads();
#pragma unroll
    for (int j = 0; j < 4; ++j) {
      int f = t + 256 * j;
      *(float4*)(A_s + 4 * f) = *(const float4*)(A + (size_t)rt * 32 * 128 + 4 * f);
    }
    __syncthreads();
    for (int k = 0; k < 128; ++k) {
      float b = B[(size_t)k * 128 + c];
#pragma unroll
      for (int i = 0; i < 16; ++i)
        acc[i] += A_s[(rh + 2 * i) * 128 + k] * b;
    }
  }
#pragma unroll
  for (int i = 0; i < 16; ++i) {
    int k = rt * 32 + rh + 2 * i;
    float v = acc[i];
    short hi = f2bf_rne(v);
    short lo = f2bf_rne(v - bfhi_f(hi));
    d.Ch[(size_t)c * 128 + k] = hi;
    d.Cl[(size_t)c * 128 + k] = lo;
  }
}

// ---------------- combined bias, both layers in one dispatch ----------------
__global__ __launch_bounds__(256) void k_bias2(const float* __restrict__ bn1,
                                               const float* __restrict__ bs1,
                                               const float* __restrict__ bu1,
                                               const float* __restrict__ Wu1,
                                               const float* __restrict__ bn2,
                                               const float* __restrict__ bs2,
                                               const float* __restrict__ bu2,
                                               const float* __restrict__ Wu2,
                                               float* __restrict__ cbA1, float* __restrict__ cbB1,
                                               float* __restrict__ cbA2, float* __restrict__ cbB2) {
  const float* bn = blockIdx.x ? bn2 : bn1;
  const float* bs = blockIdx.x ? bs2 : bs1;
  const float* bu = blockIdx.x ? bu2 : bu1;
  const float* Wu = blockIdx.x ? Wu2 : Wu1;
  float* cbA = blockIdx.x ? cbA2 : cbA1;
  float* cbB = blockIdx.x ? cbB2 : cbB1;
  int t = threadIdx.x;
  int h = t & 127;
  if (t < 128) {
    float acc = bu[0 * 128 + h] + bu[2 * 128 + h];
    for (int j = 0; j < 128; ++j) {
      acc += bn[0 * 128 + j] * Wu[(size_t)0 * 32768 + (size_t)j * 128 + h];
      acc += bs[0 * 128 + j] * Wu[(size_t)0 * 32768 + 16384 + (size_t)j * 128 + h];
      acc += bn[2 * 128 + j] * Wu[(size_t)2 * 32768 + (size_t)j * 128 + h];
      acc += bs[2 * 128 + j] * Wu[(size_t)2 * 32768 + 16384 + (size_t)j * 128 + h];
    }
    cbA[h] = acc;
  } else {
    float acc = bu[128 + h];
    for (int j = 0; j < 128; ++j) {
      acc += bn[128 + j] * Wu[(size_t)1 * 32768 + (size_t)j * 128 + h];
      acc += bs[128 + j] * Wu[(size_t)1 * 32768 + 16384 + (size_t)j * 128 + h];
    }
    cbB[h] = acc;
  }
}

// ---------------- split-bf16 MFMA multi-term matmul: A-job + B-job fused ----------------
struct MMJob {
  const uint32_t* s0; const uint32_t* s1;   // interleaved aggr terms
  const short* selfHi; const short* selfLo; // planar self term (last)
  const short* w0h; const short* w0l;
  const short* w1h; const short* w1l;
  const short* w2h; const short* w2l;
  const float* bias;
  void* out; void* out2;
  int nt;
  uint32_t k0, k1;
};

template <int MODE>
__global__ __launch_bounds__(256, 2) void k_mmx2(MMJob JA, MMJob JB, int gA, int n) {
  __shared__ short A_s[128 * 72];   // [row][32hi|32lo|8pad] shorts
  __shared__ short W_s[128 * 72];
  MMJob j;
  int bid;
  if (blockIdx.x < (unsigned)gA) { j = JA; bid = blockIdx.x; }
  else                           { j = JB; bid = blockIdx.x - gA; }
  const int t = threadIdx.x;
  const int r0 = bid * 128;
  const int lane = t & 63;
  const int w = t >> 6;
  const int wr = w >> 1, wc = w & 1;
  const int lr = lane & 15, lg = lane >> 4;
  const int sr = t >> 1, sh = t & 1;
  const int rr = min(r0 + sr, n - 1);

  f32x4 acc[4][4];
#pragma unroll
  for (int nf = 0; nf < 4; ++nf) {
    float bv = j.bias[wc * 64 + nf * 16 + lr];
#pragma unroll
    for (int mf = 0; mf < 4; ++mf) acc[mf][nf] = {bv, bv, bv, bv};
  }

  for (int term = 0; term < j.nt; ++term) {
    const short* wh = term == 0 ? j.w0h : (term == 1 ? j.w1h : j.w2h);
    const short* wl = term == 0 ? j.w0l : (term == 1 ? j.w1l : j.w2l);
    const short* wsrc = sh ? wl : wh;
    const bool isSelf = (term == j.nt - 1);
    const uint32_t* src = term == 0 ? j.s0 : j.s1;
    for (int ks = 0; ks < 4; ++ks) {
      __syncthreads();
      if (isSelf) {
        const short* pl = sh ? j.selfLo : j.selfHi;
        const uint4* gp = (const uint4*)(pl + (size_t)rr * 128 + ks * 32);
        uint4 b0 = gp[0], b1 = gp[1], b2 = gp[2], b3 = gp[3];
        uint4* la = (uint4*)(A_s + sr * 72 + sh * 32);
        la[0] = b0; la[1] = b1; la[2] = b2; la[3] = b3;
      } else {
        const uint4* ga = (const uint4*)(src + (size_t)rr * 128 + ks * 32 + sh * 16);
        uint4 q0 = ga[0], q1 = ga[1], q2 = ga[2], q3 = ga[3];
        uint32_t h[8], l[8];
        pack2(q0.x, q0.y, h[0], l[0]); pack2(q0.z, q0.w, h[1], l[1]);
        pack2(q1.x, q1.y, h[2], l[2]); pack2(q1.z, q1.w, h[3], l[3]);
        pack2(q2.x, q2.y, h[4], l[4]); pack2(q2.z, q2.w, h[5], l[5]);
        pack2(q3.x, q3.y, h[6], l[6]); pack2(q3.z, q3.w, h[7], l[7]);
        uint4* Ah = (uint4*)(A_s + sr * 72 + sh * 16);
        uint4* Al = (uint4*)(A_s + sr * 72 + 32 + sh * 16);
        Ah[0] = make_uint4(h[0], h[1], h[2], h[3]);
        Ah[1] = make_uint4(h[4], h[5], h[6], h[7]);
        Al[0] = make_uint4(l[0], l[1], l[2], l[3]);
        Al[1] = make_uint4(l[4], l[5], l[6], l[7]);
      }
      {
        const uint4* gw = (const uint4*)(wsrc + sr * 128 + ks * 32);
        uint4 b0 = gw[0], b1 = gw[1], b2 = gw[2], b3 = gw[3];
        uint4* lw = (uint4*)(W_s + sr * 72 + sh * 32);
        lw[0] = b0; lw[1] = b1; lw[2] = b2; lw[3] = b3;
      }
      __syncthreads();
      short8v whi[4], wlo[4];
#pragma unroll
      for (int nf = 0; nf < 4; ++nf) {
        int nc = wc * 64 + nf * 16 + lr;
        whi[nf] = *(const short8v*)(W_s + nc * 72 + lg * 8);
        wlo[nf] = *(const short8v*)(W_s + nc * 72 + 32 + lg * 8);
      }
#pragma unroll
      for (int mf = 0; mf < 4; ++mf) {
        int ar = wr * 64 + mf * 16 + lr;
        short8v ah = *(const short8v*)(A_s + ar * 72 + lg * 8);
        short8v al = *(const short8v*)(A_s + ar * 72 + 32 + lg * 8);
#pragma unroll
        for (int nf = 0; nf < 4; ++nf) {
          acc[mf][nf] = __builtin_amdgcn_mfma_f32_16x16x32_bf16(ah, whi[nf], acc[mf][nf], 0, 0, 0);
          acc[mf][nf] = __builtin_amdgcn_mfma_f32_16x16x32_bf16(ah, wlo[nf], acc[mf][nf], 0, 0, 0);
          acc[mf][nf] = __builtin_amdgcn_mfma_f32_16x16x32_bf16(al, whi[nf], acc[mf][nf], 0, 0, 0);
        }
      }
    }
  }

#pragma unroll
  for (int mf = 0; mf < 4; ++mf) {
#pragma unroll
    for (int r = 0; r < 4; ++r) {
      int g = r0 + wr * 64 + mf * 16 + lg * 4 + r;
      if (g >= n) continue;
#pragma unroll
      for (int nf = 0; nf < 4; ++nf) {
        int col = wc * 64 + nf * 16 + lr;
        float v = acc[mf][nf][r];
        if constexpr (MODE == 1) {
          uint32_t o0, o1;
          tf2x32(j.k0, j.k1, 0u, (uint32_t)(g * 128 + col), o0, o1);
          uint32_t bits = o0 ^ o1;
          float u = __uint_as_float((bits >> 9) | 0x3f800000u) - 1.0f;
          v = (u < 0.8f) ? (v / 0.8f) : 0.0f;
          v = fmaxf(v, 0.0f);
          short hi = f2bf_rne(v);
          short lo = f2bf_rne(v - bfhi_f(hi));
          ((short*)j.out)[(size_t)g * 128 + col] = hi;
          ((short*)j.out2)[(size_t)g * 128 + col] = lo;
        } else {
          __builtin_nontemporal_store(v, (float*)j.out + (size_t)g * 128 + col);
        }
      }
    }
  }
}

// ---------------- host driver ----------------
extern "C" void kernel_launch(void* const* d_in, const int* in_sizes, int n_in,
                              void* d_out, int out_size, void* d_ws, size_t ws_size,
                              hipStream_t stream) {
  const float* xA  = (const float*)d_in[0];
  const float* xB  = (const float*)d_in[1];
  const int*   ei0 = (const int*)d_in[2];
  const int*   ei1 = (const int*)d_in[3];
  const int*   ei2 = (const int*)d_in[4];
  const float* Wn1 = (const float*)d_in[5];
  const float* Ws1 = (const float*)d_in[6];
  const float* Wu1 = (const float*)d_in[7];
  const float* Wn2 = (const float*)d_in[8];
  const float* Ws2 = (const float*)d_in[9];
  const float* Wu2 = (const float*)d_in[10];
  const float* bn1 = (const float*)d_in[11];
  const float* bs1 = (const float*)d_in[12];
  const float* bu1 = (const float*)d_in[13];
  const float* bn2 = (const float*)d_in[14];
  const float* bs2 = (const float*)d_in[15];
  const float* bu2 = (const float*)d_in[16];

  const int n  = in_sizes[0] / DIMF;        // 100000
  const int E  = in_sizes[2] / 2;           // 1600000
  const int n3 = 3 * n;
  const int nbk = (n3 + 511) >> BKT_SHIFT;  // 586
  const size_t nh = (size_t)n * DIMF;

  short* S = (short*)d_ws;
  short* hiA = S;                       // [nh] shorts
  short* loA = S + nh;
  short* hiB = S + 2 * nh;
  short* loB = S + 3 * nh;
  uint32_t* g1 = (uint32_t*)(S + 4 * nh);   // [nh] u32; also p1o alias
  uint32_t* g2 = g1 + nh;                   // [nh] u32
  short* wtsS  = (short*)(g2 + nh);         // 10 x (16384 hi + 16384 lo)
  float* biasF = (float*)(wtsS + 10 * 32768);
  float* cbA1 = biasF, *cbB1 = biasF + 128, *cbA2 = biasF + 256, *cbB2 = biasF + 384;
  int* off  = (int*)(biasF + 512);          // [n3+1]
  int* boff = off + n3 + 1;                 // [BKT_MAX+1]
  int* gcur = boff + BKT_MAX + 1;           // [BKT_MAX]
  int* srcl = gcur + BKT_MAX;               // [3E] plane word offsets
  uint32_t* p1o = g1;                       // nbk*P1_CAP u32 (38.4MB <= 51.2MB)
  uint32_t* g3  = (uint32_t*)d_out;         // ei0 aggr scratch (d_out[0..nh) dead
                                            // until final mmx, block-local in-place)

  size_t need_bytes = (size_t)4 * nh * sizeof(short)
                    + (size_t)2 * nh * sizeof(uint32_t)
                    + (size_t)10 * 32768 * sizeof(short)
                    + 512 * sizeof(float)
                    + ((size_t)n3 + 1 + 2 * BKT_MAX + 2 + (size_t)3 * E) * sizeof(int)
                    + 65536;
  if (ws_size < need_bytes) {
    fprintf(stderr, "kernel_launch: ws too small (%zu < %zu)\n", ws_size, need_bytes);
    return;
  }
  // p1o capacity check: nbk*P1_CAP u32 must fit in g1's nh u32
  if ((size_t)nbk * P1_CAP > nh) {
    fprintf(stderr, "kernel_launch: p1o overflow\n");
    return;
  }

  // JAX keys: dk = split(key(42), 4) (partitionable threefry, verified round 2)
  uint32_t dk[4][2];
  for (uint32_t i = 0; i < 4; ++i) tf2x32(0u, 42u, 0u, i, dk[i][0], dk[i][1]);

  WPack pk;
  auto U = [](const float* Wu, int t) { return Wu + (size_t)t * 32768; };
  auto L = [](const float* Wu, int t) { return Wu + (size_t)t * 32768 + 16384; };
  auto WH = [&](int m) { return wtsS + (size_t)m * 32768; };
  auto WL = [&](int m) { return wtsS + (size_t)m * 32768 + 16384; };
  const size_t MS = 128 * 128;
  pk.d[0] = { Wn1 + 0 * MS, U(Wu1, 0), nullptr, nullptr, WH(0), WL(0) };
  pk.d[1] = { Wn1 + 1 * MS, U(Wu1, 1), nullptr, nullptr, WH(1), WL(1) };
  pk.d[2] = { Wn1 + 2 * MS, U(Wu1, 2), nullptr, nullptr, WH(2), WL(2) };
  pk.d[3] = { Ws1 + 0 * MS, L(Wu1, 0), Ws1 + 2 * MS, L(Wu1, 2), WH(3), WL(3) };
  pk.d[4] = { Ws1 + 1 * MS, L(Wu1, 1), nullptr, nullptr, WH(4), WL(4) };
  pk.d[5] = { Wn2 + 0 * MS, U(Wu2, 0), nullptr, nullptr, WH(5), WL(5) };
  pk.d[6] = { Wn2 + 1 * MS, U(Wu2, 1), nullptr, nullptr, WH(6), WL(6) };
  pk.d[7] = { Wn2 + 2 * MS, U(Wu2, 2), nullptr, nullptr, WH(7), WL(7) };
  pk.d[8] = { Ws2 + 0 * MS, L(Wu2, 0), Ws2 + 2 * MS, L(Wu2, 2), WH(8), WL(8) };
  pk.d[9] = { Ws2 + 1 * MS, L(Wu2, 1), nullptr, nullptr, WH(9), WL(9) };

  const int gdrop = (int)((nh / 2 + 255) / 256);
  const int gE8   = (E + P1_CHUNK - 1) / P1_CHUNK;
  const int gmm   = (n + 127) / 128;
  const int nwv   = (n3 + 1) / 2;
  const int gga3  = (nwv * 64 + 255) / 256;

  // ---- CSR build: padded-bucket sort ----
  k_ginit<<<1, 256, 0, stream>>>(gcur, nbk);
  k_p1<<<3 * gE8, 256, 0, stream>>>(ei0, ei1, ei2, gcur, p1o, E, n, gE8, nbk);
  k_bscan2<<<1, 256, 0, stream>>>(gcur, boff, off, nbk, n3);
  k_p2<<<nbk, 256, 0, stream>>>(p1o, boff, off, srcl, n3);

  // ---- weights / biases ----
  k_wprec<<<40, 256, 0, stream>>>(pk);
  k_bias2<<<2, 256, 0, stream>>>(bn1, bs1, bu1, Wu1, bn2, bs2, bu2, Wu2,
                                 cbA1, cbB1, cbA2, cbB2);

  // ---- input dropout+relu -> planes (both types, one dispatch) ----
  k_drop2<<<2 * gdrop, 256, 0, stream>>>(xA, xB, (uint32_t*)hiA, (uint32_t*)loA,
                                         (uint32_t*)hiB, (uint32_t*)loB,
                                         (int)(nh / 2), gdrop,
                                         dk[0][0], dk[0][1], dk[1][0], dk[1][1]);

  // ---- layer 1 ----
  k_gather3<<<gga3, 256, 0, stream>>>((const uint32_t*)hiA, (const uint32_t*)hiB,
                                      g1, g2, g3, off, srcl, n);
  {
    MMJob JA = { g3, g2, hiA, loA, WH(0), WL(0), WH(2), WL(2), WH(3), WL(3),
                 cbA1, hiA, loA, 3, dk[2][0], dk[2][1] };
    MMJob JB = { g1, nullptr, hiB, loB, WH(1), WL(1), WH(4), WL(4), nullptr, nullptr,
                 cbB1, hiB, loB, 2, dk[3][0], dk[3][1] };
    k_mmx2<1><<<2 * gmm, 256, 0, stream>>>(JA, JB, gmm, n);
  }

  // ---- layer 2 ----
  float* oA = (float*)d_out;
  float* oB = oA + nh;
  k_gather3<<<gga3, 256, 0, stream>>>((const uint32_t*)hiA, (const uint32_t*)hiB,
                                      g1, g2, g3, off, srcl, n);
  {
    MMJob JA = { g3, g2, hiA, loA, WH(5), WL(5), WH(7), WL(7), WH(8), WL(8),
                 cbA2, oA, nullptr, 3, 0u, 0u };
    MMJob JB = { g1, nullptr, hiB, loB, WH(6), WL(6), WH(9), WL(9), nullptr, nullptr,
                 cbB2, oB, nullptr, 2, 0u, 0u };
    k_mmx2<0><<<2 * gmm, 256, 0, stream>>>(JA, JB, gmm, n);
  }
}

// Round 12
// 802.040 us; speedup vs baseline: 1.5436x; 1.0458x over previous
//
#include <hip/hip_runtime.h>
#include <cstdint>
#include <cstdio>

#define DIMF 128
#define BKT_SHIFT 9        // 512 dsts per bucket
#define BKT_MAX 1024       // supports n3 <= 524288
#define P1_CHUNK 8192      // edges per p1 block
#define P1_CAP 16384       // padded slots per bucket (mean 8192, sigma ~90)
#define P2_CAP 12288       // LDS image capacity

typedef __attribute__((ext_vector_type(8))) short short8v;
typedef __attribute__((ext_vector_type(4))) short short4v;
typedef __attribute__((ext_vector_type(4))) float f32x4;

// Feature planes: hiX/loX[n*128] bf16 shorts; x ~= hi + lo (~2^-17 rel).
// Gather reads hi plane only and writes SINGLE bf16 plane g (mean rounded to
// bf16; added output error ~e-5 vs 6e-4 threshold). Self terms in mmx use
// both planes (full split precision). srcl stores hi-plane u32 word offsets
// (src * 64).

// ---------------- JAX threefry2x32 (exact) ----------------
__host__ __device__ __forceinline__ void tf2x32(uint32_t k0, uint32_t k1,
                                                uint32_t x0, uint32_t x1,
                                                uint32_t& o0, uint32_t& o1) {
  uint32_t ks2 = k0 ^ k1 ^ 0x1BD11BDAu;
  x0 += k0; x1 += k1;
#define TFR(r) { x0 += x1; x1 = (x1 << (r)) | (x1 >> (32 - (r))); x1 ^= x0; }
  TFR(13) TFR(15) TFR(26) TFR(6)
  x0 += k1;  x1 += ks2 + 1u;
  TFR(17) TFR(29) TFR(16) TFR(24)
  x0 += ks2; x1 += k0 + 2u;
  TFR(13) TFR(15) TFR(26) TFR(6)
  x0 += k0;  x1 += k1 + 3u;
  TFR(17) TFR(29) TFR(16) TFR(24)
  x0 += k1;  x1 += ks2 + 4u;
  TFR(13) TFR(15) TFR(26) TFR(6)
  x0 += ks2; x1 += k0 + 5u;
#undef TFR
  o0 = x0; o1 = x1;
}

__device__ __forceinline__ short f2bf_rne(float x) {
  uint32_t u = __float_as_uint(x);
  uint32_t r = (u + 0x7FFFu + ((u >> 16) & 1u)) >> 16;
  return (short)r;
}
__device__ __forceinline__ float bfhi_f(short h) {
  return __uint_as_float(((uint32_t)(uint16_t)h) << 16);
}
__device__ __forceinline__ void unpk2(uint32_t w, float& f0, float& f1) {
  f0 = __uint_as_float(w << 16);
  f1 = __uint_as_float(w & 0xFFFF0000u);
}

// ---------------- input dropout(0.2)+relu -> hi/lo planes, both node types ----------------
__global__ __launch_bounds__(256) void k_drop2(const float* __restrict__ xA,
                                               const float* __restrict__ xB,
                                               uint32_t* __restrict__ hiA, uint32_t* __restrict__ loA,
                                               uint32_t* __restrict__ hiB, uint32_t* __restrict__ loB,
                                               int npair, int gdrop,
                                               uint32_t ka0, uint32_t ka1,
                                               uint32_t kb0, uint32_t kb1) {
  int isB = blockIdx.x >= gdrop;
  int p = (blockIdx.x - (isB ? gdrop : 0)) * 256 + threadIdx.x;
  if (p >= npair) return;
  const float* in = isB ? xB : xA;
  uint32_t* hiP = isB ? hiB : hiA;
  uint32_t* loP = isB ? loB : loA;
  uint32_t k0 = isB ? kb0 : ka0, k1 = isB ? kb1 : ka1;
  int row = p >> 6, w = p & 63;
  int c2 = w * 2;
  float2 x = *(const float2*)(in + (size_t)row * 128 + c2);
  uint32_t idx = (uint32_t)(row * 128 + c2);
  float v[2] = {x.x, x.y};
  uint32_t hw = 0, lw = 0;
#pragma unroll
  for (int q = 0; q < 2; ++q) {
    uint32_t o0, o1;
    tf2x32(k0, k1, 0u, idx + q, o0, o1);
    uint32_t bits = o0 ^ o1;
    float u = __uint_as_float((bits >> 9) | 0x3f800000u) - 1.0f;
    float y = (u < 0.8f) ? (v[q] / 0.8f) : 0.0f;
    y = fmaxf(y, 0.0f);
    short hi = f2bf_rne(y);
    short lo = f2bf_rne(y - bfhi_f(hi));
    hw |= (uint32_t)(uint16_t)hi << (16 * q);
    lw |= (uint32_t)(uint16_t)lo << (16 * q);
  }
  hiP[(size_t)row * 64 + w] = hw;
  loP[(size_t)row * 64 + w] = lw;
}

// ---------------- CSR build: padded-bucket sort (no count pass) ----------------
__global__ __launch_bounds__(256) void k_ginit(int* __restrict__ gcur, int nbk) {
  for (int i = threadIdx.x; i < nbk; i += 256) gcur[i] = i * P1_CAP;
}

__global__ __launch_bounds__(256) void k_p1(const int* __restrict__ ei0,
                                            const int* __restrict__ ei1,
                                            const int* __restrict__ ei2,
                                            int* __restrict__ gcur,
                                            uint32_t* __restrict__ p1o,
                                            int E, int n, int gE8, int nbk) {
  __shared__ int hist[BKT_MAX];
  __shared__ int cur[BKT_MAX];
  int t = threadIdx.x;
  int type = blockIdx.x / gE8;
  int chunk = blockIdx.x - type * gE8;
  const int* ei = type == 0 ? ei0 : (type == 1 ? ei1 : ei2);
  int base = chunk * P1_CHUNK;
  int dof = type * n;
  for (int i = t; i < nbk; i += 256) hist[i] = 0;
  __syncthreads();
  int sv[P1_CHUNK / 256];
  int dv[P1_CHUNK / 256];
#pragma unroll
  for (int j = 0; j < P1_CHUNK / 256; ++j) {
    int e = base + j * 256 + t;
    if (e < E) { sv[j] = ei[e]; dv[j] = ei[E + e] + dof; }
    else dv[j] = -1;
  }
#pragma unroll
  for (int j = 0; j < P1_CHUNK / 256; ++j)
    if (dv[j] >= 0) atomicAdd(&hist[dv[j] >> BKT_SHIFT], 1);
  __syncthreads();
  for (int i = t; i < nbk; i += 256) {
    int h = hist[i];
    if (h > 0) cur[i] = atomicAdd(&gcur[i], h);
  }
  __syncthreads();
#pragma unroll
  for (int j = 0; j < P1_CHUNK / 256; ++j) {
    if (dv[j] >= 0) {
      int bkt = dv[j] >> BKT_SHIFT;
      int pos = atomicAdd(&cur[bkt], 1);
      p1o[pos] = (uint32_t)sv[j] | ((uint32_t)(dv[j] & 511) << 20);
    }
  }
}

__global__ __launch_bounds__(256) void k_bscan2(const int* __restrict__ gcur,
                                                int* __restrict__ boff,
                                                int* __restrict__ off,
                                                int nbk, int n3) {
  __shared__ int ts[256];
  int t = threadIdx.x;
  int base = t * 4;
  int v[4];
#pragma unroll
  for (int i = 0; i < 4; ++i)
    v[i] = (base + i < nbk) ? (gcur[base + i] - (base + i) * P1_CAP) : 0;
  ts[t] = v[0] + v[1] + v[2] + v[3];
  __syncthreads();
  for (int ofs = 1; ofs < 256; ofs <<= 1) {
    int x = ts[t];
    int y = (t >= ofs) ? ts[t - ofs] : 0;
    __syncthreads();
    ts[t] = x + y;
    __syncthreads();
  }
  int run = (t == 0) ? 0 : ts[t - 1];
#pragma unroll
  for (int i = 0; i < 4; ++i) {
    if (base + i < nbk) boff[base + i] = run;
    run += v[i];
  }
  if (t == 255) { boff[nbk] = ts[255]; off[n3] = ts[255]; }
}

__global__ __launch_bounds__(256) void k_p2(const uint32_t* __restrict__ p1o,
                                            const int* __restrict__ boff,
                                            int* __restrict__ off,
                                            int* __restrict__ srcl, int n3) {
  __shared__ int cnt_l[512];
  __shared__ int off_l[512];
  __shared__ int cur_l[512];
  __shared__ int ts[256];
  __shared__ int img[P2_CAP];
  int b = blockIdx.x;
  int t = threadIdx.x;
  int fb = boff[b];
  int sz = boff[b + 1] - fb;
  size_t pb = (size_t)b * P1_CAP;
  int d0 = b << BKT_SHIFT;
  cnt_l[t] = 0; cnt_l[t + 256] = 0;
  __syncthreads();
  for (int i = t; i < sz; i += 256)
    atomicAdd(&cnt_l[p1o[pb + i] >> 20], 1);
  __syncthreads();
  int c0 = cnt_l[2 * t], c1 = cnt_l[2 * t + 1];
  ts[t] = c0 + c1;
  __syncthreads();
  for (int ofs = 1; ofs < 256; ofs <<= 1) {
    int x = ts[t];
    int y = (t >= ofs) ? ts[t - ofs] : 0;
    __syncthreads();
    ts[t] = x + y;
    __syncthreads();
  }
  int ebase = (t == 0) ? 0 : ts[t - 1];
  off_l[2 * t] = ebase; off_l[2 * t + 1] = ebase + c0;
  cur_l[2 * t] = ebase; cur_l[2 * t + 1] = ebase + c0;
  __syncthreads();
  for (int j = t; j < 512; j += 256) {
    int d = d0 + j;
    if (d < n3) off[d] = fb + off_l[j];
  }
  if (sz <= P2_CAP) {
    for (int i = t; i < sz; i += 256) {
      uint32_t w = p1o[pb + i];
      int pos = atomicAdd(&cur_l[w >> 20], 1);
      img[pos] = (int)(w & 0xFFFFFu) << 6;
    }
    __syncthreads();
    for (int i = t; i < sz; i += 256) srcl[fb + i] = img[i];
  } else {
    for (int i = t; i < sz; i += 256) {
      uint32_t w = p1o[pb + i];
      int pos = atomicAdd(&cur_l[w >> 20], 1);
      srcl[fb + pos] = (int)(w & 0xFFFFFu) << 6;
    }
  }
}

// ---------------- CSR gather-mean over HI PLANE -> bf16 plane out ----------------
__device__ __forceinline__ void gather_one32(const uint32_t* __restrict__ hiP,
                                             const int* __restrict__ off,
                                             const int* __restrict__ srcl,
                                             short* __restrict__ out,
                                             int d, int lane) {
  int b = off[d], e = off[d + 1];
  const int c2 = lane * 2;
  float a0 = 0.f, a1 = 0.f, a2 = 0.f, a3 = 0.f;
  float b0 = 0.f, b1 = 0.f, b2 = 0.f, b3 = 0.f;
  float c0 = 0.f, c1 = 0.f, c2f = 0.f, c3 = 0.f;
  float e0 = 0.f, e1 = 0.f, e2 = 0.f, e3 = 0.f;
  float t0, t1;
  int j = b;
  for (; j + 3 < e; j += 4) {
    int o0 = __builtin_nontemporal_load(srcl + j);
    int o1 = __builtin_nontemporal_load(srcl + j + 1);
    int o2 = __builtin_nontemporal_load(srcl + j + 2);
    int o3 = __builtin_nontemporal_load(srcl + j + 3);
    uint2 w0 = *(const uint2*)(hiP + (size_t)(o0 + c2));
    uint2 w1 = *(const uint2*)(hiP + (size_t)(o1 + c2));
    uint2 w2 = *(const uint2*)(hiP + (size_t)(o2 + c2));
    uint2 w3 = *(const uint2*)(hiP + (size_t)(o3 + c2));
    unpk2(w0.x, t0, t1); a0 += t0; a1 += t1;
    unpk2(w0.y, t0, t1); a2 += t0; a3 += t1;
    unpk2(w1.x, t0, t1); b0 += t0; b1 += t1;
    unpk2(w1.y, t0, t1); b2 += t0; b3 += t1;
    unpk2(w2.x, t0, t1); c0 += t0; c1 += t1;
    unpk2(w2.y, t0, t1); c2f += t0; c3 += t1;
    unpk2(w3.x, t0, t1); e0 += t0; e1 += t1;
    unpk2(w3.y, t0, t1); e2 += t0; e3 += t1;
  }
  for (; j < e; ++j) {
    int o = __builtin_nontemporal_load(srcl + j);
    uint2 w = *(const uint2*)(hiP + (size_t)(o + c2));
    unpk2(w.x, t0, t1); a0 += t0; a1 += t1;
    unpk2(w.y, t0, t1); a2 += t0; a3 += t1;
  }
  float sc = 1.0f / (float)max(e - b, 1);
  short4v r = { f2bf_rne(((a0 + b0) + (c0 + e0)) * sc),
                f2bf_rne(((a1 + b1) + (c1 + e1)) * sc),
                f2bf_rne(((a2 + b2) + (c2f + e2)) * sc),
                f2bf_rne(((a3 + b3) + (c3 + e3)) * sc) };
  __builtin_nontemporal_store(r, (short4v*)(out + (size_t)d * 128 + lane * 4));
}

__global__ __launch_bounds__(256) void k_gather3(
    const uint32_t* __restrict__ hiA, const uint32_t* __restrict__ hiB,
    short* __restrict__ g1, short* __restrict__ g2, short* __restrict__ g3,
    const int* __restrict__ off, const int* __restrict__ srcl, int n) {
  int wv = (blockIdx.x * 256 + threadIdx.x) >> 6;
  int half = (threadIdx.x >> 5) & 1;
  int lane = threadIdx.x & 31;
  int d = wv * 2 + half;
  if (d >= 3 * n) return;
  if (d < n)          gather_one32(hiA, off + n,     srcl, g1, d,         lane);  // ei1: A->B
  else if (d < 2 * n) gather_one32(hiB, off + 2 * n, srcl, g2, d - n,     lane);  // ei2: B->A
  else                gather_one32(hiA, off,         srcl, g3, d - 2 * n, lane);  // ei0: A->A
}

// ---------------- combined-weight precompute ----------------
struct WDesc { const float* A0; const float* B0; const float* A1; const float* B1; short* Ch; short* Cl; };
struct WPack { WDesc d[10]; };

__global__ __launch_bounds__(256) void k_wprec(WPack p) {
  const WDesc d = p.d[blockIdx.x >> 2];
  const int rt = blockIdx.x & 3;
  __shared__ float A_s[32 * 128];
  const int t = threadIdx.x;
  const int c = t & 127, rh = t >> 7;
  float acc[16];
#pragma unroll
  for (int i = 0; i < 16; ++i) acc[i] = 0.f;
  for (int pass = 0; pass < 2; ++pass) {
    const float* A = pass ? d.A1 : d.A0;
    const float* B = pass ? d.B1 : d.B0;
    if (!A) break;
    __syncthreads();
#pragma unroll
    for (int j = 0; j < 4; ++j) {
      int f = t + 256 * j;
      *(float4*)(A_s + 4 * f) = *(const float4*)(A + (size_t)rt * 32 * 128 + 4 * f);
    }
    __syncthreads();
    for (int k = 0; k < 128; ++k) {
      float b = B[(size_t)k * 128 + c];
#pragma unroll
      for (int i = 0; i < 16; ++i)
        acc[i] += A_s[(rh + 2 * i) * 128 + k] * b;
    }
  }
#pragma unroll
  for (int i = 0; i < 16; ++i) {
    int k = rt * 32 + rh + 2 * i;
    float v = acc[i];
    short hi = f2bf_rne(v);
    short lo = f2bf_rne(v - bfhi_f(hi));
    d.Ch[(size_t)c * 128 + k] = hi;
    d.Cl[(size_t)c * 128 + k] = lo;
  }
}

// ---------------- combined bias, both layers in one dispatch ----------------
__global__ __launch_bounds__(256) void k_bias2(const float* __restrict__ bn1,
                                               const float* __restrict__ bs1,
                                               const float* __restrict__ bu1,
                                               const float* __restrict__ Wu1,
                                               const float* __restrict__ bn2,
                                               const float* __restrict__ bs2,
                                               const float* __restrict__ bu2,
                                               const float* __restrict__ Wu2,
                                               float* __restrict__ cbA1, float* __restrict__ cbB1,
                                               float* __restrict__ cbA2, float* __restrict__ cbB2) {
  const float* bn = blockIdx.x ? bn2 : bn1;
  const float* bs = blockIdx.x ? bs2 : bs1;
  const float* bu = blockIdx.x ? bu2 : bu1;
  const float* Wu = blockIdx.x ? Wu2 : Wu1;
  float* cbA = blockIdx.x ? cbA2 : cbA1;
  float* cbB = blockIdx.x ? cbB2 : cbB1;
  int t = threadIdx.x;
  int h = t & 127;
  if (t < 128) {
    float acc = bu[0 * 128 + h] + bu[2 * 128 + h];
    for (int j = 0; j < 128; ++j) {
      acc += bn[0 * 128 + j] * Wu[(size_t)0 * 32768 + (size_t)j * 128 + h];
      acc += bs[0 * 128 + j] * Wu[(size_t)0 * 32768 + 16384 + (size_t)j * 128 + h];
      acc += bn[2 * 128 + j] * Wu[(size_t)2 * 32768 + (size_t)j * 128 + h];
      acc += bs[2 * 128 + j] * Wu[(size_t)2 * 32768 + 16384 + (size_t)j * 128 + h];
    }
    cbA[h] = acc;
  } else {
    float acc = bu[128 + h];
    for (int j = 0; j < 128; ++j) {
      acc += bn[128 + j] * Wu[(size_t)1 * 32768 + (size_t)j * 128 + h];
      acc += bs[128 + j] * Wu[(size_t)1 * 32768 + 16384 + (size_t)j * 128 + h];
    }
    cbB[h] = acc;
  }
}

// ---------------- split-bf16 MFMA multi-term matmul: A-job + B-job fused ----------------
// Aggr terms (0..nt-2): single bf16 plane, 2 MFMAs (ah*whi + ah*wlo).
// Self term (nt-1): hi/lo planes, 3 MFMAs (ah*whi + ah*wlo + al*whi).
struct MMJob {
  const short* s0; const short* s1;         // bf16 aggr planes
  const short* selfHi; const short* selfLo; // planar self term (last)
  const short* w0h; const short* w0l;
  const short* w1h; const short* w1l;
  const short* w2h; const short* w2l;
  const float* bias;
  void* out; void* out2;
  int nt;
  uint32_t k0, k1;
};

template <int MODE>
__global__ __launch_bounds__(256, 2) void k_mmx2(MMJob JA, MMJob JB, int gA, int n) {
  __shared__ short A_s[128 * 72];   // [row][32hi|32lo|8pad] shorts
  __shared__ short W_s[128 * 72];
  MMJob j;
  int bid;
  if (blockIdx.x < (unsigned)gA) { j = JA; bid = blockIdx.x; }
  else                           { j = JB; bid = blockIdx.x - gA; }
  const int t = threadIdx.x;
  const int r0 = bid * 128;
  const int lane = t & 63;
  const int w = t >> 6;
  const int wr = w >> 1, wc = w & 1;
  const int lr = lane & 15, lg = lane >> 4;
  const int sr = t >> 1, sh = t & 1;
  const int rr = min(r0 + sr, n - 1);

  f32x4 acc[4][4];
#pragma unroll
  for (int nf = 0; nf < 4; ++nf) {
    float bv = j.bias[wc * 64 + nf * 16 + lr];
#pragma unroll
    for (int mf = 0; mf < 4; ++mf) acc[mf][nf] = {bv, bv, bv, bv};
  }

  for (int term = 0; term < j.nt; ++term) {
    const short* wh = term == 0 ? j.w0h : (term == 1 ? j.w1h : j.w2h);
    const short* wl = term == 0 ? j.w0l : (term == 1 ? j.w1l : j.w2l);
    const short* wsrc = sh ? wl : wh;
    const bool isSelf = (term == j.nt - 1);
    const short* src = term == 0 ? j.s0 : j.s1;
    for (int ks = 0; ks < 4; ++ks) {
      __syncthreads();
      if (isSelf) {
        const short* pl = sh ? j.selfLo : j.selfHi;
        const uint4* gp = (const uint4*)(pl + (size_t)rr * 128 + ks * 32);
        uint4 b0 = gp[0], b1 = gp[1], b2 = gp[2], b3 = gp[3];
        uint4* la = (uint4*)(A_s + sr * 72 + sh * 32);
        la[0] = b0; la[1] = b1; la[2] = b2; la[3] = b3;
      } else {
        // bf16 plane: 32 shorts/row-slice; each (sr,sh) copies 16 shorts
        const uint4* ga = (const uint4*)(src + (size_t)rr * 128 + ks * 32 + sh * 16);
        uint4 q0 = ga[0], q1 = ga[1];
        uint4* Ah = (uint4*)(A_s + sr * 72 + sh * 16);
        Ah[0] = q0; Ah[1] = q1;
      }
      {
        const uint4* gw = (const uint4*)(wsrc + sr * 128 + ks * 32);
        uint4 b0 = gw[0], b1 = gw[1], b2 = gw[2], b3 = gw[3];
        uint4* lw = (uint4*)(W_s + sr * 72 + sh * 32);
        lw[0] = b0; lw[1] = b1; lw[2] = b2; lw[3] = b3;
      }
      __syncthreads();
      short8v whi[4], wlo[4];
#pragma unroll
      for (int nf = 0; nf < 4; ++nf) {
        int nc = wc * 64 + nf * 16 + lr;
        whi[nf] = *(const short8v*)(W_s + nc * 72 + lg * 8);
        wlo[nf] = *(const short8v*)(W_s + nc * 72 + 32 + lg * 8);
      }
#pragma unroll
      for (int mf = 0; mf < 4; ++mf) {
        int ar = wr * 64 + mf * 16 + lr;
        short8v ah = *(const short8v*)(A_s + ar * 72 + lg * 8);
        if (isSelf) {
          short8v al = *(const short8v*)(A_s + ar * 72 + 32 + lg * 8);
#pragma unroll
          for (int nf = 0; nf < 4; ++nf) {
            acc[mf][nf] = __builtin_amdgcn_mfma_f32_16x16x32_bf16(ah, whi[nf], acc[mf][nf], 0, 0, 0);
            acc[mf][nf] = __builtin_amdgcn_mfma_f32_16x16x32_bf16(ah, wlo[nf], acc[mf][nf], 0, 0, 0);
            acc[mf][nf] = __builtin_amdgcn_mfma_f32_16x16x32_bf16(al, whi[nf], acc[mf][nf], 0, 0, 0);
          }
        } else {
#pragma unroll
          for (int nf = 0; nf < 4; ++nf) {
            acc[mf][nf] = __builtin_amdgcn_mfma_f32_16x16x32_bf16(ah, whi[nf], acc[mf][nf], 0, 0, 0);
            acc[mf][nf] = __builtin_amdgcn_mfma_f32_16x16x32_bf16(ah, wlo[nf], acc[mf][nf], 0, 0, 0);
          }
        }
      }
    }
  }

#pragma unroll
  for (int mf = 0; mf < 4; ++mf) {
#pragma unroll
    for (int r = 0; r < 4; ++r) {
      int g = r0 + wr * 64 + mf * 16 + lg * 4 + r;
      if (g >= n) continue;
#pragma unroll
      for (int nf = 0; nf < 4; ++nf) {
        int col = wc * 64 + nf * 16 + lr;
        float v = acc[mf][nf][r];
        if constexpr (MODE == 1) {
          uint32_t o0, o1;
          tf2x32(j.k0, j.k1, 0u, (uint32_t)(g * 128 + col), o0, o1);
          uint32_t bits = o0 ^ o1;
          float u = __uint_as_float((bits >> 9) | 0x3f800000u) - 1.0f;
          v = (u < 0.8f) ? (v / 0.8f) : 0.0f;
          v = fmaxf(v, 0.0f);
          short hi = f2bf_rne(v);
          short lo = f2bf_rne(v - bfhi_f(hi));
          ((short*)j.out)[(size_t)g * 128 + col] = hi;
          ((short*)j.out2)[(size_t)g * 128 + col] = lo;
        } else {
          __builtin_nontemporal_store(v, (float*)j.out + (size_t)g * 128 + col);
        }
      }
    }
  }
}

// ---------------- host driver ----------------
extern "C" void kernel_launch(void* const* d_in, const int* in_sizes, int n_in,
                              void* d_out, int out_size, void* d_ws, size_t ws_size,
                              hipStream_t stream) {
  const float* xA  = (const float*)d_in[0];
  const float* xB  = (const float*)d_in[1];
  const int*   ei0 = (const int*)d_in[2];
  const int*   ei1 = (const int*)d_in[3];
  const int*   ei2 = (const int*)d_in[4];
  const float* Wn1 = (const float*)d_in[5];
  const float* Ws1 = (const float*)d_in[6];
  const float* Wu1 = (const float*)d_in[7];
  const float* Wn2 = (const float*)d_in[8];
  const float* Ws2 = (const float*)d_in[9];
  const float* Wu2 = (const float*)d_in[10];
  const float* bn1 = (const float*)d_in[11];
  const float* bs1 = (const float*)d_in[12];
  const float* bu1 = (const float*)d_in[13];
  const float* bn2 = (const float*)d_in[14];
  const float* bs2 = (const float*)d_in[15];
  const float* bu2 = (const float*)d_in[16];

  const int n  = in_sizes[0] / DIMF;        // 100000
  const int E  = in_sizes[2] / 2;           // 1600000
  const int n3 = 3 * n;
  const int nbk = (n3 + 511) >> BKT_SHIFT;  // 586
  const size_t nh = (size_t)n * DIMF;

  short* S = (short*)d_ws;
  short* hiA = S;                       // [nh] shorts each
  short* loA = S + nh;
  short* hiB = S + 2 * nh;
  short* loB = S + 3 * nh;
  short* g1  = S + 4 * nh;              // bf16 aggr planes
  short* g2  = S + 5 * nh;
  short* g3  = S + 6 * nh;
  short* wtsS = S + 7 * nh;             // 10 x (16384 hi + 16384 lo)
  float* biasF = (float*)(wtsS + 10 * 32768);
  float* cbA1 = biasF, *cbB1 = biasF + 128, *cbA2 = biasF + 256, *cbB2 = biasF + 384;
  int* off  = (int*)(biasF + 512);          // [n3+1]
  int* boff = off + n3 + 1;                 // [BKT_MAX+1]
  int* gcur = boff + BKT_MAX + 1;           // [BKT_MAX]
  int* srcl = gcur + BKT_MAX;               // [3E] hi-plane word offsets
  uint32_t* p1o = (uint32_t*)g1;            // spans g1+g2: nh u32 >= nbk*P1_CAP

  size_t need_bytes = (size_t)7 * nh * sizeof(short)
                    + (size_t)10 * 32768 * sizeof(short)
                    + 512 * sizeof(float)
                    + ((size_t)n3 + 1 + 2 * BKT_MAX + 2 + (size_t)3 * E) * sizeof(int)
                    + 65536;
  if (ws_size < need_bytes) {
    fprintf(stderr, "kernel_launch: ws too small (%zu < %zu)\n", ws_size, need_bytes);
    return;
  }
  if ((size_t)nbk * P1_CAP > nh) {   // p1o must fit in g1+g2 (nh u32)
    fprintf(stderr, "kernel_launch: p1o overflow\n");
    return;
  }

  // JAX keys: dk = split(key(42), 4) (partitionable threefry, verified round 2)
  uint32_t dk[4][2];
  for (uint32_t i = 0; i < 4; ++i) tf2x32(0u, 42u, 0u, i, dk[i][0], dk[i][1]);

  WPack pk;
  auto U = [](const float* Wu, int t) { return Wu + (size_t)t * 32768; };
  auto L = [](const float* Wu, int t) { return Wu + (size_t)t * 32768 + 16384; };
  auto WH = [&](int m) { return wtsS + (size_t)m * 32768; };
  auto WL = [&](int m) { return wtsS + (size_t)m * 32768 + 16384; };
  const size_t MS = 128 * 128;
  pk.d[0] = { Wn1 + 0 * MS, U(Wu1, 0), nullptr, nullptr, WH(0), WL(0) };
  pk.d[1] = { Wn1 + 1 * MS, U(Wu1, 1), nullptr, nullptr, WH(1), WL(1) };
  pk.d[2] = { Wn1 + 2 * MS, U(Wu1, 2), nullptr, nullptr, WH(2), WL(2) };
  pk.d[3] = { Ws1 + 0 * MS, L(Wu1, 0), Ws1 + 2 * MS, L(Wu1, 2), WH(3), WL(3) };
  pk.d[4] = { Ws1 + 1 * MS, L(Wu1, 1), nullptr, nullptr, WH(4), WL(4) };
  pk.d[5] = { Wn2 + 0 * MS, U(Wu2, 0), nullptr, nullptr, WH(5), WL(5) };
  pk.d[6] = { Wn2 + 1 * MS, U(Wu2, 1), nullptr, nullptr, WH(6), WL(6) };
  pk.d[7] = { Wn2 + 2 * MS, U(Wu2, 2), nullptr, nullptr, WH(7), WL(7) };
  pk.d[8] = { Ws2 + 0 * MS, L(Wu2, 0), Ws2 + 2 * MS, L(Wu2, 2), WH(8), WL(8) };
  pk.d[9] = { Ws2 + 1 * MS, L(Wu2, 1), nullptr, nullptr, WH(9), WL(9) };

  const int gdrop = (int)((nh / 2 + 255) / 256);
  const int gE8   = (E + P1_CHUNK - 1) / P1_CHUNK;
  const int gmm   = (n + 127) / 128;
  const int nwv   = (n3 + 1) / 2;
  const int gga3  = (nwv * 64 + 255) / 256;

  // ---- CSR build: padded-bucket sort (uses g1/g2 as scratch, pre-gather) ----
  k_ginit<<<1, 256, 0, stream>>>(gcur, nbk);
  k_p1<<<3 * gE8, 256, 0, stream>>>(ei0, ei1, ei2, gcur, p1o, E, n, gE8, nbk);
  k_bscan2<<<1, 256, 0, stream>>>(gcur, boff, off, nbk, n3);
  k_p2<<<nbk, 256, 0, stream>>>(p1o, boff, off, srcl, n3);

  // ---- weights / biases ----
  k_wprec<<<40, 256, 0, stream>>>(pk);
  k_bias2<<<2, 256, 0, stream>>>(bn1, bs1, bu1, Wu1, bn2, bs2, bu2, Wu2,
                                 cbA1, cbB1, cbA2, cbB2);

  // ---- input dropout+relu -> planes ----
  k_drop2<<<2 * gdrop, 256, 0, stream>>>(xA, xB, (uint32_t*)hiA, (uint32_t*)loA,
                                         (uint32_t*)hiB, (uint32_t*)loB,
                                         (int)(nh / 2), gdrop,
                                         dk[0][0], dk[0][1], dk[1][0], dk[1][1]);

  // ---- layer 1 ----
  k_gather3<<<gga3, 256, 0, stream>>>((const uint32_t*)hiA, (const uint32_t*)hiB,
                                      g1, g2, g3, off, srcl, n);
  {
    MMJob JA = { g3, g2, hiA, loA, WH(0), WL(0), WH(2), WL(2), WH(3), WL(3),
                 cbA1, hiA, loA, 3, dk[2][0], dk[2][1] };
    MMJob JB = { g1, nullptr, hiB, loB, WH(1), WL(1), WH(4), WL(4), nullptr, nullptr,
                 cbB1, hiB, loB, 2, dk[3][0], dk[3][1] };
    k_mmx2<1><<<2 * gmm, 256, 0, stream>>>(JA, JB, gmm, n);
  }

  // ---- layer 2 ----
  float* oA = (float*)d_out;
  float* oB = oA + nh;
  k_gather3<<<gga3, 256, 0, stream>>>((const uint32_t*)hiA, (const uint32_t*)hiB,
                                      g1, g2, g3, off, srcl, n);
  {
    MMJob JA = { g3, g2, hiA, loA, WH(5), WL(5), WH(7), WL(7), WH(8), WL(8),
                 cbA2, oA, nullptr, 3, 0u, 0u };
    MMJob JB = { g1, nullptr, hiB, loB, WH(6), WL(6), WH(9), WL(9), nullptr, nullptr,
                 cbB2, oB, nullptr, 2, 0u, 0u };
    k_mmx2<0><<<2 * gmm, 256, 0, stream>>>(JA, JB, gmm, n);
  }
}

// Round 13
// 722.264 us; speedup vs baseline: 1.7141x; 1.1105x over previous
//
#include <hip/hip_runtime.h>
#include <cstdint>
#include <cstdio>

#define DIMF 128
#define BKT_SHIFT 9        // 512 dsts per bucket
#define BKT_MAX 1024       // supports n3 <= 524288 (p2 scan supports nbk <= 768)
#define P1_CHUNK 8192      // edges per p1 block
#define P1_CAP 16384       // padded slots per bucket (mean 8192, sigma ~90)
#define P2_CAP 12288       // LDS image capacity

typedef __attribute__((ext_vector_type(8))) short short8v;
typedef __attribute__((ext_vector_type(4))) short short4v;
typedef __attribute__((ext_vector_type(4))) float f32x4;

// Feature planes: PLAIN bf16 [n*128] shorts everywhere (r12 showed absmax is
// insensitive to feature quantization; analysis: added error ~1e-4 max vs
// 6.05e-4 threshold). Weights stay SPLIT hi/lo bf16 (2 MFMAs per term).
// Gather reads plane, writes bf16 plane. srcl stores u32-word offsets (src*64).

// ---------------- JAX threefry2x32 (exact) ----------------
__host__ __device__ __forceinline__ void tf2x32(uint32_t k0, uint32_t k1,
                                                uint32_t x0, uint32_t x1,
                                                uint32_t& o0, uint32_t& o1) {
  uint32_t ks2 = k0 ^ k1 ^ 0x1BD11BDAu;
  x0 += k0; x1 += k1;
#define TFR(r) { x0 += x1; x1 = (x1 << (r)) | (x1 >> (32 - (r))); x1 ^= x0; }
  TFR(13) TFR(15) TFR(26) TFR(6)
  x0 += k1;  x1 += ks2 + 1u;
  TFR(17) TFR(29) TFR(16) TFR(24)
  x0 += ks2; x1 += k0 + 2u;
  TFR(13) TFR(15) TFR(26) TFR(6)
  x0 += k0;  x1 += k1 + 3u;
  TFR(17) TFR(29) TFR(16) TFR(24)
  x0 += k1;  x1 += ks2 + 4u;
  TFR(13) TFR(15) TFR(26) TFR(6)
  x0 += ks2; x1 += k0 + 5u;
#undef TFR
  o0 = x0; o1 = x1;
}

__device__ __forceinline__ short f2bf_rne(float x) {
  uint32_t u = __float_as_uint(x);
  uint32_t r = (u + 0x7FFFu + ((u >> 16) & 1u)) >> 16;
  return (short)r;
}
__device__ __forceinline__ float bfhi_f(short h) {
  return __uint_as_float(((uint32_t)(uint16_t)h) << 16);
}
__device__ __forceinline__ void unpk2(uint32_t w, float& f0, float& f1) {
  f0 = __uint_as_float(w << 16);
  f1 = __uint_as_float(w & 0xFFFF0000u);
}

// ---------------- combined-weight precompute (desc) ----------------
struct WDesc { const float* A0; const float* B0; const float* A1; const float* B1; short* Ch; short* Cl; };
struct WPack { WDesc d[10]; };

// ---------------- setup mega-kernel: wprec (blocks 0..39) | bias (40,41) | ginit (42) ----------------
__global__ __launch_bounds__(256) void k_setup(WPack p,
    const float* __restrict__ bn1, const float* __restrict__ bs1,
    const float* __restrict__ bu1, const float* __restrict__ Wu1,
    const float* __restrict__ bn2, const float* __restrict__ bs2,
    const float* __restrict__ bu2, const float* __restrict__ Wu2,
    float* __restrict__ cbA1, float* __restrict__ cbB1,
    float* __restrict__ cbA2, float* __restrict__ cbB2,
    int* __restrict__ gcur, int nbk) {
  __shared__ float A_s[32 * 128];
  const int bx = blockIdx.x;
  const int t = threadIdx.x;
  if (bx < 40) {
    const WDesc d = p.d[bx >> 2];
    const int rt = bx & 3;
    const int c = t & 127, rh = t >> 7;
    float acc[16];
#pragma unroll
    for (int i = 0; i < 16; ++i) acc[i] = 0.f;
    for (int pass = 0; pass < 2; ++pass) {
      const float* A = pass ? d.A1 : d.A0;
      const float* B = pass ? d.B1 : d.B0;
      if (!A) break;
      __syncthreads();
#pragma unroll
      for (int jj = 0; jj < 4; ++jj) {
        int f = t + 256 * jj;
        *(float4*)(A_s + 4 * f) = *(const float4*)(A + (size_t)rt * 32 * 128 + 4 * f);
      }
      __syncthreads();
      for (int k = 0; k < 128; ++k) {
        float b = B[(size_t)k * 128 + c];
#pragma unroll
        for (int i = 0; i < 16; ++i)
          acc[i] += A_s[(rh + 2 * i) * 128 + k] * b;
      }
    }
#pragma unroll
    for (int i = 0; i < 16; ++i) {
      int k = rt * 32 + rh + 2 * i;
      float v = acc[i];
      short hi = f2bf_rne(v);
      short lo = f2bf_rne(v - bfhi_f(hi));
      d.Ch[(size_t)c * 128 + k] = hi;
      d.Cl[(size_t)c * 128 + k] = lo;
    }
  } else if (bx < 42) {
    const int layer = bx - 40;
    const float* bn = layer ? bn2 : bn1;
    const float* bs = layer ? bs2 : bs1;
    const float* bu = layer ? bu2 : bu1;
    const float* Wu = layer ? Wu2 : Wu1;
    float* cbA = layer ? cbA2 : cbA1;
    float* cbB = layer ? cbB2 : cbB1;
    int h = t & 127;
    if (t < 128) {
      float acc = bu[0 * 128 + h] + bu[2 * 128 + h];
      for (int j = 0; j < 128; ++j) {
        acc += bn[0 * 128 + j] * Wu[(size_t)0 * 32768 + (size_t)j * 128 + h];
        acc += bs[0 * 128 + j] * Wu[(size_t)0 * 32768 + 16384 + (size_t)j * 128 + h];
        acc += bn[2 * 128 + j] * Wu[(size_t)2 * 32768 + (size_t)j * 128 + h];
        acc += bs[2 * 128 + j] * Wu[(size_t)2 * 32768 + 16384 + (size_t)j * 128 + h];
      }
      cbA[h] = acc;
    } else {
      float acc = bu[128 + h];
      for (int j = 0; j < 128; ++j) {
        acc += bn[128 + j] * Wu[(size_t)1 * 32768 + (size_t)j * 128 + h];
        acc += bs[128 + j] * Wu[(size_t)1 * 32768 + 16384 + (size_t)j * 128 + h];
      }
      cbB[h] = acc;
    }
  } else {
    for (int i = t; i < nbk; i += 256) gcur[i] = i * P1_CAP;
  }
}

// ---------------- p1 (padded-bucket scatter) fused with dropout ----------------
__global__ __launch_bounds__(256) void k_p1drop(
    const int* __restrict__ ei0, const int* __restrict__ ei1, const int* __restrict__ ei2,
    int* __restrict__ gcur, uint32_t* __restrict__ p1o,
    int E, int n, int gE8, int nbk,
    const float* __restrict__ xA, const float* __restrict__ xB,
    uint32_t* __restrict__ pA, uint32_t* __restrict__ pB,
    int npair, int gdrop,
    uint32_t ka0, uint32_t ka1, uint32_t kb0, uint32_t kb1) {
  __shared__ int hist[BKT_MAX];
  __shared__ int cur[BKT_MAX];
  const int t = threadIdx.x;
  if (blockIdx.x < (unsigned)(3 * gE8)) {
    // ---- p1 path ----
    int type = blockIdx.x / gE8;
    int chunk = blockIdx.x - type * gE8;
    const int* ei = type == 0 ? ei0 : (type == 1 ? ei1 : ei2);
    int base = chunk * P1_CHUNK;
    int dof = type * n;
    for (int i = t; i < nbk; i += 256) hist[i] = 0;
    __syncthreads();
    int sv[P1_CHUNK / 256];
    int dv[P1_CHUNK / 256];
#pragma unroll
    for (int j = 0; j < P1_CHUNK / 256; ++j) {
      int e = base + j * 256 + t;
      if (e < E) { sv[j] = ei[e]; dv[j] = ei[E + e] + dof; }
      else dv[j] = -1;
    }
#pragma unroll
    for (int j = 0; j < P1_CHUNK / 256; ++j)
      if (dv[j] >= 0) atomicAdd(&hist[dv[j] >> BKT_SHIFT], 1);
    __syncthreads();
    for (int i = t; i < nbk; i += 256) {
      int h = hist[i];
      if (h > 0) cur[i] = atomicAdd(&gcur[i], h);
    }
    __syncthreads();
#pragma unroll
    for (int j = 0; j < P1_CHUNK / 256; ++j) {
      if (dv[j] >= 0) {
        int bkt = dv[j] >> BKT_SHIFT;
        int pos = atomicAdd(&cur[bkt], 1);
        p1o[pos] = (uint32_t)sv[j] | ((uint32_t)(dv[j] & 511) << 20);
      }
    }
  } else {
    // ---- dropout+relu path -> bf16 plane ----
    int bd = blockIdx.x - 3 * gE8;
    int isB = bd >= gdrop;
    int p = (bd - (isB ? gdrop : 0)) * 256 + t;
    if (p >= npair) return;
    const float* in = isB ? xB : xA;
    uint32_t* plane = isB ? pB : pA;
    uint32_t k0 = isB ? kb0 : ka0, k1 = isB ? kb1 : ka1;
    int row = p >> 6, w = p & 63;
    int c2 = w * 2;
    float2 x = *(const float2*)(in + (size_t)row * 128 + c2);
    uint32_t idx = (uint32_t)(row * 128 + c2);
    float v[2] = {x.x, x.y};
    uint32_t hw = 0;
#pragma unroll
    for (int q = 0; q < 2; ++q) {
      uint32_t o0, o1;
      tf2x32(k0, k1, 0u, idx + q, o0, o1);
      uint32_t bits = o0 ^ o1;
      float u = __uint_as_float((bits >> 9) | 0x3f800000u) - 1.0f;
      float y = (u < 0.8f) ? (v[q] / 0.8f) : 0.0f;
      y = fmaxf(y, 0.0f);
      hw |= (uint32_t)(uint16_t)f2bf_rne(y) << (16 * q);
    }
    plane[(size_t)row * 64 + w] = hw;
  }
}

// ---------------- p2: self-prefix + counting sort within bucket ----------------
__global__ __launch_bounds__(256) void k_p2(const uint32_t* __restrict__ p1o,
                                            const int* __restrict__ gcur,
                                            int* __restrict__ off,
                                            int* __restrict__ srcl,
                                            int nbk, int n3) {
  __shared__ int redA[256];
  __shared__ int redB[256];
  __shared__ int sh_szb;
  __shared__ int cnt_l[512];
  __shared__ int off_l[512];
  __shared__ int cur_l[512];
  __shared__ int ts[256];
  __shared__ int img[P2_CAP];
  const int b = blockIdx.x;
  const int t = threadIdx.x;
  // bucket sizes: s_i = gcur[i] - i*P1_CAP; need fb = sum_{i<b}, sz = s_b, tot
  {
    int t3 = t * 3;
    int s0 = 0, s1 = 0, s2 = 0;
    if (t3     < nbk) s0 = gcur[t3]     - t3 * P1_CAP;
    if (t3 + 1 < nbk) s1 = gcur[t3 + 1] - (t3 + 1) * P1_CAP;
    if (t3 + 2 < nbk) s2 = gcur[t3 + 2] - (t3 + 2) * P1_CAP;
    int lt = 0;
    if (t3     < b) lt += s0;
    if (t3 + 1 < b) lt += s1;
    if (t3 + 2 < b) lt += s2;
    if (b == t3) sh_szb = s0;
    else if (b == t3 + 1) sh_szb = s1;
    else if (b == t3 + 2) sh_szb = s2;
    redA[t] = lt;
    redB[t] = s0 + s1 + s2;
    __syncthreads();
    for (int ofs = 128; ofs > 0; ofs >>= 1) {
      if (t < ofs) { redA[t] += redA[t + ofs]; redB[t] += redB[t + ofs]; }
      __syncthreads();
    }
  }
  const int fb = redA[0];
  const int sz = sh_szb;
  if (b == 0 && t == 0) off[n3] = redB[0];
  const size_t pb = (size_t)b * P1_CAP;
  const int d0 = b << BKT_SHIFT;
  cnt_l[t] = 0; cnt_l[t + 256] = 0;
  __syncthreads();
  for (int i = t; i < sz; i += 256)
    atomicAdd(&cnt_l[p1o[pb + i] >> 20], 1);
  __syncthreads();
  int c0 = cnt_l[2 * t], c1 = cnt_l[2 * t + 1];
  ts[t] = c0 + c1;
  __syncthreads();
  for (int ofs = 1; ofs < 256; ofs <<= 1) {
    int x = ts[t];
    int y = (t >= ofs) ? ts[t - ofs] : 0;
    __syncthreads();
    ts[t] = x + y;
    __syncthreads();
  }
  int ebase = (t == 0) ? 0 : ts[t - 1];
  off_l[2 * t] = ebase; off_l[2 * t + 1] = ebase + c0;
  cur_l[2 * t] = ebase; cur_l[2 * t + 1] = ebase + c0;
  __syncthreads();
  for (int j = t; j < 512; j += 256) {
    int d = d0 + j;
    if (d < n3) off[d] = fb + off_l[j];
  }
  if (sz <= P2_CAP) {
    for (int i = t; i < sz; i += 256) {
      uint32_t w = p1o[pb + i];
      int pos = atomicAdd(&cur_l[w >> 20], 1);
      img[pos] = (int)(w & 0xFFFFFu) << 6;   // u32-word offset (src*64)
    }
    __syncthreads();
    for (int i = t; i < sz; i += 256) srcl[fb + i] = img[i];
  } else {  // statistically unreachable
    for (int i = t; i < sz; i += 256) {
      uint32_t w = p1o[pb + i];
      int pos = atomicAdd(&cur_l[w >> 20], 1);
      srcl[fb + pos] = (int)(w & 0xFFFFFu) << 6;
    }
  }
}

// ---------------- CSR gather-mean over bf16 plane: 32 lanes/dst, 2 dsts/wave ----------------
__device__ __forceinline__ void gather_one32(const uint32_t* __restrict__ plane,
                                             const int* __restrict__ off,
                                             const int* __restrict__ srcl,
                                             short* __restrict__ out,
                                             int d, int lane) {
  int b = off[d], e = off[d + 1];
  const int c2 = lane * 2;
  float a0 = 0.f, a1 = 0.f, a2 = 0.f, a3 = 0.f;
  float b0 = 0.f, b1 = 0.f, b2 = 0.f, b3 = 0.f;
  float c0 = 0.f, c1 = 0.f, c2f = 0.f, c3 = 0.f;
  float e0 = 0.f, e1 = 0.f, e2 = 0.f, e3 = 0.f;
  float t0, t1;
  int j = b;
  for (; j + 3 < e; j += 4) {
    int o0 = __builtin_nontemporal_load(srcl + j);
    int o1 = __builtin_nontemporal_load(srcl + j + 1);
    int o2 = __builtin_nontemporal_load(srcl + j + 2);
    int o3 = __builtin_nontemporal_load(srcl + j + 3);
    uint2 w0 = *(const uint2*)(plane + (size_t)(o0 + c2));
    uint2 w1 = *(const uint2*)(plane + (size_t)(o1 + c2));
    uint2 w2 = *(const uint2*)(plane + (size_t)(o2 + c2));
    uint2 w3 = *(const uint2*)(plane + (size_t)(o3 + c2));
    unpk2(w0.x, t0, t1); a0 += t0; a1 += t1;
    unpk2(w0.y, t0, t1); a2 += t0; a3 += t1;
    unpk2(w1.x, t0, t1); b0 += t0; b1 += t1;
    unpk2(w1.y, t0, t1); b2 += t0; b3 += t1;
    unpk2(w2.x, t0, t1); c0 += t0; c1 += t1;
    unpk2(w2.y, t0, t1); c2f += t0; c3 += t1;
    unpk2(w3.x, t0, t1); e0 += t0; e1 += t1;
    unpk2(w3.y, t0, t1); e2 += t0; e3 += t1;
  }
  for (; j < e; ++j) {
    int o = __builtin_nontemporal_load(srcl + j);
    uint2 w = *(const uint2*)(plane + (size_t)(o + c2));
    unpk2(w.x, t0, t1); a0 += t0; a1 += t1;
    unpk2(w.y, t0, t1); a2 += t0; a3 += t1;
  }
  float sc = 1.0f / (float)max(e - b, 1);
  short4v r = { f2bf_rne(((a0 + b0) + (c0 + e0)) * sc),
                f2bf_rne(((a1 + b1) + (c1 + e1)) * sc),
                f2bf_rne(((a2 + b2) + (c2f + e2)) * sc),
                f2bf_rne(((a3 + b3) + (c3 + e3)) * sc) };
  __builtin_nontemporal_store(r, (short4v*)(out + (size_t)d * 128 + lane * 4));
}

__global__ __launch_bounds__(256) void k_gather3(
    const uint32_t* __restrict__ pA, const uint32_t* __restrict__ pB,
    short* __restrict__ g1, short* __restrict__ g2, short* __restrict__ g3,
    const int* __restrict__ off, const int* __restrict__ srcl, int n) {
  int wv = (blockIdx.x * 256 + threadIdx.x) >> 6;
  int half = (threadIdx.x >> 5) & 1;
  int lane = threadIdx.x & 31;
  int d = wv * 2 + half;
  if (d >= 3 * n) return;
  if (d < n)          gather_one32(pA, off + n,     srcl, g1, d,         lane);  // ei1: A->B
  else if (d < 2 * n) gather_one32(pB, off + 2 * n, srcl, g2, d - n,     lane);  // ei2: B->A
  else                gather_one32(pA, off,         srcl, g3, d - 2 * n, lane);  // ei0: A->A
}

// ---------------- split-weight bf16 MFMA multi-term matmul: A-job + B-job fused ----------------
// All terms: bf16 feature plane, 2 MFMAs (ah*whi + ah*wlo).
struct MMJob {
  const short* s0; const short* s1; const short* s2;   // bf16 planes (s2 = self)
  const short* w0h; const short* w0l;
  const short* w1h; const short* w1l;
  const short* w2h; const short* w2l;
  const float* bias;
  void* out;
  int nt;
  uint32_t k0, k1;
};

template <int MODE>
__global__ __launch_bounds__(256, 2) void k_mmx2(MMJob JA, MMJob JB, int gA, int n) {
  __shared__ short A_s[128 * 72];   // hi region [0..32) used; 72-stride (2-way-free banks)
  __shared__ short W_s[128 * 72];   // [n][32hi|32lo|8pad]
  MMJob j;
  int bid;
  if (blockIdx.x < (unsigned)gA) { j = JA; bid = blockIdx.x; }
  else                           { j = JB; bid = blockIdx.x - gA; }
  const int t = threadIdx.x;
  const int r0 = bid * 128;
  const int lane = t & 63;
  const int w = t >> 6;
  const int wr = w >> 1, wc = w & 1;
  const int lr = lane & 15, lg = lane >> 4;
  const int sr = t >> 1, sh = t & 1;
  const int rr = min(r0 + sr, n - 1);

  f32x4 acc[4][4];
#pragma unroll
  for (int nf = 0; nf < 4; ++nf) {
    float bv = j.bias[wc * 64 + nf * 16 + lr];
#pragma unroll
    for (int mf = 0; mf < 4; ++mf) acc[mf][nf] = {bv, bv, bv, bv};
  }

  for (int term = 0; term < j.nt; ++term) {
    const short* src = term == 0 ? j.s0 : (term == 1 ? j.s1 : j.s2);
    const short* wh  = term == 0 ? j.w0h : (term == 1 ? j.w1h : j.w2h);
    const short* wl  = term == 0 ? j.w0l : (term == 1 ? j.w1l : j.w2l);
    const short* wsrc = sh ? wl : wh;
    for (int ks = 0; ks < 4; ++ks) {
      __syncthreads();
      { // A tile: 16 shorts per thread (bf16 plane)
        const uint4* ga = (const uint4*)(src + (size_t)rr * 128 + ks * 32 + sh * 16);
        uint4 q0 = ga[0], q1 = ga[1];
        uint4* Ah = (uint4*)(A_s + sr * 72 + sh * 16);
        Ah[0] = q0; Ah[1] = q1;
      }
      { // W tile: 32 shorts of hi or lo plane per thread
        const uint4* gw = (const uint4*)(wsrc + sr * 128 + ks * 32);
        uint4 b0 = gw[0], b1 = gw[1], b2 = gw[2], b3 = gw[3];
        uint4* lw = (uint4*)(W_s + sr * 72 + sh * 32);
        lw[0] = b0; lw[1] = b1; lw[2] = b2; lw[3] = b3;
      }
      __syncthreads();
      short8v whi[4], wlo[4];
#pragma unroll
      for (int nf = 0; nf < 4; ++nf) {
        int nc = wc * 64 + nf * 16 + lr;
        whi[nf] = *(const short8v*)(W_s + nc * 72 + lg * 8);
        wlo[nf] = *(const short8v*)(W_s + nc * 72 + 32 + lg * 8);
      }
#pragma unroll
      for (int mf = 0; mf < 4; ++mf) {
        int ar = wr * 64 + mf * 16 + lr;
        short8v ah = *(const short8v*)(A_s + ar * 72 + lg * 8);
#pragma unroll
        for (int nf = 0; nf < 4; ++nf) {
          acc[mf][nf] = __builtin_amdgcn_mfma_f32_16x16x32_bf16(ah, whi[nf], acc[mf][nf], 0, 0, 0);
          acc[mf][nf] = __builtin_amdgcn_mfma_f32_16x16x32_bf16(ah, wlo[nf], acc[mf][nf], 0, 0, 0);
        }
      }
    }
  }

#pragma unroll
  for (int mf = 0; mf < 4; ++mf) {
#pragma unroll
    for (int r = 0; r < 4; ++r) {
      int g = r0 + wr * 64 + mf * 16 + lg * 4 + r;
      if (g >= n) continue;
#pragma unroll
      for (int nf = 0; nf < 4; ++nf) {
        int col = wc * 64 + nf * 16 + lr;
        float v = acc[mf][nf][r];
        if constexpr (MODE == 1) {
          uint32_t o0, o1;
          tf2x32(j.k0, j.k1, 0u, (uint32_t)(g * 128 + col), o0, o1);
          uint32_t bits = o0 ^ o1;
          float u = __uint_as_float((bits >> 9) | 0x3f800000u) - 1.0f;
          v = (u < 0.8f) ? (v / 0.8f) : 0.0f;
          v = fmaxf(v, 0.0f);
          ((short*)j.out)[(size_t)g * 128 + col] = f2bf_rne(v);
        } else {
          __builtin_nontemporal_store(v, (float*)j.out + (size_t)g * 128 + col);
        }
      }
    }
  }
}

// ---------------- host driver ----------------
extern "C" void kernel_launch(void* const* d_in, const int* in_sizes, int n_in,
                              void* d_out, int out_size, void* d_ws, size_t ws_size,
                              hipStream_t stream) {
  const float* xA  = (const float*)d_in[0];
  const float* xB  = (const float*)d_in[1];
  const int*   ei0 = (const int*)d_in[2];
  const int*   ei1 = (const int*)d_in[3];
  const int*   ei2 = (const int*)d_in[4];
  const float* Wn1 = (const float*)d_in[5];
  const float* Ws1 = (const float*)d_in[6];
  const float* Wu1 = (const float*)d_in[7];
  const float* Wn2 = (const float*)d_in[8];
  const float* Ws2 = (const float*)d_in[9];
  const float* Wu2 = (const float*)d_in[10];
  const float* bn1 = (const float*)d_in[11];
  const float* bs1 = (const float*)d_in[12];
  const float* bu1 = (const float*)d_in[13];
  const float* bn2 = (const float*)d_in[14];
  const float* bs2 = (const float*)d_in[15];
  const float* bu2 = (const float*)d_in[16];

  const int n  = in_sizes[0] / DIMF;        // 100000
  const int E  = in_sizes[2] / 2;           // 1600000
  const int n3 = 3 * n;
  const int nbk = (n3 + 511) >> BKT_SHIFT;  // 586 (p2 scan supports <= 768)
  const size_t nh = (size_t)n * DIMF;

  short* S = (short*)d_ws;
  short* hA = S;                        // [nh] bf16 plane (x -> h2A in place)
  short* hB = S + nh;
  short* g1 = S + 2 * nh;               // bf16 aggr planes; g1+g2 alias p1o
  short* g2 = S + 3 * nh;
  short* g3 = S + 4 * nh;
  short* wtsS = S + 5 * nh;             // 10 x (16384 hi + 16384 lo)
  float* biasF = (float*)(wtsS + 10 * 32768);
  float* cbA1 = biasF, *cbB1 = biasF + 128, *cbA2 = biasF + 256, *cbB2 = biasF + 384;
  int* off  = (int*)(biasF + 512);          // [n3+1]
  int* gcur = off + n3 + 1;                 // [BKT_MAX]
  int* srcl = gcur + BKT_MAX;               // [3E] plane u32-word offsets
  uint32_t* p1o = (uint32_t*)g1;            // spans g1+g2: nh u32 >= nbk*P1_CAP

  size_t need_bytes = (size_t)5 * nh * sizeof(short)
                    + (size_t)10 * 32768 * sizeof(short)
                    + 512 * sizeof(float)
                    + ((size_t)n3 + 1 + BKT_MAX + (size_t)3 * E) * sizeof(int)
                    + 65536;
  if (ws_size < need_bytes) {
    fprintf(stderr, "kernel_launch: ws too small (%zu < %zu)\n", ws_size, need_bytes);
    return;
  }
  if ((size_t)nbk * P1_CAP > nh || nbk > 768) {
    fprintf(stderr, "kernel_launch: bucket config overflow\n");
    return;
  }

  // JAX keys: dk = split(key(42), 4) (partitionable threefry, verified round 2)
  uint32_t dk[4][2];
  for (uint32_t i = 0; i < 4; ++i) tf2x32(0u, 42u, 0u, i, dk[i][0], dk[i][1]);

  WPack pk;
  auto U = [](const float* Wu, int t) { return Wu + (size_t)t * 32768; };
  auto L = [](const float* Wu, int t) { return Wu + (size_t)t * 32768 + 16384; };
  auto WH = [&](int m) { return wtsS + (size_t)m * 32768; };
  auto WL = [&](int m) { return wtsS + (size_t)m * 32768 + 16384; };
  const size_t MS = 128 * 128;
  pk.d[0] = { Wn1 + 0 * MS, U(Wu1, 0), nullptr, nullptr, WH(0), WL(0) };
  pk.d[1] = { Wn1 + 1 * MS, U(Wu1, 1), nullptr, nullptr, WH(1), WL(1) };
  pk.d[2] = { Wn1 + 2 * MS, U(Wu1, 2), nullptr, nullptr, WH(2), WL(2) };
  pk.d[3] = { Ws1 + 0 * MS, L(Wu1, 0), Ws1 + 2 * MS, L(Wu1, 2), WH(3), WL(3) };
  pk.d[4] = { Ws1 + 1 * MS, L(Wu1, 1), nullptr, nullptr, WH(4), WL(4) };
  pk.d[5] = { Wn2 + 0 * MS, U(Wu2, 0), nullptr, nullptr, WH(5), WL(5) };
  pk.d[6] = { Wn2 + 1 * MS, U(Wu2, 1), nullptr, nullptr, WH(6), WL(6) };
  pk.d[7] = { Wn2 + 2 * MS, U(Wu2, 2), nullptr, nullptr, WH(7), WL(7) };
  pk.d[8] = { Ws2 + 0 * MS, L(Wu2, 0), Ws2 + 2 * MS, L(Wu2, 2), WH(8), WL(8) };
  pk.d[9] = { Ws2 + 1 * MS, L(Wu2, 1), nullptr, nullptr, WH(9), WL(9) };

  const int npair = (int)(nh / 2);
  const int gdrop = (npair + 255) / 256;
  const int gE8   = (E + P1_CHUNK - 1) / P1_CHUNK;
  const int gmm   = (n + 127) / 128;
  const int nwv   = (n3 + 1) / 2;
  const int gga3  = (nwv * 64 + 255) / 256;

  // 1. setup: wprec | bias | gcur-init
  k_setup<<<43, 256, 0, stream>>>(pk, bn1, bs1, bu1, Wu1, bn2, bs2, bu2, Wu2,
                                  cbA1, cbB1, cbA2, cbB2, gcur, nbk);
  // 2. p1 (bucket scatter) || dropout (independent; co-scheduled)
  k_p1drop<<<3 * gE8 + 2 * gdrop, 256, 0, stream>>>(
      ei0, ei1, ei2, gcur, p1o, E, n, gE8, nbk,
      xA, xB, (uint32_t*)hA, (uint32_t*)hB, npair, gdrop,
      dk[0][0], dk[0][1], dk[1][0], dk[1][1]);
  // 3. p2: per-bucket prefix + counting sort -> off, srcl
  k_p2<<<nbk, 256, 0, stream>>>(p1o, gcur, off, srcl, nbk, n3);

  // ---- layer 1 ----
  k_gather3<<<gga3, 256, 0, stream>>>((const uint32_t*)hA, (const uint32_t*)hB,
                                      g1, g2, g3, off, srcl, n);
  {
    MMJob JA = { g3, g2, hA, WH(0), WL(0), WH(2), WL(2), WH(3), WL(3),
                 cbA1, hA, 3, dk[2][0], dk[2][1] };
    MMJob JB = { g1, hB, nullptr, WH(1), WL(1), WH(4), WL(4), nullptr, nullptr,
                 cbB1, hB, 2, dk[3][0], dk[3][1] };
    k_mmx2<1><<<2 * gmm, 256, 0, stream>>>(JA, JB, gmm, n);
  }

  // ---- layer 2 ----
  float* oA = (float*)d_out;
  float* oB = oA + nh;
  k_gather3<<<gga3, 256, 0, stream>>>((const uint32_t*)hA, (const uint32_t*)hB,
                                      g1, g2, g3, off, srcl, n);
  {
    MMJob JA = { g3, g2, hA, WH(5), WL(5), WH(7), WL(7), WH(8), WL(8),
                 cbA2, oA, 3, 0u, 0u };
    MMJob JB = { g1, hB, nullptr, WH(6), WL(6), WH(9), WL(9), nullptr, nullptr,
                 cbB2, oB, 2, 0u, 0u };
    k_mmx2<0><<<2 * gmm, 256, 0, stream>>>(JA, JB, gmm, n);
  }
}

// Round 16
// 718.916 us; speedup vs baseline: 1.7221x; 1.0047x over previous
//
#include <hip/hip_runtime.h>
#include <cstdint>
#include <cstdio>

#define DIMF 128
#define BKT_SHIFT 9        // 512 dsts per bucket
#define BKT_MAX 1024       // p2 internal scan supports nbk <= 768
#define P1_CHUNK 8192      // edges per p1 block
#define P1_CAP 16384       // padded slots per bucket (mean 8192, sigma ~90)
#define P2_CAP 12288       // LDS image capacity

typedef __attribute__((ext_vector_type(8))) short short8v;
typedef __attribute__((ext_vector_type(4))) short short4v;
typedef __attribute__((ext_vector_type(4))) float f32x4;

// Feature planes: PLAIN bf16 [n*128] shorts everywhere (r13-verified: absmax
// insensitive; added error ~1e-4 max vs 6.05e-4 threshold). Weights SPLIT
// hi/lo bf16 (2 MFMAs per term). Gather reads plane, writes bf16 plane.
// srcl stores u32-word offsets (src*64).

// ---------------- JAX threefry2x32 (exact) ----------------
__host__ __device__ __forceinline__ void tf2x32(uint32_t k0, uint32_t k1,
                                                uint32_t x0, uint32_t x1,
                                                uint32_t& o0, uint32_t& o1) {
  uint32_t ks2 = k0 ^ k1 ^ 0x1BD11BDAu;
  x0 += k0; x1 += k1;
#define TFR(r) { x0 += x1; x1 = (x1 << (r)) | (x1 >> (32 - (r))); x1 ^= x0; }
  TFR(13) TFR(15) TFR(26) TFR(6)
  x0 += k1;  x1 += ks2 + 1u;
  TFR(17) TFR(29) TFR(16) TFR(24)
  x0 += ks2; x1 += k0 + 2u;
  TFR(13) TFR(15) TFR(26) TFR(6)
  x0 += k0;  x1 += k1 + 3u;
  TFR(17) TFR(29) TFR(16) TFR(24)
  x0 += k1;  x1 += ks2 + 4u;
  TFR(13) TFR(15) TFR(26) TFR(6)
  x0 += ks2; x1 += k0 + 5u;
#undef TFR
  o0 = x0; o1 = x1;
}

__device__ __forceinline__ short f2bf_rne(float x) {
  uint32_t u = __float_as_uint(x);
  uint32_t r = (u + 0x7FFFu + ((u >> 16) & 1u)) >> 16;
  return (short)r;
}
__device__ __forceinline__ float bfhi_f(short h) {
  return __uint_as_float(((uint32_t)(uint16_t)h) << 16);
}
__device__ __forceinline__ void unpk2(uint32_t w, float& f0, float& f1) {
  f0 = __uint_as_float(w << 16);
  f1 = __uint_as_float(w & 0xFFFF0000u);
}

// ---------------- combined-weight precompute (desc) ----------------
struct WDesc { const float* A0; const float* B0; const float* A1; const float* B1; short* Ch; short* Cl; };
struct WPack { WDesc d[10]; };

// ---------------- setup mega-kernel: wprec (blocks 0..39) | bias (40,41) | ginit (42) ----------------
__global__ __launch_bounds__(256) void k_setup(WPack p,
    const float* __restrict__ bn1, const float* __restrict__ bs1,
    const float* __restrict__ bu1, const float* __restrict__ Wu1,
    const float* __restrict__ bn2, const float* __restrict__ bs2,
    const float* __restrict__ bu2, const float* __restrict__ Wu2,
    float* __restrict__ cbA1, float* __restrict__ cbB1,
    float* __restrict__ cbA2, float* __restrict__ cbB2,
    int* __restrict__ gcur, int nbk) {
  __shared__ float A_s[32 * 128];
  const int bx = blockIdx.x;
  const int t = threadIdx.x;
  if (bx < 40) {
    const WDesc d = p.d[bx >> 2];
    const int rt = bx & 3;
    const int c = t & 127, rh = t >> 7;
    float acc[16];
#pragma unroll
    for (int i = 0; i < 16; ++i) acc[i] = 0.f;
    for (int pass = 0; pass < 2; ++pass) {
      const float* A = pass ? d.A1 : d.A0;
      const float* B = pass ? d.B1 : d.B0;
      if (!A) break;
      __syncthreads();
#pragma unroll
      for (int jj = 0; jj < 4; ++jj) {
        int f = t + 256 * jj;
        *(float4*)(A_s + 4 * f) = *(const float4*)(A + (size_t)rt * 32 * 128 + 4 * f);
      }
      __syncthreads();
      for (int k = 0; k < 128; ++k) {
        float b = B[(size_t)k * 128 + c];
#pragma unroll
        for (int i = 0; i < 16; ++i)
          acc[i] += A_s[(rh + 2 * i) * 128 + k] * b;
      }
    }
#pragma unroll
    for (int i = 0; i < 16; ++i) {
      int k = rt * 32 + rh + 2 * i;
      float v = acc[i];
      short hi = f2bf_rne(v);
      short lo = f2bf_rne(v - bfhi_f(hi));
      d.Ch[(size_t)c * 128 + k] = hi;
      d.Cl[(size_t)c * 128 + k] = lo;
    }
  } else if (bx < 42) {
    const int layer = bx - 40;
    const float* bn = layer ? bn2 : bn1;
    const float* bs = layer ? bs2 : bs1;
    const float* bu = layer ? bu2 : bu1;
    const float* Wu = layer ? Wu2 : Wu1;
    float* cbA = layer ? cbA2 : cbA1;
    float* cbB = layer ? cbB2 : cbB1;
    int h = t & 127;
    if (t < 128) {
      float acc = bu[0 * 128 + h] + bu[2 * 128 + h];
      for (int j = 0; j < 128; ++j) {
        acc += bn[0 * 128 + j] * Wu[(size_t)0 * 32768 + (size_t)j * 128 + h];
        acc += bs[0 * 128 + j] * Wu[(size_t)0 * 32768 + 16384 + (size_t)j * 128 + h];
        acc += bn[2 * 128 + j] * Wu[(size_t)2 * 32768 + (size_t)j * 128 + h];
        acc += bs[2 * 128 + j] * Wu[(size_t)2 * 32768 + 16384 + (size_t)j * 128 + h];
      }
      cbA[h] = acc;
    } else {
      float acc = bu[128 + h];
      for (int j = 0; j < 128; ++j) {
        acc += bn[128 + j] * Wu[(size_t)1 * 32768 + (size_t)j * 128 + h];
        acc += bs[128 + j] * Wu[(size_t)1 * 32768 + 16384 + (size_t)j * 128 + h];
      }
      cbB[h] = acc;
    }
  } else {
    for (int i = t; i < nbk; i += 256) gcur[i] = i * P1_CAP;
  }
}

// ---------------- p1 (padded-bucket scatter) fused with dropout ----------------
__global__ __launch_bounds__(256) void k_p1drop(
    const int* __restrict__ ei0, const int* __restrict__ ei1, const int* __restrict__ ei2,
    int* __restrict__ gcur, uint32_t* __restrict__ p1o,
    int E, int n, int gE8, int nbk,
    const float* __restrict__ xA, const float* __restrict__ xB,
    uint32_t* __restrict__ pA, uint32_t* __restrict__ pB,
    int npair, int gdrop,
    uint32_t ka0, uint32_t ka1, uint32_t kb0, uint32_t kb1) {
  __shared__ int hist[BKT_MAX];
  __shared__ int cur[BKT_MAX];
  const int t = threadIdx.x;
  if (blockIdx.x < (unsigned)(3 * gE8)) {
    // ---- p1 path ----
    int type = blockIdx.x / gE8;
    int chunk = blockIdx.x - type * gE8;
    const int* ei = type == 0 ? ei0 : (type == 1 ? ei1 : ei2);
    int base = chunk * P1_CHUNK;
    int dof = type * n;
    for (int i = t; i < nbk; i += 256) hist[i] = 0;
    __syncthreads();
    int sv[P1_CHUNK / 256];
    int dv[P1_CHUNK / 256];
#pragma unroll
    for (int j = 0; j < P1_CHUNK / 256; ++j) {
      int e = base + j * 256 + t;
      if (e < E) { sv[j] = ei[e]; dv[j] = ei[E + e] + dof; }
      else dv[j] = -1;
    }
#pragma unroll
    for (int j = 0; j < P1_CHUNK / 256; ++j)
      if (dv[j] >= 0) atomicAdd(&hist[dv[j] >> BKT_SHIFT], 1);
    __syncthreads();
    for (int i = t; i < nbk; i += 256) {
      int h = hist[i];
      if (h > 0) cur[i] = atomicAdd(&gcur[i], h);
    }
    __syncthreads();
#pragma unroll
    for (int j = 0; j < P1_CHUNK / 256; ++j) {
      if (dv[j] >= 0) {
        int bkt = dv[j] >> BKT_SHIFT;
        int pos = atomicAdd(&cur[bkt], 1);
        p1o[pos] = (uint32_t)sv[j] | ((uint32_t)(dv[j] & 511) << 20);
      }
    }
  } else {
    // ---- dropout+relu path -> bf16 plane ----
    int bd = blockIdx.x - 3 * gE8;
    int isB = bd >= gdrop;
    int p = (bd - (isB ? gdrop : 0)) * 256 + t;
    if (p >= npair) return;
    const float* in = isB ? xB : xA;
    uint32_t* plane = isB ? pB : pA;
    uint32_t k0 = isB ? kb0 : ka0, k1 = isB ? kb1 : ka1;
    int row = p >> 6, w = p & 63;
    int c2 = w * 2;
    float2 x = *(const float2*)(in + (size_t)row * 128 + c2);
    uint32_t idx = (uint32_t)(row * 128 + c2);
    float v[2] = {x.x, x.y};
    uint32_t hw = 0;
#pragma unroll
    for (int q = 0; q < 2; ++q) {
      uint32_t o0, o1;
      tf2x32(k0, k1, 0u, idx + q, o0, o1);
      uint32_t bits = o0 ^ o1;
      float u = __uint_as_float((bits >> 9) | 0x3f800000u) - 1.0f;
      float y = (u < 0.8f) ? (v[q] / 0.8f) : 0.0f;
      y = fmaxf(y, 0.0f);
      hw |= (uint32_t)(uint16_t)f2bf_rne(y) << (16 * q);
    }
    plane[(size_t)row * 64 + w] = hw;
  }
}

// ---------------- p2: self-prefix + counting sort within bucket ----------------
__global__ __launch_bounds__(256) void k_p2(const uint32_t* __restrict__ p1o,
                                            const int* __restrict__ gcur,
                                            int* __restrict__ off,
                                            int* __restrict__ srcl,
                                            int nbk, int n3) {
  __shared__ int redA[256];
  __shared__ int redB[256];
  __shared__ int sh_szb;
  __shared__ int cnt_l[512];
  __shared__ int off_l[512];
  __shared__ int cur_l[512];
  __shared__ int ts[256];
  __shared__ int img[P2_CAP];
  const int b = blockIdx.x;
  const int t = threadIdx.x;
  // bucket sizes: s_i = gcur[i] - i*P1_CAP; need fb = sum_{i<b}, sz = s_b, tot
  {
    int t3 = t * 3;
    int s0 = 0, s1 = 0, s2 = 0;
    if (t3     < nbk) s0 = gcur[t3]     - t3 * P1_CAP;
    if (t3 + 1 < nbk) s1 = gcur[t3 + 1] - (t3 + 1) * P1_CAP;
    if (t3 + 2 < nbk) s2 = gcur[t3 + 2] - (t3 + 2) * P1_CAP;
    int lt = 0;
    if (t3     < b) lt += s0;
    if (t3 + 1 < b) lt += s1;
    if (t3 + 2 < b) lt += s2;
    if (b == t3) sh_szb = s0;
    else if (b == t3 + 1) sh_szb = s1;
    else if (b == t3 + 2) sh_szb = s2;
    redA[t] = lt;
    redB[t] = s0 + s1 + s2;
    __syncthreads();
    for (int ofs = 128; ofs > 0; ofs >>= 1) {
      if (t < ofs) { redA[t] += redA[t + ofs]; redB[t] += redB[t + ofs]; }
      __syncthreads();
    }
  }
  const int fb = redA[0];
  const int sz = sh_szb;
  if (b == 0 && t == 0) off[n3] = redB[0];
  const size_t pb = (size_t)b * P1_CAP;
  const int d0 = b << BKT_SHIFT;
  cnt_l[t] = 0; cnt_l[t + 256] = 0;
  __syncthreads();
  for (int i = t; i < sz; i += 256)
    atomicAdd(&cnt_l[p1o[pb + i] >> 20], 1);
  __syncthreads();
  int c0 = cnt_l[2 * t], c1 = cnt_l[2 * t + 1];
  ts[t] = c0 + c1;
  __syncthreads();
  for (int ofs = 1; ofs < 256; ofs <<= 1) {
    int x = ts[t];
    int y = (t >= ofs) ? ts[t - ofs] : 0;
    __syncthreads();
    ts[t] = x + y;
    __syncthreads();
  }
  int ebase = (t == 0) ? 0 : ts[t - 1];
  off_l[2 * t] = ebase; off_l[2 * t + 1] = ebase + c0;
  cur_l[2 * t] = ebase; cur_l[2 * t + 1] = ebase + c0;
  __syncthreads();
  for (int j = t; j < 512; j += 256) {
    int d = d0 + j;
    if (d < n3) off[d] = fb + off_l[j];
  }
  if (sz <= P2_CAP) {
    for (int i = t; i < sz; i += 256) {
      uint32_t w = p1o[pb + i];
      int pos = atomicAdd(&cur_l[w >> 20], 1);
      img[pos] = (int)(w & 0xFFFFFu) << 6;   // u32-word offset (src*64)
    }
    __syncthreads();
    for (int i = t; i < sz; i += 256) srcl[fb + i] = img[i];
  } else {  // statistically unreachable
    for (int i = t; i < sz; i += 256) {
      uint32_t w = p1o[pb + i];
      int pos = atomicAdd(&cur_l[w >> 20], 1);
      srcl[fb + pos] = (int)(w & 0xFFFFFu) << 6;
    }
  }
}

// ---------------- CSR gather-mean over bf16 plane: 32 lanes/dst, 2 dsts/wave ----------------
__device__ __forceinline__ void gather_one32(const uint32_t* __restrict__ plane,
                                             const int* __restrict__ off,
                                             const int* __restrict__ srcl,
                                             short* __restrict__ out,
                                             int d, int lane) {
  int b = off[d], e = off[d + 1];
  const int c2 = lane * 2;
  float a0 = 0.f, a1 = 0.f, a2 = 0.f, a3 = 0.f;
  float b0 = 0.f, b1 = 0.f, b2 = 0.f, b3 = 0.f;
  float c0 = 0.f, c1 = 0.f, c2f = 0.f, c3 = 0.f;
  float e0 = 0.f, e1 = 0.f, e2 = 0.f, e3 = 0.f;
  float t0, t1;
  int j = b;
  for (; j + 3 < e; j += 4) {
    int o0 = __builtin_nontemporal_load(srcl + j);
    int o1 = __builtin_nontemporal_load(srcl + j + 1);
    int o2 = __builtin_nontemporal_load(srcl + j + 2);
    int o3 = __builtin_nontemporal_load(srcl + j + 3);
    uint2 w0 = *(const uint2*)(plane + (size_t)(o0 + c2));
    uint2 w1 = *(const uint2*)(plane + (size_t)(o1 + c2));
    uint2 w2 = *(const uint2*)(plane + (size_t)(o2 + c2));
    uint2 w3 = *(const uint2*)(plane + (size_t)(o3 + c2));
    unpk2(w0.x, t0, t1); a0 += t0; a1 += t1;
    unpk2(w0.y, t0, t1); a2 += t0; a3 += t1;
    unpk2(w1.x, t0, t1); b0 += t0; b1 += t1;
    unpk2(w1.y, t0, t1); b2 += t0; b3 += t1;
    unpk2(w2.x, t0, t1); c0 += t0; c1 += t1;
    unpk2(w2.y, t0, t1); c2f += t0; c3 += t1;
    unpk2(w3.x, t0, t1); e0 += t0; e1 += t1;
    unpk2(w3.y, t0, t1); e2 += t0; e3 += t1;
  }
  for (; j < e; ++j) {
    int o = __builtin_nontemporal_load(srcl + j);
    uint2 w = *(const uint2*)(plane + (size_t)(o + c2));
    unpk2(w.x, t0, t1); a0 += t0; a1 += t1;
    unpk2(w.y, t0, t1); a2 += t0; a3 += t1;
  }
  float sc = 1.0f / (float)max(e - b, 1);
  short4v r = { f2bf_rne(((a0 + b0) + (c0 + e0)) * sc),
                f2bf_rne(((a1 + b1) + (c1 + e1)) * sc),
                f2bf_rne(((a2 + b2) + (c2f + e2)) * sc),
                f2bf_rne(((a3 + b3) + (c3 + e3)) * sc) };
  __builtin_nontemporal_store(r, (short4v*)(out + (size_t)d * 128 + lane * 4));
}

__global__ __launch_bounds__(256) void k_gather3(
    const uint32_t* __restrict__ pA, const uint32_t* __restrict__ pB,
    short* __restrict__ g1, short* __restrict__ g2, short* __restrict__ g3,
    const int* __restrict__ off, const int* __restrict__ srcl, int n) {
  int wv = (blockIdx.x * 256 + threadIdx.x) >> 6;
  int half = (threadIdx.x >> 5) & 1;
  int lane = threadIdx.x & 31;
  int d = wv * 2 + half;
  if (d >= 3 * n) return;
  if (d < n)          gather_one32(pA, off + n,     srcl, g1, d,         lane);  // ei1: A->B
  else if (d < 2 * n) gather_one32(pB, off + 2 * n, srcl, g2, d - n,     lane);  // ei2: B->A
  else                gather_one32(pA, off,         srcl, g3, d - 2 * n, lane);  // ei0: A->A
}

// ---------------- split-weight bf16 MFMA multi-term matmul: A-job + B-job fused ----------------
// All terms: bf16 feature plane, 2 MFMAs (ah*whi + ah*wlo).
struct MMJob {
  const short* s0; const short* s1; const short* s2;   // bf16 planes (s2 = self)
  const short* w0h; const short* w0l;
  const short* w1h; const short* w1l;
  const short* w2h; const short* w2l;
  const float* bias;
  void* out;
  int nt;
  uint32_t k0, k1;
};

template <int MODE>
__global__ __launch_bounds__(256, 2) void k_mmx2(MMJob JA, MMJob JB, int gA, int n) {
  __shared__ short A_s[128 * 72];   // hi region [0..32) used; 72-stride (2-way-free banks)
  __shared__ short W_s[128 * 72];   // [n][32hi|32lo|8pad]
  MMJob j;
  int bid;
  if (blockIdx.x < (unsigned)gA) { j = JA; bid = blockIdx.x; }
  else                           { j = JB; bid = blockIdx.x - gA; }
  const int t = threadIdx.x;
  const int r0 = bid * 128;
  const int lane = t & 63;
  const int w = t >> 6;
  const int wr = w >> 1, wc = w & 1;
  const int lr = lane & 15, lg = lane >> 4;
  const int sr = t >> 1, sh = t & 1;
  const int rr = min(r0 + sr, n - 1);

  f32x4 acc[4][4];
#pragma unroll
  for (int nf = 0; nf < 4; ++nf) {
    float bv = j.bias[wc * 64 + nf * 16 + lr];
#pragma unroll
    for (int mf = 0; mf < 4; ++mf) acc[mf][nf] = {bv, bv, bv, bv};
  }

  for (int term = 0; term < j.nt; ++term) {
    const short* src = term == 0 ? j.s0 : (term == 1 ? j.s1 : j.s2);
    const short* wh  = term == 0 ? j.w0h : (term == 1 ? j.w1h : j.w2h);
    const short* wl  = term == 0 ? j.w0l : (term == 1 ? j.w1l : j.w2l);
    const short* wsrc = sh ? wl : wh;
    for (int ks = 0; ks < 4; ++ks) {
      __syncthreads();
      { // A tile: 16 shorts per thread (bf16 plane)
        const uint4* ga = (const uint4*)(src + (size_t)rr * 128 + ks * 32 + sh * 16);
        uint4 q0 = ga[0], q1 = ga[1];
        uint4* Ah = (uint4*)(A_s + sr * 72 + sh * 16);
        Ah[0] = q0; Ah[1] = q1;
      }
      { // W tile: 32 shorts of hi or lo plane per thread
        const uint4* gw = (const uint4*)(wsrc + sr * 128 + ks * 32);
        uint4 b0 = gw[0], b1 = gw[1], b2 = gw[2], b3 = gw[3];
        uint4* lw = (uint4*)(W_s + sr * 72 + sh * 32);
        lw[0] = b0; lw[1] = b1; lw[2] = b2; lw[3] = b3;
      }
      __syncthreads();
      short8v whi[4], wlo[4];
#pragma unroll
      for (int nf = 0; nf < 4; ++nf) {
        int nc = wc * 64 + nf * 16 + lr;
        whi[nf] = *(const short8v*)(W_s + nc * 72 + lg * 8);
        wlo[nf] = *(const short8v*)(W_s + nc * 72 + 32 + lg * 8);
      }
#pragma unroll
      for (int mf = 0; mf < 4; ++mf) {
        int ar = wr * 64 + mf * 16 + lr;
        short8v ah = *(const short8v*)(A_s + ar * 72 + lg * 8);
#pragma unroll
        for (int nf = 0; nf < 4; ++nf) {
          acc[mf][nf] = __builtin_amdgcn_mfma_f32_16x16x32_bf16(ah, whi[nf], acc[mf][nf], 0, 0, 0);
          acc[mf][nf] = __builtin_amdgcn_mfma_f32_16x16x32_bf16(ah, wlo[nf], acc[mf][nf], 0, 0, 0);
        }
      }
    }
  }

#pragma unroll
  for (int mf = 0; mf < 4; ++mf) {
#pragma unroll
    for (int r = 0; r < 4; ++r) {
      int g = r0 + wr * 64 + mf * 16 + lg * 4 + r;
      if (g >= n) continue;
#pragma unroll
      for (int nf = 0; nf < 4; ++nf) {
        int col = wc * 64 + nf * 16 + lr;
        float v = acc[mf][nf][r];
        if constexpr (MODE == 1) {
          uint32_t o0, o1;
          tf2x32(j.k0, j.k1, 0u, (uint32_t)(g * 128 + col), o0, o1);
          uint32_t bits = o0 ^ o1;
          float u = __uint_as_float((bits >> 9) | 0x3f800000u) - 1.0f;
          v = (u < 0.8f) ? (v / 0.8f) : 0.0f;
          v = fmaxf(v, 0.0f);
          ((short*)j.out)[(size_t)g * 128 + col] = f2bf_rne(v);
        } else {
          __builtin_nontemporal_store(v, (float*)j.out + (size_t)g * 128 + col);
        }
      }
    }
  }
}

// ---------------- host driver ----------------
extern "C" void kernel_launch(void* const* d_in, const int* in_sizes, int n_in,
                              void* d_out, int out_size, void* d_ws, size_t ws_size,
                              hipStream_t stream) {
  const float* xA  = (const float*)d_in[0];
  const float* xB  = (const float*)d_in[1];
  const int*   ei0 = (const int*)d_in[2];
  const int*   ei1 = (const int*)d_in[3];
  const int*   ei2 = (const int*)d_in[4];
  const float* Wn1 = (const float*)d_in[5];
  const float* Ws1 = (const float*)d_in[6];
  const float* Wu1 = (const float*)d_in[7];
  const float* Wn2 = (const float*)d_in[8];
  const float* Ws2 = (const float*)d_in[9];
  const float* Wu2 = (const float*)d_in[10];
  const float* bn1 = (const float*)d_in[11];
  const float* bs1 = (const float*)d_in[12];
  const float* bu1 = (const float*)d_in[13];
  const float* bn2 = (const float*)d_in[14];
  const float* bs2 = (const float*)d_in[15];
  const float* bu2 = (const float*)d_in[16];

  const int n  = in_sizes[0] / DIMF;        // 100000
  const int E  = in_sizes[2] / 2;           // 1600000
  const int n3 = 3 * n;
  const int nbk = (n3 + 511) >> BKT_SHIFT;  // 586 (p2 scan supports <= 768)
  const size_t nh = (size_t)n * DIMF;

  short* S = (short*)d_ws;
  short* hA = S;                        // [nh] bf16 plane (x -> h2A in place)
  short* hB = S + nh;
  short* g1 = S + 2 * nh;               // bf16 aggr planes; g1+g2 alias p1o
  short* g2 = S + 3 * nh;
  short* g3 = S + 4 * nh;
  short* wtsS = S + 5 * nh;             // 10 x (16384 hi + 16384 lo)
  float* biasF = (float*)(wtsS + 10 * 32768);
  float* cbA1 = biasF, *cbB1 = biasF + 128, *cbA2 = biasF + 256, *cbB2 = biasF + 384;
  int* off  = (int*)(biasF + 512);          // [n3+1]
  int* gcur = off + n3 + 1;                 // [BKT_MAX]
  int* srcl = gcur + BKT_MAX;               // [3E] plane u32-word offsets
  uint32_t* p1o = (uint32_t*)g1;            // spans g1+g2: nh u32 >= nbk*P1_CAP

  size_t need_bytes = (size_t)5 * nh * sizeof(short)
                    + (size_t)10 * 32768 * sizeof(short)
                    + 512 * sizeof(float)
                    + ((size_t)n3 + 1 + BKT_MAX + (size_t)3 * E) * sizeof(int)
                    + 65536;
  if (ws_size < need_bytes) {
    fprintf(stderr, "kernel_launch: ws too small (%zu < %zu)\n", ws_size, need_bytes);
    return;
  }
  if ((size_t)nbk * P1_CAP > nh || nbk > 768) {
    fprintf(stderr, "kernel_launch: bucket config overflow\n");
    return;
  }

  // JAX keys: dk = split(key(42), 4) (partitionable threefry, verified round 2)
  uint32_t dk[4][2];
  for (uint32_t i = 0; i < 4; ++i) tf2x32(0u, 42u, 0u, i, dk[i][0], dk[i][1]);

  WPack pk;
  auto U = [](const float* Wu, int t) { return Wu + (size_t)t * 32768; };
  auto L = [](const float* Wu, int t) { return Wu + (size_t)t * 32768 + 16384; };
  auto WH = [&](int m) { return wtsS + (size_t)m * 32768; };
  auto WL = [&](int m) { return wtsS + (size_t)m * 32768 + 16384; };
  const size_t MS = 128 * 128;
  pk.d[0] = { Wn1 + 0 * MS, U(Wu1, 0), nullptr, nullptr, WH(0), WL(0) };
  pk.d[1] = { Wn1 + 1 * MS, U(Wu1, 1), nullptr, nullptr, WH(1), WL(1) };
  pk.d[2] = { Wn1 + 2 * MS, U(Wu1, 2), nullptr, nullptr, WH(2), WL(2) };
  pk.d[3] = { Ws1 + 0 * MS, L(Wu1, 0), Ws1 + 2 * MS, L(Wu1, 2), WH(3), WL(3) };
  pk.d[4] = { Ws1 + 1 * MS, L(Wu1, 1), nullptr, nullptr, WH(4), WL(4) };
  pk.d[5] = { Wn2 + 0 * MS, U(Wu2, 0), nullptr, nullptr, WH(5), WL(5) };
  pk.d[6] = { Wn2 + 1 * MS, U(Wu2, 1), nullptr, nullptr, WH(6), WL(6) };
  pk.d[7] = { Wn2 + 2 * MS, U(Wu2, 2), nullptr, nullptr, WH(7), WL(7) };
  pk.d[8] = { Ws2 + 0 * MS, L(Wu2, 0), Ws2 + 2 * MS, L(Wu2, 2), WH(8), WL(8) };
  pk.d[9] = { Ws2 + 1 * MS, L(Wu2, 1), nullptr, nullptr, WH(9), WL(9) };

  const int npair = (int)(nh / 2);
  const int gdrop = (npair + 255) / 256;
  const int gE8   = (E + P1_CHUNK - 1) / P1_CHUNK;
  const int gmm   = (n + 127) / 128;
  const int nwv   = (n3 + 1) / 2;
  const int gga3  = (nwv * 64 + 255) / 256;

  // 1. setup: wprec | bias | gcur-init
  k_setup<<<43, 256, 0, stream>>>(pk, bn1, bs1, bu1, Wu1, bn2, bs2, bu2, Wu2,
                                  cbA1, cbB1, cbA2, cbB2, gcur, nbk);
  // 2. p1 (bucket scatter) || dropout (independent; co-scheduled)
  k_p1drop<<<3 * gE8 + 2 * gdrop, 256, 0, stream>>>(
      ei0, ei1, ei2, gcur, p1o, E, n, gE8, nbk,
      xA, xB, (uint32_t*)hA, (uint32_t*)hB, npair, gdrop,
      dk[0][0], dk[0][1], dk[1][0], dk[1][1]);
  // 3. p2: per-bucket prefix + counting sort -> off, srcl
  k_p2<<<nbk, 256, 0, stream>>>(p1o, gcur, off, srcl, nbk, n3);

  // ---- layer 1 ----
  k_gather3<<<gga3, 256, 0, stream>>>((const uint32_t*)hA, (const uint32_t*)hB,
                                      g1, g2, g3, off, srcl, n);
  {
    MMJob JA = { g3, g2, hA, WH(0), WL(0), WH(2), WL(2), WH(3), WL(3),
                 cbA1, hA, 3, dk[2][0], dk[2][1] };
    MMJob JB = { g1, hB, nullptr, WH(1), WL(1), WH(4), WL(4), nullptr, nullptr,
                 cbB1, hB, 2, dk[3][0], dk[3][1] };
    k_mmx2<1><<<2 * gmm, 256, 0, stream>>>(JA, JB, gmm, n);
  }

  // ---- layer 2 ----
  float* oA = (float*)d_out;
  float* oB = oA + nh;
  k_gather3<<<gga3, 256, 0, stream>>>((const uint32_t*)hA, (const uint32_t*)hB,
                                      g1, g2, g3, off, srcl, n);
  {
    MMJob JA = { g3, g2, hA, WH(5), WL(5), WH(7), WL(7), WH(8), WL(8),
                 cbA2, oA, 3, 0u, 0u };
    MMJob JB = { g1, hB, nullptr, WH(6), WL(6), WH(9), WL(9), nullptr, nullptr,
                 cbB2, oB, 2, 0u, 0u };
    k_mmx2<0><<<2 * gmm, 256, 0, stream>>>(JA, JB, gmm, n);
  }
}

// Round 18
// 679.698 us; speedup vs baseline: 1.8215x; 1.0577x over previous
//
#include <hip/hip_runtime.h>
#include <cstdint>
#include <cstdio>

#define DIMF 128
#define BKT_SHIFT 9        // 512 dsts per bucket
#define BKT_MAX 1024       // p2 internal scan supports nbk <= 768
#define P1_CHUNK 8192      // edges per p1 block
#define P1_CAP 16384       // padded slots per bucket (mean 8192, sigma ~90)
#define P2_CAP 12288       // LDS image capacity

typedef __attribute__((ext_vector_type(8))) short short8v;
typedef __attribute__((ext_vector_type(4))) short short4v;
typedef __attribute__((ext_vector_type(4))) float f32x4;

// Feature planes: PLAIN bf16 [n*128] shorts (r13/r16-verified). Weights now
// PLAIN bf16 too (1 MFMA per term; predicted absmax <= ~3.5e-4 vs 6.05e-4).
// Gather reads plane, writes bf16 plane. srcl stores u32-word offsets (src*64).

// ---------------- JAX threefry2x32 (exact) ----------------
__host__ __device__ __forceinline__ void tf2x32(uint32_t k0, uint32_t k1,
                                                uint32_t x0, uint32_t x1,
                                                uint32_t& o0, uint32_t& o1) {
  uint32_t ks2 = k0 ^ k1 ^ 0x1BD11BDAu;
  x0 += k0; x1 += k1;
#define TFR(r) { x0 += x1; x1 = (x1 << (r)) | (x1 >> (32 - (r))); x1 ^= x0; }
  TFR(13) TFR(15) TFR(26) TFR(6)
  x0 += k1;  x1 += ks2 + 1u;
  TFR(17) TFR(29) TFR(16) TFR(24)
  x0 += ks2; x1 += k0 + 2u;
  TFR(13) TFR(15) TFR(26) TFR(6)
  x0 += k0;  x1 += k1 + 3u;
  TFR(17) TFR(29) TFR(16) TFR(24)
  x0 += k1;  x1 += ks2 + 4u;
  TFR(13) TFR(15) TFR(26) TFR(6)
  x0 += ks2; x1 += k0 + 5u;
#undef TFR
  o0 = x0; o1 = x1;
}

__device__ __forceinline__ short f2bf_rne(float x) {
  uint32_t u = __float_as_uint(x);
  uint32_t r = (u + 0x7FFFu + ((u >> 16) & 1u)) >> 16;
  return (short)r;
}
__device__ __forceinline__ float bfhi_f(short h) {
  return __uint_as_float(((uint32_t)(uint16_t)h) << 16);
}
__device__ __forceinline__ void unpk2(uint32_t w, float& f0, float& f1) {
  f0 = __uint_as_float(w << 16);
  f1 = __uint_as_float(w & 0xFFFF0000u);
}

// ---------------- combined-weight precompute (desc) ----------------
struct WDesc { const float* A0; const float* B0; const float* A1; const float* B1; short* Ch; };
struct WPack { WDesc d[10]; };

// ---------------- setup mega-kernel: wprec (blocks 0..39) | bias (40,41) | ginit (42) ----------------
__global__ __launch_bounds__(256) void k_setup(WPack p,
    const float* __restrict__ bn1, const float* __restrict__ bs1,
    const float* __restrict__ bu1, const float* __restrict__ Wu1,
    const float* __restrict__ bn2, const float* __restrict__ bs2,
    const float* __restrict__ bu2, const float* __restrict__ Wu2,
    float* __restrict__ cbA1, float* __restrict__ cbB1,
    float* __restrict__ cbA2, float* __restrict__ cbB2,
    int* __restrict__ gcur, int nbk) {
  __shared__ float A_s[32 * 128];
  const int bx = blockIdx.x;
  const int t = threadIdx.x;
  if (bx < 40) {
    const WDesc d = p.d[bx >> 2];
    const int rt = bx & 3;
    const int c = t & 127, rh = t >> 7;
    float acc[16];
#pragma unroll
    for (int i = 0; i < 16; ++i) acc[i] = 0.f;
    for (int pass = 0; pass < 2; ++pass) {
      const float* A = pass ? d.A1 : d.A0;
      const float* B = pass ? d.B1 : d.B0;
      if (!A) break;
      __syncthreads();
#pragma unroll
      for (int jj = 0; jj < 4; ++jj) {
        int f = t + 256 * jj;
        *(float4*)(A_s + 4 * f) = *(const float4*)(A + (size_t)rt * 32 * 128 + 4 * f);
      }
      __syncthreads();
      for (int k = 0; k < 128; ++k) {
        float b = B[(size_t)k * 128 + c];
#pragma unroll
        for (int i = 0; i < 16; ++i)
          acc[i] += A_s[(rh + 2 * i) * 128 + k] * b;
      }
    }
#pragma unroll
    for (int i = 0; i < 16; ++i) {
      int k = rt * 32 + rh + 2 * i;
      d.Ch[(size_t)c * 128 + k] = f2bf_rne(acc[i]);
    }
  } else if (bx < 42) {
    const int layer = bx - 40;
    const float* bn = layer ? bn2 : bn1;
    const float* bs = layer ? bs2 : bs1;
    const float* bu = layer ? bu2 : bu1;
    const float* Wu = layer ? Wu2 : Wu1;
    float* cbA = layer ? cbA2 : cbA1;
    float* cbB = layer ? cbB2 : cbB1;
    int h = t & 127;
    if (t < 128) {
      float acc = bu[0 * 128 + h] + bu[2 * 128 + h];
      for (int j = 0; j < 128; ++j) {
        acc += bn[0 * 128 + j] * Wu[(size_t)0 * 32768 + (size_t)j * 128 + h];
        acc += bs[0 * 128 + j] * Wu[(size_t)0 * 32768 + 16384 + (size_t)j * 128 + h];
        acc += bn[2 * 128 + j] * Wu[(size_t)2 * 32768 + (size_t)j * 128 + h];
        acc += bs[2 * 128 + j] * Wu[(size_t)2 * 32768 + 16384 + (size_t)j * 128 + h];
      }
      cbA[h] = acc;
    } else {
      float acc = bu[128 + h];
      for (int j = 0; j < 128; ++j) {
        acc += bn[128 + j] * Wu[(size_t)1 * 32768 + (size_t)j * 128 + h];
        acc += bs[128 + j] * Wu[(size_t)1 * 32768 + 16384 + (size_t)j * 128 + h];
      }
      cbB[h] = acc;
    }
  } else {
    for (int i = t; i < nbk; i += 256) gcur[i] = i * P1_CAP;
  }
}

// ---------------- p1 (padded-bucket scatter) fused with dropout ----------------
__global__ __launch_bounds__(256) void k_p1drop(
    const int* __restrict__ ei0, const int* __restrict__ ei1, const int* __restrict__ ei2,
    int* __restrict__ gcur, uint32_t* __restrict__ p1o,
    int E, int n, int gE8, int nbk,
    const float* __restrict__ xA, const float* __restrict__ xB,
    uint32_t* __restrict__ pA, uint32_t* __restrict__ pB,
    int npair, int gdrop,
    uint32_t ka0, uint32_t ka1, uint32_t kb0, uint32_t kb1) {
  __shared__ int hist[BKT_MAX];
  __shared__ int cur[BKT_MAX];
  const int t = threadIdx.x;
  if (blockIdx.x < (unsigned)(3 * gE8)) {
    // ---- p1 path ----
    int type = blockIdx.x / gE8;
    int chunk = blockIdx.x - type * gE8;
    const int* ei = type == 0 ? ei0 : (type == 1 ? ei1 : ei2);
    int base = chunk * P1_CHUNK;
    int dof = type * n;
    for (int i = t; i < nbk; i += 256) hist[i] = 0;
    __syncthreads();
    int sv[P1_CHUNK / 256];
    int dv[P1_CHUNK / 256];
#pragma unroll
    for (int j = 0; j < P1_CHUNK / 256; ++j) {
      int e = base + j * 256 + t;
      if (e < E) { sv[j] = ei[e]; dv[j] = ei[E + e] + dof; }
      else dv[j] = -1;
    }
#pragma unroll
    for (int j = 0; j < P1_CHUNK / 256; ++j)
      if (dv[j] >= 0) atomicAdd(&hist[dv[j] >> BKT_SHIFT], 1);
    __syncthreads();
    for (int i = t; i < nbk; i += 256) {
      int h = hist[i];
      if (h > 0) cur[i] = atomicAdd(&gcur[i], h);
    }
    __syncthreads();
#pragma unroll
    for (int j = 0; j < P1_CHUNK / 256; ++j) {
      if (dv[j] >= 0) {
        int bkt = dv[j] >> BKT_SHIFT;
        int pos = atomicAdd(&cur[bkt], 1);
        p1o[pos] = (uint32_t)sv[j] | ((uint32_t)(dv[j] & 511) << 20);
      }
    }
  } else {
    // ---- dropout+relu path -> bf16 plane ----
    int bd = blockIdx.x - 3 * gE8;
    int isB = bd >= gdrop;
    int p = (bd - (isB ? gdrop : 0)) * 256 + t;
    if (p >= npair) return;
    const float* in = isB ? xB : xA;
    uint32_t* plane = isB ? pB : pA;
    uint32_t k0 = isB ? kb0 : ka0, k1 = isB ? kb1 : ka1;
    int row = p >> 6, w = p & 63;
    int c2 = w * 2;
    float2 x = *(const float2*)(in + (size_t)row * 128 + c2);
    uint32_t idx = (uint32_t)(row * 128 + c2);
    float v[2] = {x.x, x.y};
    uint32_t hw = 0;
#pragma unroll
    for (int q = 0; q < 2; ++q) {
      uint32_t o0, o1;
      tf2x32(k0, k1, 0u, idx + q, o0, o1);
      uint32_t bits = o0 ^ o1;
      float u = __uint_as_float((bits >> 9) | 0x3f800000u) - 1.0f;
      float y = (u < 0.8f) ? (v[q] / 0.8f) : 0.0f;
      y = fmaxf(y, 0.0f);
      hw |= (uint32_t)(uint16_t)f2bf_rne(y) << (16 * q);
    }
    plane[(size_t)row * 64 + w] = hw;
  }
}

// ---------------- p2: self-prefix + counting sort within bucket ----------------
__global__ __launch_bounds__(256) void k_p2(const uint32_t* __restrict__ p1o,
                                            const int* __restrict__ gcur,
                                            int* __restrict__ off,
                                            int* __restrict__ srcl,
                                            int nbk, int n3) {
  __shared__ int redA[256];
  __shared__ int redB[256];
  __shared__ int sh_szb;
  __shared__ int cnt_l[512];
  __shared__ int off_l[512];
  __shared__ int cur_l[512];
  __shared__ int ts[256];
  __shared__ int img[P2_CAP];
  const int b = blockIdx.x;
  const int t = threadIdx.x;
  {
    int t3 = t * 3;
    int s0 = 0, s1 = 0, s2 = 0;
    if (t3     < nbk) s0 = gcur[t3]     - t3 * P1_CAP;
    if (t3 + 1 < nbk) s1 = gcur[t3 + 1] - (t3 + 1) * P1_CAP;
    if (t3 + 2 < nbk) s2 = gcur[t3 + 2] - (t3 + 2) * P1_CAP;
    int lt = 0;
    if (t3     < b) lt += s0;
    if (t3 + 1 < b) lt += s1;
    if (t3 + 2 < b) lt += s2;
    if (b == t3) sh_szb = s0;
    else if (b == t3 + 1) sh_szb = s1;
    else if (b == t3 + 2) sh_szb = s2;
    redA[t] = lt;
    redB[t] = s0 + s1 + s2;
    __syncthreads();
    for (int ofs = 128; ofs > 0; ofs >>= 1) {
      if (t < ofs) { redA[t] += redA[t + ofs]; redB[t] += redB[t + ofs]; }
      __syncthreads();
    }
  }
  const int fb = redA[0];
  const int sz = sh_szb;
  if (b == 0 && t == 0) off[n3] = redB[0];
  const size_t pb = (size_t)b * P1_CAP;
  const int d0 = b << BKT_SHIFT;
  cnt_l[t] = 0; cnt_l[t + 256] = 0;
  __syncthreads();
  for (int i = t; i < sz; i += 256)
    atomicAdd(&cnt_l[p1o[pb + i] >> 20], 1);
  __syncthreads();
  int c0 = cnt_l[2 * t], c1 = cnt_l[2 * t + 1];
  ts[t] = c0 + c1;
  __syncthreads();
  for (int ofs = 1; ofs < 256; ofs <<= 1) {
    int x = ts[t];
    int y = (t >= ofs) ? ts[t - ofs] : 0;
    __syncthreads();
    ts[t] = x + y;
    __syncthreads();
  }
  int ebase = (t == 0) ? 0 : ts[t - 1];
  off_l[2 * t] = ebase; off_l[2 * t + 1] = ebase + c0;
  cur_l[2 * t] = ebase; cur_l[2 * t + 1] = ebase + c0;
  __syncthreads();
  for (int j = t; j < 512; j += 256) {
    int d = d0 + j;
    if (d < n3) off[d] = fb + off_l[j];
  }
  if (sz <= P2_CAP) {
    for (int i = t; i < sz; i += 256) {
      uint32_t w = p1o[pb + i];
      int pos = atomicAdd(&cur_l[w >> 20], 1);
      img[pos] = (int)(w & 0xFFFFFu) << 6;   // u32-word offset (src*64)
    }
    __syncthreads();
    for (int i = t; i < sz; i += 256) srcl[fb + i] = img[i];
  } else {  // statistically unreachable
    for (int i = t; i < sz; i += 256) {
      uint32_t w = p1o[pb + i];
      int pos = atomicAdd(&cur_l[w >> 20], 1);
      srcl[fb + pos] = (int)(w & 0xFFFFFu) << 6;
    }
  }
}

// ---------------- CSR gather-mean over bf16 plane: 32 lanes/dst, 2 dsts/wave ----------------
__device__ __forceinline__ void gather_one32(const uint32_t* __restrict__ plane,
                                             const int* __restrict__ off,
                                             const int* __restrict__ srcl,
                                             short* __restrict__ out,
                                             int d, int lane) {
  int b = off[d], e = off[d + 1];
  const int c2 = lane * 2;
  float a0 = 0.f, a1 = 0.f, a2 = 0.f, a3 = 0.f;
  float b0 = 0.f, b1 = 0.f, b2 = 0.f, b3 = 0.f;
  float c0 = 0.f, c1 = 0.f, c2f = 0.f, c3 = 0.f;
  float e0 = 0.f, e1 = 0.f, e2 = 0.f, e3 = 0.f;
  float t0, t1;
  int j = b;
  for (; j + 3 < e; j += 4) {
    int o0 = __builtin_nontemporal_load(srcl + j);
    int o1 = __builtin_nontemporal_load(srcl + j + 1);
    int o2 = __builtin_nontemporal_load(srcl + j + 2);
    int o3 = __builtin_nontemporal_load(srcl + j + 3);
    uint2 w0 = *(const uint2*)(plane + (size_t)(o0 + c2));
    uint2 w1 = *(const uint2*)(plane + (size_t)(o1 + c2));
    uint2 w2 = *(const uint2*)(plane + (size_t)(o2 + c2));
    uint2 w3 = *(const uint2*)(plane + (size_t)(o3 + c2));
    unpk2(w0.x, t0, t1); a0 += t0; a1 += t1;
    unpk2(w0.y, t0, t1); a2 += t0; a3 += t1;
    unpk2(w1.x, t0, t1); b0 += t0; b1 += t1;
    unpk2(w1.y, t0, t1); b2 += t0; b3 += t1;
    unpk2(w2.x, t0, t1); c0 += t0; c1 += t1;
    unpk2(w2.y, t0, t1); c2f += t0; c3 += t1;
    unpk2(w3.x, t0, t1); e0 += t0; e1 += t1;
    unpk2(w3.y, t0, t1); e2 += t0; e3 += t1;
  }
  for (; j < e; ++j) {
    int o = __builtin_nontemporal_load(srcl + j);
    uint2 w = *(const uint2*)(plane + (size_t)(o + c2));
    unpk2(w.x, t0, t1); a0 += t0; a1 += t1;
    unpk2(w.y, t0, t1); a2 += t0; a3 += t1;
  }
  float sc = 1.0f / (float)max(e - b, 1);
  short4v r = { f2bf_rne(((a0 + b0) + (c0 + e0)) * sc),
                f2bf_rne(((a1 + b1) + (c1 + e1)) * sc),
                f2bf_rne(((a2 + b2) + (c2f + e2)) * sc),
                f2bf_rne(((a3 + b3) + (c3 + e3)) * sc) };
  __builtin_nontemporal_store(r, (short4v*)(out + (size_t)d * 128 + lane * 4));
}

__global__ __launch_bounds__(256) void k_gather3(
    const uint32_t* __restrict__ pA, const uint32_t* __restrict__ pB,
    short* __restrict__ g1, short* __restrict__ g2, short* __restrict__ g3,
    const int* __restrict__ off, const int* __restrict__ srcl, int n) {
  int wv = (blockIdx.x * 256 + threadIdx.x) >> 6;
  int half = (threadIdx.x >> 5) & 1;
  int lane = threadIdx.x & 31;
  int d = wv * 2 + half;
  if (d >= 3 * n) return;
  if (d < n)          gather_one32(pA, off + n,     srcl, g1, d,         lane);  // ei1: A->B
  else if (d < 2 * n) gather_one32(pB, off + 2 * n, srcl, g2, d - n,     lane);  // ei2: B->A
  else                gather_one32(pA, off,         srcl, g3, d - 2 * n, lane);  // ei0: A->A
}

// ---------------- plain-bf16 MFMA multi-term matmul: A-job + B-job fused ----------------
// All terms: bf16 feature plane x bf16 weight, 1 MFMA per fragment.
struct MMJob {
  const short* s0; const short* s1; const short* s2;   // bf16 planes (s2 = self)
  const short* w0; const short* w1; const short* w2;   // bf16 weights (n-major)
  const float* bias;
  void* out;
  int nt;
  uint32_t k0, k1;
};

template <int MODE>
__global__ __launch_bounds__(256, 2) void k_mmx2(MMJob JA, MMJob JB, int gA, int n) {
  __shared__ short A_s[128 * 72];   // region [0..32) used per row; 72-stride
  __shared__ short W_s[128 * 72];   // [n][32k|40pad]
  MMJob j;
  int bid;
  if (blockIdx.x < (unsigned)gA) { j = JA; bid = blockIdx.x; }
  else                           { j = JB; bid = blockIdx.x - gA; }
  const int t = threadIdx.x;
  const int r0 = bid * 128;
  const int lane = t & 63;
  const int w = t >> 6;
  const int wr = w >> 1, wc = w & 1;
  const int lr = lane & 15, lg = lane >> 4;
  const int sr = t >> 1, sh = t & 1;
  const int rr = min(r0 + sr, n - 1);

  f32x4 acc[4][4];
#pragma unroll
  for (int nf = 0; nf < 4; ++nf) {
    float bv = j.bias[wc * 64 + nf * 16 + lr];
#pragma unroll
    for (int mf = 0; mf < 4; ++mf) acc[mf][nf] = {bv, bv, bv, bv};
  }

  for (int term = 0; term < j.nt; ++term) {
    const short* src = term == 0 ? j.s0 : (term == 1 ? j.s1 : j.s2);
    const short* wsrc = term == 0 ? j.w0 : (term == 1 ? j.w1 : j.w2);
    for (int ks = 0; ks < 4; ++ks) {
      __syncthreads();
      { // A tile: 16 shorts per thread (bf16 plane)
        const uint4* ga = (const uint4*)(src + (size_t)rr * 128 + ks * 32 + sh * 16);
        uint4 q0 = ga[0], q1 = ga[1];
        uint4* Ah = (uint4*)(A_s + sr * 72 + sh * 16);
        Ah[0] = q0; Ah[1] = q1;
      }
      { // W tile: 16 shorts per thread (bf16 weight plane)
        const uint4* gw = (const uint4*)(wsrc + sr * 128 + ks * 32 + sh * 16);
        uint4 b0 = gw[0], b1 = gw[1];
        uint4* lw = (uint4*)(W_s + sr * 72 + sh * 16);
        lw[0] = b0; lw[1] = b1;
      }
      __syncthreads();
      short8v whi[4];
#pragma unroll
      for (int nf = 0; nf < 4; ++nf) {
        int nc = wc * 64 + nf * 16 + lr;
        whi[nf] = *(const short8v*)(W_s + nc * 72 + lg * 8);
      }
#pragma unroll
      for (int mf = 0; mf < 4; ++mf) {
        int ar = wr * 64 + mf * 16 + lr;
        short8v ah = *(const short8v*)(A_s + ar * 72 + lg * 8);
#pragma unroll
        for (int nf = 0; nf < 4; ++nf) {
          acc[mf][nf] = __builtin_amdgcn_mfma_f32_16x16x32_bf16(ah, whi[nf], acc[mf][nf], 0, 0, 0);
        }
      }
    }
  }

#pragma unroll
  for (int mf = 0; mf < 4; ++mf) {
#pragma unroll
    for (int r = 0; r < 4; ++r) {
      int g = r0 + wr * 64 + mf * 16 + lg * 4 + r;
      if (g >= n) continue;
#pragma unroll
      for (int nf = 0; nf < 4; ++nf) {
        int col = wc * 64 + nf * 16 + lr;
        float v = acc[mf][nf][r];
        if constexpr (MODE == 1) {
          uint32_t o0, o1;
          tf2x32(j.k0, j.k1, 0u, (uint32_t)(g * 128 + col), o0, o1);
          uint32_t bits = o0 ^ o1;
          float u = __uint_as_float((bits >> 9) | 0x3f800000u) - 1.0f;
          v = (u < 0.8f) ? (v / 0.8f) : 0.0f;
          v = fmaxf(v, 0.0f);
          ((short*)j.out)[(size_t)g * 128 + col] = f2bf_rne(v);
        } else {
          __builtin_nontemporal_store(v, (float*)j.out + (size_t)g * 128 + col);
        }
      }
    }
  }
}

// ---------------- host driver ----------------
extern "C" void kernel_launch(void* const* d_in, const int* in_sizes, int n_in,
                              void* d_out, int out_size, void* d_ws, size_t ws_size,
                              hipStream_t stream) {
  const float* xA  = (const float*)d_in[0];
  const float* xB  = (const float*)d_in[1];
  const int*   ei0 = (const int*)d_in[2];
  const int*   ei1 = (const int*)d_in[3];
  const int*   ei2 = (const int*)d_in[4];
  const float* Wn1 = (const float*)d_in[5];
  const float* Ws1 = (const float*)d_in[6];
  const float* Wu1 = (const float*)d_in[7];
  const float* Wn2 = (const float*)d_in[8];
  const float* Ws2 = (const float*)d_in[9];
  const float* Wu2 = (const float*)d_in[10];
  const float* bn1 = (const float*)d_in[11];
  const float* bs1 = (const float*)d_in[12];
  const float* bu1 = (const float*)d_in[13];
  const float* bn2 = (const float*)d_in[14];
  const float* bs2 = (const float*)d_in[15];
  const float* bu2 = (const float*)d_in[16];

  const int n  = in_sizes[0] / DIMF;        // 100000
  const int E  = in_sizes[2] / 2;           // 1600000
  const int n3 = 3 * n;
  const int nbk = (n3 + 511) >> BKT_SHIFT;  // 586 (p2 scan supports <= 768)
  const size_t nh = (size_t)n * DIMF;

  short* S = (short*)d_ws;
  short* hA = S;                        // [nh] bf16 plane (x -> h2A in place)
  short* hB = S + nh;
  short* g1 = S + 2 * nh;               // bf16 aggr planes; g1+g2 alias p1o
  short* g2 = S + 3 * nh;
  short* g3 = S + 4 * nh;
  short* wtsS = S + 5 * nh;             // 10 x 16384 bf16 weights
  float* biasF = (float*)(wtsS + 10 * 16384);
  float* cbA1 = biasF, *cbB1 = biasF + 128, *cbA2 = biasF + 256, *cbB2 = biasF + 384;
  int* off  = (int*)(biasF + 512);          // [n3+1]
  int* gcur = off + n3 + 1;                 // [BKT_MAX]
  int* srcl = gcur + BKT_MAX;               // [3E] plane u32-word offsets
  uint32_t* p1o = (uint32_t*)g1;            // spans g1+g2: nh u32 >= nbk*P1_CAP

  size_t need_bytes = (size_t)5 * nh * sizeof(short)
                    + (size_t)10 * 16384 * sizeof(short)
                    + 512 * sizeof(float)
                    + ((size_t)n3 + 1 + BKT_MAX + (size_t)3 * E) * sizeof(int)
                    + 65536;
  if (ws_size < need_bytes) {
    fprintf(stderr, "kernel_launch: ws too small (%zu < %zu)\n", ws_size, need_bytes);
    return;
  }
  if ((size_t)nbk * P1_CAP > nh || nbk > 768) {
    fprintf(stderr, "kernel_launch: bucket config overflow\n");
    return;
  }

  // JAX keys: dk = split(key(42), 4) (partitionable threefry, verified round 2)
  uint32_t dk[4][2];
  for (uint32_t i = 0; i < 4; ++i) tf2x32(0u, 42u, 0u, i, dk[i][0], dk[i][1]);

  WPack pk;
  auto U = [](const float* Wu, int t) { return Wu + (size_t)t * 32768; };
  auto L = [](const float* Wu, int t) { return Wu + (size_t)t * 32768 + 16384; };
  auto WH = [&](int m) { return wtsS + (size_t)m * 16384; };
  const size_t MS = 128 * 128;
  pk.d[0] = { Wn1 + 0 * MS, U(Wu1, 0), nullptr, nullptr, WH(0) };
  pk.d[1] = { Wn1 + 1 * MS, U(Wu1, 1), nullptr, nullptr, WH(1) };
  pk.d[2] = { Wn1 + 2 * MS, U(Wu1, 2), nullptr, nullptr, WH(2) };
  pk.d[3] = { Ws1 + 0 * MS, L(Wu1, 0), Ws1 + 2 * MS, L(Wu1, 2), WH(3) };
  pk.d[4] = { Ws1 + 1 * MS, L(Wu1, 1), nullptr, nullptr, WH(4) };
  pk.d[5] = { Wn2 + 0 * MS, U(Wu2, 0), nullptr, nullptr, WH(5) };
  pk.d[6] = { Wn2 + 1 * MS, U(Wu2, 1), nullptr, nullptr, WH(6) };
  pk.d[7] = { Wn2 + 2 * MS, U(Wu2, 2), nullptr, nullptr, WH(7) };
  pk.d[8] = { Ws2 + 0 * MS, L(Wu2, 0), Ws2 + 2 * MS, L(Wu2, 2), WH(8) };
  pk.d[9] = { Ws2 + 1 * MS, L(Wu2, 1), nullptr, nullptr, WH(9) };

  const int npair = (int)(nh / 2);
  const int gdrop = (npair + 255) / 256;
  const int gE8   = (E + P1_CHUNK - 1) / P1_CHUNK;
  const int gmm   = (n + 127) / 128;
  const int nwv   = (n3 + 1) / 2;
  const int gga3  = (nwv * 64 + 255) / 256;

  // 1. setup: wprec | bias | gcur-init
  k_setup<<<43, 256, 0, stream>>>(pk, bn1, bs1, bu1, Wu1, bn2, bs2, bu2, Wu2,
                                  cbA1, cbB1, cbA2, cbB2, gcur, nbk);
  // 2. p1 (bucket scatter) || dropout (independent; co-scheduled)
  k_p1drop<<<3 * gE8 + 2 * gdrop, 256, 0, stream>>>(
      ei0, ei1, ei2, gcur, p1o, E, n, gE8, nbk,
      xA, xB, (uint32_t*)hA, (uint32_t*)hB, npair, gdrop,
      dk[0][0], dk[0][1], dk[1][0], dk[1][1]);
  // 3. p2: per-bucket prefix + counting sort -> off, srcl
  k_p2<<<nbk, 256, 0, stream>>>(p1o, gcur, off, srcl, nbk, n3);

  // ---- layer 1 ----
  k_gather3<<<gga3, 256, 0, stream>>>((const uint32_t*)hA, (const uint32_t*)hB,
                                      g1, g2, g3, off, srcl, n);
  {
    MMJob JA = { g3, g2, hA, WH(0), WH(2), WH(3), cbA1, hA, 3, dk[2][0], dk[2][1] };
    MMJob JB = { g1, hB, nullptr, WH(1), WH(4), nullptr, cbB1, hB, 2, dk[3][0], dk[3][1] };
    k_mmx2<1><<<2 * gmm, 256, 0, stream>>>(JA, JB, gmm, n);
  }

  // ---- layer 2 ----
  float* oA = (float*)d_out;
  float* oB = oA + nh;
  k_gather3<<<gga3, 256, 0, stream>>>((const uint32_t*)hA, (const uint32_t*)hB,
                                      g1, g2, g3, off, srcl, n);
  {
    MMJob JA = { g3, g2, hA, WH(5), WH(7), WH(8), cbA2, oA, 3, 0u, 0u };
    MMJob JB = { g1, hB, nullptr, WH(6), WH(9), nullptr, cbB2, oB, 2, 0u, 0u };
    k_mmx2<0><<<2 * gmm, 256, 0, stream>>>(JA, JB, gmm, n);
  }
}